// Round 16
// baseline (329.723 us; speedup 1.0000x reference)
//
#include <hip/hip_runtime.h>
#include <hip/hip_bf16.h>
#include <cstdint>
#include <cstddef>

typedef __attribute__((ext_vector_type(8))) short bf16x8;
typedef __attribute__((ext_vector_type(4))) float f32x4;
typedef __attribute__((ext_vector_type(4))) short short4v;
typedef __attribute__((ext_vector_type(2))) unsigned int uint2v;
typedef __attribute__((ext_vector_type(4))) unsigned int uint4v;

__device__ inline void gload_lds16(const void* g, void* l) {
  __builtin_amdgcn_global_load_lds((const __attribute__((address_space(1))) void*)g,
                                   (__attribute__((address_space(3))) void*)l, 16, 0, 0);
}

__device__ inline float exp2_fast(float x) {
  float r;
  asm volatile("v_exp_f32 %0, %1" : "=v"(r) : "v"(x));
  return r;
}

__device__ inline unsigned int cvt_pk_bf16(float lo, float hi) {
  unsigned int r;
  asm volatile("v_cvt_pk_bf16_f32 %0, %1, %2" : "=v"(r) : "v"(lo), "v"(hi));
  return r;
}

__device__ inline float bf2f(short s) {
  return __uint_as_float(((unsigned int)(unsigned short)s) << 16);
}

// -------------------- transpose fp32 [R][C] -> bf16 [C][R] --------------------
__global__ void transpose_pack(const float* __restrict__ src, __hip_bfloat16* __restrict__ dst,
                               int R, int C, int ldDst, long zSrcStride, int zDstRow)
{
  __shared__ float tile[64][65];
  src += (size_t)blockIdx.z * zSrcStride;
  const int r0 = blockIdx.y * 64, c0 = blockIdx.x * 64;
  const int t = threadIdx.x;
#pragma unroll
  for (int i = 0; i < 16; ++i) {
    int idx = i * 256 + t;
    int r = idx >> 6, c = idx & 63;
    tile[r][c] = src[(size_t)(r0 + r) * C + c0 + c];
  }
  __syncthreads();
  const int drow0 = blockIdx.z * zDstRow + c0;
#pragma unroll
  for (int i = 0; i < 16; ++i) {
    int idx = i * 256 + t;
    int cc = idx >> 6, rr = idx & 63;
    dst[(size_t)(drow0 + cc) * ldDst + r0 + rr] = __float2bfloat16(tile[rr][cc]);
  }
}

// -------------------- LN1: LayerNorm(x) -> f32 + bf16 --------------------
__global__ void ln_fused(const float* __restrict__ x,
                         const float* __restrict__ g, const float* __restrict__ bta,
                         float* __restrict__ of32, __hip_bfloat16* __restrict__ obf)
{
  const int row = blockIdx.x;
  const int t = threadIdx.x;
  float4 v = ((const float4*)(x + (size_t)row * 1024))[t];
  float s = v.x + v.y + v.z + v.w;
  float ss = v.x * v.x + v.y * v.y + v.z * v.z + v.w * v.w;
#pragma unroll
  for (int off = 1; off < 64; off <<= 1) {
    s += __shfl_xor(s, off);
    ss += __shfl_xor(ss, off);
  }
  __shared__ float sb[4], ssb[4];
  const int w = t >> 6, lane = t & 63;
  if (lane == 0) { sb[w] = s; ssb[w] = ss; }
  __syncthreads();
  s = sb[0] + sb[1] + sb[2] + sb[3];
  ss = ssb[0] + ssb[1] + ssb[2] + ssb[3];
  const float mu = s * (1.f / 1024.f);
  const float var = ss * (1.f / 1024.f) - mu * mu;
  const float rstd = rsqrtf(var + 1e-5f);
  float4 gv = ((const float4*)g)[t];
  float4 bv = ((const float4*)bta)[t];
  float4 o;
  o.x = (v.x - mu) * rstd * gv.x + bv.x;
  o.y = (v.y - mu) * rstd * gv.y + bv.y;
  o.z = (v.z - mu) * rstd * gv.z + bv.z;
  o.w = (v.w - mu) * rstd * gv.w + bv.w;
  ((float4*)(of32 + (size_t)row * 1024))[t] = o;
  __hip_bfloat16 hb[4] = { __float2bfloat16(o.x), __float2bfloat16(o.y),
                           __float2bfloat16(o.z), __float2bfloat16(o.w) };
  *(short4v*)(obf + (size_t)row * 1024 + t * 4) = *(const short4v*)hb;
}

// ---------- LN2 fused with KV-split merge: y = h + sum(O)/sum(l); z = LN(y) ----------
__global__ void ln2_merge_fused(const float* __restrict__ hres,
                                const __hip_bfloat16* __restrict__ Opart,
                                const float* __restrict__ Lpart,
                                const float* __restrict__ g, const float* __restrict__ bta,
                                float* __restrict__ of32, __hip_bfloat16* __restrict__ obf)
{
  const int row = blockIdx.x;            // b*2048 + t
  const int b = row >> 11, tt = row & 2047;
  const int qblk = tt >> 7, qloc = tt & 127;
  const int nch = (qblk >> 2) + 1;
  const int t = threadIdx.x;
  const int hd = t >> 4;                 // head (4 cols per thread, within one head)
  const int d0 = (t & 15) * 4;
  const int base = ((b * 16 + hd) * 16 + qblk) << 2;

  float4 v = ((const float4*)(hres + (size_t)row * 1024))[t];
  float l = 0.f;
  float o0 = 0.f, o1 = 0.f, o2 = 0.f, o3 = 0.f;
  for (int ch = 0; ch < nch; ++ch) {     // nch uniform per block (row)
    l += Lpart[(size_t)(base + ch) * 128 + qloc];
    short4v o4 = *(const short4v*)(Opart + (size_t)(base + ch) * 8192 + qloc * 64 + d0);
    o0 += bf2f(o4[0]); o1 += bf2f(o4[1]); o2 += bf2f(o4[2]); o3 += bf2f(o4[3]);
  }
  const float inv = 1.f / l;
  v.x += o0 * inv; v.y += o1 * inv; v.z += o2 * inv; v.w += o3 * inv;

  float s = v.x + v.y + v.z + v.w;
  float ss = v.x * v.x + v.y * v.y + v.z * v.z + v.w * v.w;
#pragma unroll
  for (int off = 1; off < 64; off <<= 1) {
    s += __shfl_xor(s, off);
    ss += __shfl_xor(ss, off);
  }
  __shared__ float sb[4], ssb[4];
  const int w = t >> 6, lane = t & 63;
  if (lane == 0) { sb[w] = s; ssb[w] = ss; }
  __syncthreads();
  s = sb[0] + sb[1] + sb[2] + sb[3];
  ss = ssb[0] + ssb[1] + ssb[2] + ssb[3];
  const float mu = s * (1.f / 1024.f);
  const float var = ss * (1.f / 1024.f) - mu * mu;
  const float rstd = rsqrtf(var + 1e-5f);
  float4 gv = ((const float4*)g)[t];
  float4 bv = ((const float4*)bta)[t];
  float4 o;
  o.x = (v.x - mu) * rstd * gv.x + bv.x;
  o.y = (v.y - mu) * rstd * gv.y + bv.y;
  o.z = (v.z - mu) * rstd * gv.z + bv.z;
  o.w = (v.w - mu) * rstd * gv.w + bv.w;
  ((float4*)(of32 + (size_t)row * 1024))[t] = o;
  __hip_bfloat16 hb[4] = { __float2bfloat16(o.x), __float2bfloat16(o.y),
                           __float2bfloat16(o.z), __float2bfloat16(o.w) };
  *(short4v*)(obf + (size_t)row * 1024 + t * 4) = *(const short4v*)hb;
}

// -------------------- GEMM (R14 green): 8 waves, BM=128 BN=256 BK=32 ------------------
// 2-deep dbuf + vmcnt(3), + T1 XCD-aware chunked blockIdx swizzle.
template<int EPI>
__global__ __launch_bounds__(512, 2) void gemm_bt(
    const __hip_bfloat16* __restrict__ A, const __hip_bfloat16* __restrict__ Bt,
    int N, int Kf, int kLen,
    const float* __restrict__ bias,
    const float* __restrict__ bq, const float* __restrict__ bk, const float* __restrict__ bv,
    __hip_bfloat16* __restrict__ oq, __hip_bfloat16* __restrict__ ok, __hip_bfloat16* __restrict__ ovt,
    __hip_bfloat16* __restrict__ obf,
    float* __restrict__ opart0, float* __restrict__ opart1, float* __restrict__ opart2)
{
  __shared__ short As[2][128 * 32];   //  8 KB per buf
  __shared__ short Bs[2][256 * 32];   // 16 KB per buf
  const int t = threadIdx.x;
  const int lane = t & 63;
  const int w = t >> 6;               // 0..7
  const int wm = w >> 2, wn = w & 3;  // 2 x 4 wave grid
  const int l15 = lane & 15, lg = lane >> 4;

  const int nwg = (int)(gridDim.x * gridDim.y);
  int wgid = (int)blockIdx.y * (int)gridDim.x + (int)blockIdx.x;
  wgid = (wgid & 7) * (nwg >> 3) + (wgid >> 3);
  const int bx = wgid % (int)gridDim.x;
  const int by = wgid / (int)gridDim.x;
  const int m0 = by * 128;
  const int n0 = bx * 256;
  const int kBase = (EPI == 2) ? (int)blockIdx.z * kLen : 0;
  const int kEnd0 = kBase + kLen;
  const int kEnd = (kEnd0 > Kf) ? Kf : kEnd0;

  f32x4 acc[4][4];
#pragma unroll
  for (int i = 0; i < 4; ++i)
#pragma unroll
    for (int j = 0; j < 4; ++j)
#pragma unroll
      for (int e = 0; e < 4; ++e) acc[i][j][e] = 0.f;

  auto STAGE = [&](int buf, int kk0) {
    {
      const int r = t >> 2, cc = t & 3;
      const int kk = (cc ^ ((r >> 1) & 3)) * 8;
      gload_lds16(A + (size_t)(m0 + r) * Kf + kk0 + kk, (char*)As + buf * 8192 + t * 16);
    }
#pragma unroll
    for (int i = 0; i < 2; ++i) {
      const int c = t + 512 * i;
      const int r = c >> 2, cc = c & 3;
      const int kk = (cc ^ ((r >> 1) & 3)) * 8;
      gload_lds16(Bt + (size_t)(n0 + r) * Kf + kk0 + kk, (char*)Bs + buf * 16384 + c * 16);
    }
  };

  STAGE(0, kBase);
  int buf = 0;
  for (int k0 = kBase; k0 < kEnd; k0 += 32) {
    const int knext = (k0 + 32 < kEnd) ? k0 + 32 : k0;
    STAGE(buf ^ 1, knext);
    asm volatile("s_waitcnt vmcnt(3)" ::: "memory");
    __builtin_amdgcn_s_barrier();
    asm volatile("" ::: "memory");

    bf16x8 af[4], bfr[4];
#pragma unroll
    for (int fm = 0; fm < 4; ++fm) {
      const int r = wm * 64 + fm * 16 + l15;
      const int kc = lg ^ ((r >> 1) & 3);
      af[fm] = *(const bf16x8*)&As[buf][r * 32 + kc * 8];
    }
#pragma unroll
    for (int fn = 0; fn < 4; ++fn) {
      const int r = wn * 64 + fn * 16 + l15;
      const int kc = lg ^ ((r >> 1) & 3);
      bfr[fn] = *(const bf16x8*)&Bs[buf][r * 32 + kc * 8];
    }
#pragma unroll
    for (int fm = 0; fm < 4; ++fm)
#pragma unroll
      for (int fn = 0; fn < 4; ++fn)
        acc[fm][fn] = __builtin_amdgcn_mfma_f32_16x16x32_bf16(af[fm], bfr[fn], acc[fm][fn], 0, 0, 0);

    asm volatile("" ::: "memory");
    __builtin_amdgcn_s_barrier();
    buf ^= 1;
  }

  // epilogue: C row = (lg*4 + rg), col = l15 within each 16x16 fragment
#pragma unroll
  for (int fm = 0; fm < 4; ++fm) {
    const int mbase = m0 + wm * 64 + fm * 16 + lg * 4;
#pragma unroll
    for (int fn = 0; fn < 4; ++fn) {
      const int n = n0 + wn * 64 + fn * 16 + l15;
      if (EPI == 0) {
        const int seg = n >> 10;
        const int cn = n & 1023;
        const int h = cn >> 6, d = cn & 63;
        const float* bp = (seg == 0) ? bq : (seg == 1) ? bk : bv;
        const float bias_v = bp[cn];
#pragma unroll
        for (int rg = 0; rg < 4; ++rg) {
          const int m = mbase + rg;
          const int b = m >> 11, tt = m & 2047;
          const size_t bh = (size_t)(b * 16 + h);
          const float val = acc[fm][fn][rg] + bias_v;
          if (seg == 0)      oq[(bh * 2048 + tt) * 64 + d] = __float2bfloat16(val);
          else if (seg == 1) ok[(bh * 2048 + tt) * 64 + d] = __float2bfloat16(val);
          else               ovt[(bh * 64 + d) * 2048 + tt] = __float2bfloat16(val);
        }
      } else if (EPI == 1) {
        const float bias_v = bias[n];
#pragma unroll
        for (int rg = 0; rg < 4; ++rg) {
          const int m = mbase + rg;
          float val = acc[fm][fn][rg] + bias_v;
          val = fmaxf(val, 0.f);
          obf[(size_t)m * N + n] = __float2bfloat16(val);
        }
      } else {
        float* op = (blockIdx.z == 0) ? opart0 : (blockIdx.z == 1) ? opart1 : opart2;
#pragma unroll
        for (int rg = 0; rg < 4; ++rg) {
          const int m = mbase + rg;
          op[(size_t)m * 1024 + n] = acc[fm][fn][rg];
        }
      }
    }
  }
}

// -------------------- FFN2 merge: out = z + b2 + p0 + p1 + p2 --------------------
__global__ void ffn2_merge(const float* __restrict__ p0, const float* __restrict__ p1,
                           const float* __restrict__ p2,
                           const float* __restrict__ z, const float* __restrict__ b2,
                           float* __restrict__ out)
{
  const size_t i = ((size_t)blockIdx.x * 256 + threadIdx.x) * 4;
  const float4 a = *(const float4*)(p0 + i);
  const float4 b = *(const float4*)(p1 + i);
  const float4 d = *(const float4*)(p2 + i);
  const float4 c = *(const float4*)(z + i);
  const float4 bb = *(const float4*)(b2 + (i & 1023));
  float4 o;
  o.x = c.x + bb.x + a.x + b.x + d.x;
  o.y = c.y + bb.y + a.y + b.y + d.y;
  o.z = c.z + bb.z + a.z + b.z + d.z;
  o.w = c.w + bb.w + a.w + b.w + d.w;
  *(float4*)(out + i) = o;
}

// ---------- flash attention v7b: in-register P via ext-vector (no scratch) -----------
// R15's lane-permutation was CORRECT (absmax passed) but spilled to scratch via an
// address-taken local array (VGPR 48, WRITE 259MB). Fix: build fragment in an
// ext_vector uint4 with static component writes + bit_cast. LDS 32KB => 5 blocks/CU.
__global__ __launch_bounds__(256, 5) void flash_attn(
    const __hip_bfloat16* __restrict__ Q, const __hip_bfloat16* __restrict__ Kb,
    const __hip_bfloat16* __restrict__ Vt,
    __hip_bfloat16* __restrict__ Opart, float* __restrict__ Lpart)
{
  __shared__ short Ks[2][64 * 64];
  __shared__ short Vs[2][64 * 64];
  const int t = threadIdx.x;
  const int lane = t & 63, w = t >> 6;
  const int l15 = lane & 15, lg = lane >> 4;
  const int chunk = blockIdx.x, qblk = blockIdx.y, bh = blockIdx.z;
  const int q0 = qblk * 128;
  const int s_base = chunk * 512;
  if (s_base > q0 + 127) return;
  const int s_hi = (s_base + 512 < q0 + 128) ? s_base + 512 : q0 + 128;
  const int ntiles = (s_hi - s_base) >> 6;
  const int qw = q0 + w * 32;

  const __hip_bfloat16* Qbh = Q + (size_t)bh * 2048 * 64;
  const __hip_bfloat16* Kbh = Kb + (size_t)bh * 2048 * 64;
  const __hip_bfloat16* Vbh = Vt + (size_t)bh * 64 * 2048;

  bf16x8 qf[2][2];
#pragma unroll
  for (int fm = 0; fm < 2; ++fm)
#pragma unroll
    for (int kc = 0; kc < 2; ++kc)
      qf[fm][kc] = *(const bf16x8*)(Qbh + (size_t)(qw + fm * 16 + l15) * 64 + kc * 32 + lg * 8);

  const int srow = (w << 4) + (lane >> 3);
  const int schunk = ((lane & 7) ^ (lane >> 3)) * 8;

  auto STAGE = [&](int bufi, int s0) {
#pragma unroll
    for (int i = 0; i < 2; ++i) {
      const int r = srow + i * 8;
      const int dst = bufi * 8192 + w * 2048 + i * 1024 + lane * 16;
      gload_lds16(Kbh + (size_t)(s0 + r) * 64 + schunk, (char*)Ks + dst);
      gload_lds16(Vbh + (size_t)r * 2048 + s0 + schunk, (char*)Vs + dst);
    }
  };

  f32x4 o_acc[2][4];
  float lpart[2] = {0.f, 0.f};
#pragma unroll
  for (int fm = 0; fm < 2; ++fm)
#pragma unroll
    for (int fd = 0; fd < 4; ++fd)
#pragma unroll
      for (int e = 0; e < 4; ++e) o_acc[fm][fd][e] = 0.f;

  const float C = 0.18033688011112042f;   // 0.125 * log2(e)
  // P permutation source lanes: dest lane (lg,l15) pulls u32s from lanes
  // ((lg&1)*2)*16 + l15 and ((lg&1)*2+1)*16 + l15; fragment select by lg>=2.
  const int srcA = ((lg & 1) * 2) * 16 + l15;
  const int srcB = srcA + 16;
  const bool hiSel = (lg >= 2);

  STAGE(0, s_base);
  int cur = 0;
  for (int ti = 0; ti < ntiles; ++ti) {
    const int s0 = s_base + ti * 64;
    const int nxt = (ti + 1 < ntiles) ? s0 + 64 : s0;
    STAGE(cur ^ 1, nxt);
    asm volatile("s_waitcnt vmcnt(4)" ::: "memory");
    __builtin_amdgcn_s_barrier();
    asm volatile("" ::: "memory");

    if (s0 <= qw + 31) {
      // ---- S^T = K Q^T ----
      f32x4 s_acc[2][4];
#pragma unroll
      for (int fm = 0; fm < 2; ++fm)
#pragma unroll
        for (int fn = 0; fn < 4; ++fn)
#pragma unroll
          for (int e = 0; e < 4; ++e) s_acc[fm][fn][e] = 0.f;
#pragma unroll
      for (int kc = 0; kc < 2; ++kc)
#pragma unroll
        for (int fn = 0; fn < 4; ++fn) {
          const int r = fn * 16 + l15;
          bf16x8 kf = *(const bf16x8*)&Ks[cur][r * 64 + ((((kc << 2) | lg) ^ (l15 & 7)) << 3)];
          s_acc[0][fn] = __builtin_amdgcn_mfma_f32_16x16x32_bf16(kf, qf[0][kc], s_acc[0][fn], 0, 0, 0);
          s_acc[1][fn] = __builtin_amdgcn_mfma_f32_16x16x32_bf16(kf, qf[1][kc], s_acc[1][fn], 0, 0, 0);
        }

      // ---- fixed-base softmax -> packed bf16 pairs u[fm][fn] ----
      const bool needmask = (s0 + 63 > qw);
      uint2v u[2][4];
#pragma unroll
      for (int fm = 0; fm < 2; ++fm) {
        const int qv = qw + fm * 16 + l15;
#pragma unroll
        for (int fn = 0; fn < 4; ++fn) {
          float p[4];
#pragma unroll
          for (int rg = 0; rg < 4; ++rg) {
            float pv = exp2_fast(s_acc[fm][fn][rg] * C);
            if (needmask) {
              const int sg = s0 + fn * 16 + lg * 4 + rg;
              pv = (sg <= qv) ? pv : 0.f;
            }
            p[rg] = pv;
            lpart[fm] += pv;
          }
          u[fm][fn].x = cvt_pk_bf16(p[0], p[1]);
          u[fm][fn].y = cvt_pk_bf16(p[2], p[3]);
        }
      }

      // ---- C-layout -> B-fragment via lane permutation, ext-vector build ----
      bf16x8 pf[2][2];
#pragma unroll
      for (int fm = 0; fm < 2; ++fm)
#pragma unroll
        for (int kc = 0; kc < 2; ++kc) {
          const unsigned int ax = u[fm][2 * kc].x,  ay = u[fm][2 * kc].y;
          const unsigned int bx = u[fm][2 * kc + 1].x, by = u[fm][2 * kc + 1].y;
          const unsigned int r0a = (unsigned int)__shfl((int)ax, srcA);
          const unsigned int r0b = (unsigned int)__shfl((int)bx, srcA);
          const unsigned int r1a = (unsigned int)__shfl((int)ay, srcA);
          const unsigned int r1b = (unsigned int)__shfl((int)by, srcA);
          const unsigned int r2a = (unsigned int)__shfl((int)ax, srcB);
          const unsigned int r2b = (unsigned int)__shfl((int)bx, srcB);
          const unsigned int r3a = (unsigned int)__shfl((int)ay, srcB);
          const unsigned int r3b = (unsigned int)__shfl((int)by, srcB);
          uint4v rv;
          rv.x = hiSel ? r0b : r0a;
          rv.y = hiSel ? r1b : r1a;
          rv.z = hiSel ? r2b : r2a;
          rv.w = hiSel ? r3b : r3a;
          pf[fm][kc] = __builtin_bit_cast(bf16x8, rv);
        }

      // ---- O^T += V^T P^T ----
#pragma unroll
      for (int kc = 0; kc < 2; ++kc)
#pragma unroll
        for (int fd = 0; fd < 4; ++fd) {
          const int r = fd * 16 + l15;
          bf16x8 vf = *(const bf16x8*)&Vs[cur][r * 64 + ((((kc << 2) | lg) ^ (l15 & 7)) << 3)];
          o_acc[0][fd] = __builtin_amdgcn_mfma_f32_16x16x32_bf16(vf, pf[0][kc], o_acc[0][fd], 0, 0, 0);
          o_acc[1][fd] = __builtin_amdgcn_mfma_f32_16x16x32_bf16(vf, pf[1][kc], o_acc[1][fd], 0, 0, 0);
        }
    }

    asm volatile("" ::: "memory");
    __builtin_amdgcn_s_barrier();
    cur ^= 1;
  }

  const int pslot = ((bh * 16 + qblk) << 2) + chunk;
  __hip_bfloat16* op = Opart + (size_t)pslot * 8192;
#pragma unroll
  for (int fm = 0; fm < 2; ++fm) {
    float l = lpart[fm];
    l += __shfl_xor(l, 16);
    l += __shfl_xor(l, 32);
    const int qloc = w * 32 + fm * 16 + l15;
    if (lg == 0) Lpart[pslot * 128 + qloc] = l;
#pragma unroll
    for (int fd = 0; fd < 4; ++fd) {
      uint2v uo;
      uo.x = cvt_pk_bf16(o_acc[fm][fd][0], o_acc[fm][fd][1]);
      uo.y = cvt_pk_bf16(o_acc[fm][fd][2], o_acc[fm][fd][3]);
      *(uint2v*)(op + (size_t)qloc * 64 + fd * 16 + lg * 4) = uo;
    }
  }
}

// -------------------- launch --------------------
extern "C" void kernel_launch(void* const* d_in, const int* in_sizes, int n_in,
                              void* d_out, int out_size, void* d_ws, size_t ws_size,
                              hipStream_t stream) {
  const float* x    = (const float*)d_in[0];
  const float* wq   = (const float*)d_in[1];
  const float* bq   = (const float*)d_in[2];
  const float* wk   = (const float*)d_in[3];
  const float* bk   = (const float*)d_in[4];
  const float* wv   = (const float*)d_in[5];
  const float* bv   = (const float*)d_in[6];
  const float* ln1g = (const float*)d_in[7];
  const float* ln1b = (const float*)d_in[8];
  const float* ln2g = (const float*)d_in[9];
  const float* ln2b = (const float*)d_in[10];
  const float* w1   = (const float*)d_in[11];
  const float* b1   = (const float*)d_in[12];
  const float* w2   = (const float*)d_in[13];
  const float* b2   = (const float*)d_in[14];
  float* out = (float*)d_out;

  char* ws = (char*)d_ws;
  const size_t MB = 1024 * 1024;
  __hip_bfloat16* h_bf  = (__hip_bfloat16*)(ws + 0);
  float* z_f32          = (float*)(ws + 0);
  __hip_bfloat16* qb    = (__hip_bfloat16*)(ws + 8 * MB);
  __hip_bfloat16* kb    = (__hip_bfloat16*)(ws + 16 * MB);
  __hip_bfloat16* z_bf  = (__hip_bfloat16*)(ws + 16 * MB);
  __hip_bfloat16* vtb   = (__hip_bfloat16*)(ws + 24 * MB);
  __hip_bfloat16* ff1   = (__hip_bfloat16*)(ws + 24 * MB);
  float* h_f32          = (float*)(ws + 32 * MB);
  __hip_bfloat16* Opart = (__hip_bfloat16*)(ws + 48 * MB);
  float* p0             = (float*)(ws + 56 * MB);
  float* p1             = (float*)(ws + 72 * MB);
  float* Lpart          = (float*)(ws + 80 * MB);
  __hip_bfloat16* wqkvT = (__hip_bfloat16*)(ws + 88 * MB);
  float* p2             = (float*)(ws + 88 * MB);
  __hip_bfloat16* w1T   = (__hip_bfloat16*)(ws + 96 * MB);
  __hip_bfloat16* w2T   = (__hip_bfloat16*)(ws + 104 * MB);

  transpose_pack<<<dim3(1, 16, 16), 256, 0, stream>>>(wq, wqkvT + 0 * 1024 * 1024, 1024, 64, 1024, 65536, 64);
  transpose_pack<<<dim3(1, 16, 16), 256, 0, stream>>>(wk, wqkvT + 1 * 1024 * 1024, 1024, 64, 1024, 65536, 64);
  transpose_pack<<<dim3(1, 16, 16), 256, 0, stream>>>(wv, wqkvT + 2 * 1024 * 1024, 1024, 64, 1024, 65536, 64);
  transpose_pack<<<dim3(64, 16, 1), 256, 0, stream>>>(w1, w1T, 1024, 4096, 1024, 0, 0);
  transpose_pack<<<dim3(16, 64, 1), 256, 0, stream>>>(w2, w2T, 4096, 1024, 4096, 0, 0);

  ln_fused<<<4096, 256, 0, stream>>>(x, ln1g, ln1b, h_f32, h_bf);

  // QKV projection: M=4096, N=3072, K=1024  (grid 12*32=384, %8==0)
  gemm_bt<0><<<dim3(12, 32), 512, 0, stream>>>(h_bf, wqkvT, 3072, 1024, 1024,
      nullptr, bq, bk, bv, qb, kb, vtb, nullptr, nullptr, nullptr, nullptr);

  flash_attn<<<dim3(4, 16, 32), 256, 0, stream>>>(qb, kb, vtb, Opart, Lpart);

  // LN2 + KV-split merge fused: z = LN(h + sum(O)/sum(l))
  ln2_merge_fused<<<4096, 256, 0, stream>>>(h_f32, Opart, Lpart, ln2g, ln2b, z_f32, z_bf);

  // FFN1: relu(z @ w1 + b1), M=4096, N=4096, K=1024  (grid 16*32=512, %8==0)
  gemm_bt<1><<<dim3(16, 32), 512, 0, stream>>>(z_bf, w1T, 4096, 1024, 1024,
      b1, nullptr, nullptr, nullptr, nullptr, nullptr, nullptr, ff1, nullptr, nullptr, nullptr);

  // FFN2 split-K=3 (1376/1376/1344), f32 partials: M=4096, N=1024, K=4096 (4*32=128 %8==0)
  gemm_bt<2><<<dim3(4, 32, 3), 512, 0, stream>>>(ff1, w2T, 1024, 4096, 1376,
      nullptr, nullptr, nullptr, nullptr, nullptr, nullptr, nullptr, nullptr, p0, p1, p2);

  // out = z + b2 + p0 + p1 + p2
  ffn2_merge<<<4096, 256, 0, stream>>>(p0, p1, p2, z_f32, b2, out);
}

// Round 17
// 243.949 us; speedup vs baseline: 1.3516x; 1.3516x over previous
//
#include <hip/hip_runtime.h>
#include <hip/hip_bf16.h>
#include <cstdint>
#include <cstddef>

typedef __attribute__((ext_vector_type(8))) short bf16x8;
typedef __attribute__((ext_vector_type(4))) float f32x4;
typedef __attribute__((ext_vector_type(4))) short short4v;
typedef __attribute__((ext_vector_type(2))) unsigned int uint2v;
typedef __attribute__((ext_vector_type(4))) unsigned int uint4v;

__device__ inline void gload_lds16(const void* g, void* l) {
  __builtin_amdgcn_global_load_lds((const __attribute__((address_space(1))) void*)g,
                                   (__attribute__((address_space(3))) void*)l, 16, 0, 0);
}

__device__ inline float exp2_fast(float x) {
  float r;
  asm volatile("v_exp_f32 %0, %1" : "=v"(r) : "v"(x));
  return r;
}

__device__ inline unsigned int cvt_pk_bf16(float lo, float hi) {
  unsigned int r;
  asm volatile("v_cvt_pk_bf16_f32 %0, %1, %2" : "=v"(r) : "v"(lo), "v"(hi));
  return r;
}

__device__ inline float bf2f(short s) {
  return __uint_as_float(((unsigned int)(unsigned short)s) << 16);
}

// -------------------- transpose fp32 [R][C] -> bf16 [C][R] --------------------
__global__ void transpose_pack(const float* __restrict__ src, __hip_bfloat16* __restrict__ dst,
                               int R, int C, int ldDst, long zSrcStride, int zDstRow)
{
  __shared__ float tile[64][65];
  src += (size_t)blockIdx.z * zSrcStride;
  const int r0 = blockIdx.y * 64, c0 = blockIdx.x * 64;
  const int t = threadIdx.x;
#pragma unroll
  for (int i = 0; i < 16; ++i) {
    int idx = i * 256 + t;
    int r = idx >> 6, c = idx & 63;
    tile[r][c] = src[(size_t)(r0 + r) * C + c0 + c];
  }
  __syncthreads();
  const int drow0 = blockIdx.z * zDstRow + c0;
#pragma unroll
  for (int i = 0; i < 16; ++i) {
    int idx = i * 256 + t;
    int cc = idx >> 6, rr = idx & 63;
    dst[(size_t)(drow0 + cc) * ldDst + r0 + rr] = __float2bfloat16(tile[rr][cc]);
  }
}

// -------------------- LN1: LayerNorm(x) -> f32 + bf16 --------------------
__global__ void ln_fused(const float* __restrict__ x,
                         const float* __restrict__ g, const float* __restrict__ bta,
                         float* __restrict__ of32, __hip_bfloat16* __restrict__ obf)
{
  const int row = blockIdx.x;
  const int t = threadIdx.x;
  float4 v = ((const float4*)(x + (size_t)row * 1024))[t];
  float s = v.x + v.y + v.z + v.w;
  float ss = v.x * v.x + v.y * v.y + v.z * v.z + v.w * v.w;
#pragma unroll
  for (int off = 1; off < 64; off <<= 1) {
    s += __shfl_xor(s, off);
    ss += __shfl_xor(ss, off);
  }
  __shared__ float sb[4], ssb[4];
  const int w = t >> 6, lane = t & 63;
  if (lane == 0) { sb[w] = s; ssb[w] = ss; }
  __syncthreads();
  s = sb[0] + sb[1] + sb[2] + sb[3];
  ss = ssb[0] + ssb[1] + ssb[2] + ssb[3];
  const float mu = s * (1.f / 1024.f);
  const float var = ss * (1.f / 1024.f) - mu * mu;
  const float rstd = rsqrtf(var + 1e-5f);
  float4 gv = ((const float4*)g)[t];
  float4 bv = ((const float4*)bta)[t];
  float4 o;
  o.x = (v.x - mu) * rstd * gv.x + bv.x;
  o.y = (v.y - mu) * rstd * gv.y + bv.y;
  o.z = (v.z - mu) * rstd * gv.z + bv.z;
  o.w = (v.w - mu) * rstd * gv.w + bv.w;
  ((float4*)(of32 + (size_t)row * 1024))[t] = o;
  __hip_bfloat16 hb[4] = { __float2bfloat16(o.x), __float2bfloat16(o.y),
                           __float2bfloat16(o.z), __float2bfloat16(o.w) };
  *(short4v*)(obf + (size_t)row * 1024 + t * 4) = *(const short4v*)hb;
}

// ---------- LN2 fused with KV-split merge: y = h + sum(O)/sum(l); z = LN(y) ----------
__global__ void ln2_merge_fused(const float* __restrict__ hres,
                                const __hip_bfloat16* __restrict__ Opart,
                                const float* __restrict__ Lpart,
                                const float* __restrict__ g, const float* __restrict__ bta,
                                float* __restrict__ of32, __hip_bfloat16* __restrict__ obf)
{
  const int row = blockIdx.x;            // b*2048 + t
  const int b = row >> 11, tt = row & 2047;
  const int qblk = tt >> 7, qloc = tt & 127;
  const int nch = (qblk >> 2) + 1;
  const int t = threadIdx.x;
  const int hd = t >> 4;                 // head (4 cols per thread, within one head)
  const int d0 = (t & 15) * 4;
  const int base = ((b * 16 + hd) * 16 + qblk) << 2;

  float4 v = ((const float4*)(hres + (size_t)row * 1024))[t];
  float l = 0.f;
  float o0 = 0.f, o1 = 0.f, o2 = 0.f, o3 = 0.f;
  for (int ch = 0; ch < nch; ++ch) {     // nch uniform per block (row)
    l += Lpart[(size_t)(base + ch) * 128 + qloc];
    short4v o4 = *(const short4v*)(Opart + (size_t)(base + ch) * 8192 + qloc * 64 + d0);
    o0 += bf2f(o4[0]); o1 += bf2f(o4[1]); o2 += bf2f(o4[2]); o3 += bf2f(o4[3]);
  }
  const float inv = 1.f / l;
  v.x += o0 * inv; v.y += o1 * inv; v.z += o2 * inv; v.w += o3 * inv;

  float s = v.x + v.y + v.z + v.w;
  float ss = v.x * v.x + v.y * v.y + v.z * v.z + v.w * v.w;
#pragma unroll
  for (int off = 1; off < 64; off <<= 1) {
    s += __shfl_xor(s, off);
    ss += __shfl_xor(ss, off);
  }
  __shared__ float sb[4], ssb[4];
  const int w = t >> 6, lane = t & 63;
  if (lane == 0) { sb[w] = s; ssb[w] = ss; }
  __syncthreads();
  s = sb[0] + sb[1] + sb[2] + sb[3];
  ss = ssb[0] + ssb[1] + ssb[2] + ssb[3];
  const float mu = s * (1.f / 1024.f);
  const float var = ss * (1.f / 1024.f) - mu * mu;
  const float rstd = rsqrtf(var + 1e-5f);
  float4 gv = ((const float4*)g)[t];
  float4 bv = ((const float4*)bta)[t];
  float4 o;
  o.x = (v.x - mu) * rstd * gv.x + bv.x;
  o.y = (v.y - mu) * rstd * gv.y + bv.y;
  o.z = (v.z - mu) * rstd * gv.z + bv.z;
  o.w = (v.w - mu) * rstd * gv.w + bv.w;
  ((float4*)(of32 + (size_t)row * 1024))[t] = o;
  __hip_bfloat16 hb[4] = { __float2bfloat16(o.x), __float2bfloat16(o.y),
                           __float2bfloat16(o.z), __float2bfloat16(o.w) };
  *(short4v*)(obf + (size_t)row * 1024 + t * 4) = *(const short4v*)hb;
}

// -------------------- GEMM (R14 green): 8 waves, BM=128 BN=256 BK=32 ------------------
// 2-deep dbuf + vmcnt(3), + T1 XCD-aware chunked blockIdx swizzle.
template<int EPI>
__global__ __launch_bounds__(512, 2) void gemm_bt(
    const __hip_bfloat16* __restrict__ A, const __hip_bfloat16* __restrict__ Bt,
    int N, int Kf, int kLen,
    const float* __restrict__ bias,
    const float* __restrict__ bq, const float* __restrict__ bk, const float* __restrict__ bv,
    __hip_bfloat16* __restrict__ oq, __hip_bfloat16* __restrict__ ok, __hip_bfloat16* __restrict__ ovt,
    __hip_bfloat16* __restrict__ obf,
    float* __restrict__ opart0, float* __restrict__ opart1, float* __restrict__ opart2)
{
  __shared__ short As[2][128 * 32];   //  8 KB per buf
  __shared__ short Bs[2][256 * 32];   // 16 KB per buf
  const int t = threadIdx.x;
  const int lane = t & 63;
  const int w = t >> 6;               // 0..7
  const int wm = w >> 2, wn = w & 3;  // 2 x 4 wave grid
  const int l15 = lane & 15, lg = lane >> 4;

  const int nwg = (int)(gridDim.x * gridDim.y);
  int wgid = (int)blockIdx.y * (int)gridDim.x + (int)blockIdx.x;
  wgid = (wgid & 7) * (nwg >> 3) + (wgid >> 3);
  const int bx = wgid % (int)gridDim.x;
  const int by = wgid / (int)gridDim.x;
  const int m0 = by * 128;
  const int n0 = bx * 256;
  const int kBase = (EPI == 2) ? (int)blockIdx.z * kLen : 0;
  const int kEnd0 = kBase + kLen;
  const int kEnd = (kEnd0 > Kf) ? Kf : kEnd0;

  f32x4 acc[4][4];
#pragma unroll
  for (int i = 0; i < 4; ++i)
#pragma unroll
    for (int j = 0; j < 4; ++j)
#pragma unroll
      for (int e = 0; e < 4; ++e) acc[i][j][e] = 0.f;

  auto STAGE = [&](int buf, int kk0) {
    {
      const int r = t >> 2, cc = t & 3;
      const int kk = (cc ^ ((r >> 1) & 3)) * 8;
      gload_lds16(A + (size_t)(m0 + r) * Kf + kk0 + kk, (char*)As + buf * 8192 + t * 16);
    }
#pragma unroll
    for (int i = 0; i < 2; ++i) {
      const int c = t + 512 * i;
      const int r = c >> 2, cc = c & 3;
      const int kk = (cc ^ ((r >> 1) & 3)) * 8;
      gload_lds16(Bt + (size_t)(n0 + r) * Kf + kk0 + kk, (char*)Bs + buf * 16384 + c * 16);
    }
  };

  STAGE(0, kBase);
  int buf = 0;
  for (int k0 = kBase; k0 < kEnd; k0 += 32) {
    const int knext = (k0 + 32 < kEnd) ? k0 + 32 : k0;
    STAGE(buf ^ 1, knext);
    asm volatile("s_waitcnt vmcnt(3)" ::: "memory");
    __builtin_amdgcn_s_barrier();
    asm volatile("" ::: "memory");

    bf16x8 af[4], bfr[4];
#pragma unroll
    for (int fm = 0; fm < 4; ++fm) {
      const int r = wm * 64 + fm * 16 + l15;
      const int kc = lg ^ ((r >> 1) & 3);
      af[fm] = *(const bf16x8*)&As[buf][r * 32 + kc * 8];
    }
#pragma unroll
    for (int fn = 0; fn < 4; ++fn) {
      const int r = wn * 64 + fn * 16 + l15;
      const int kc = lg ^ ((r >> 1) & 3);
      bfr[fn] = *(const bf16x8*)&Bs[buf][r * 32 + kc * 8];
    }
#pragma unroll
    for (int fm = 0; fm < 4; ++fm)
#pragma unroll
      for (int fn = 0; fn < 4; ++fn)
        acc[fm][fn] = __builtin_amdgcn_mfma_f32_16x16x32_bf16(af[fm], bfr[fn], acc[fm][fn], 0, 0, 0);

    asm volatile("" ::: "memory");
    __builtin_amdgcn_s_barrier();
    buf ^= 1;
  }

  // epilogue: C row = (lg*4 + rg), col = l15 within each 16x16 fragment
#pragma unroll
  for (int fm = 0; fm < 4; ++fm) {
    const int mbase = m0 + wm * 64 + fm * 16 + lg * 4;
#pragma unroll
    for (int fn = 0; fn < 4; ++fn) {
      const int n = n0 + wn * 64 + fn * 16 + l15;
      if (EPI == 0) {
        const int seg = n >> 10;
        const int cn = n & 1023;
        const int h = cn >> 6, d = cn & 63;
        const float* bp = (seg == 0) ? bq : (seg == 1) ? bk : bv;
        const float bias_v = bp[cn];
#pragma unroll
        for (int rg = 0; rg < 4; ++rg) {
          const int m = mbase + rg;
          const int b = m >> 11, tt = m & 2047;
          const size_t bh = (size_t)(b * 16 + h);
          const float val = acc[fm][fn][rg] + bias_v;
          if (seg == 0)      oq[(bh * 2048 + tt) * 64 + d] = __float2bfloat16(val);
          else if (seg == 1) ok[(bh * 2048 + tt) * 64 + d] = __float2bfloat16(val);
          else               ovt[(bh * 64 + d) * 2048 + tt] = __float2bfloat16(val);
        }
      } else if (EPI == 1) {
        const float bias_v = bias[n];
#pragma unroll
        for (int rg = 0; rg < 4; ++rg) {
          const int m = mbase + rg;
          float val = acc[fm][fn][rg] + bias_v;
          val = fmaxf(val, 0.f);
          obf[(size_t)m * N + n] = __float2bfloat16(val);
        }
      } else {
        float* op = (blockIdx.z == 0) ? opart0 : (blockIdx.z == 1) ? opart1 : opart2;
#pragma unroll
        for (int rg = 0; rg < 4; ++rg) {
          const int m = mbase + rg;
          op[(size_t)m * 1024 + n] = acc[fm][fn][rg];
        }
      }
    }
  }
}

// -------------------- FFN2 merge: out = z + b2 + p0 + p1 + p2 --------------------
__global__ void ffn2_merge(const float* __restrict__ p0, const float* __restrict__ p1,
                           const float* __restrict__ p2,
                           const float* __restrict__ z, const float* __restrict__ b2,
                           float* __restrict__ out)
{
  const size_t i = ((size_t)blockIdx.x * 256 + threadIdx.x) * 4;
  const float4 a = *(const float4*)(p0 + i);
  const float4 b = *(const float4*)(p1 + i);
  const float4 d = *(const float4*)(p2 + i);
  const float4 c = *(const float4*)(z + i);
  const float4 bb = *(const float4*)(b2 + (i & 1023));
  float4 o;
  o.x = c.x + bb.x + a.x + b.x + d.x;
  o.y = c.y + bb.y + a.y + b.y + d.y;
  o.z = c.z + bb.z + a.z + b.z + d.z;
  o.w = c.w + bb.w + a.w + b.w + d.w;
  *(float4*)(out + i) = o;
}

// ---------- flash attention v7c: in-register P, launch_bounds relaxed to 3 -----------
// R15/R16 spilled because __launch_bounds__(256,5) capped the allocator below the
// ~120-VGPR working set (VGPR_Count 48, WRITE 259MB scratch traffic). With bounds=3
// the cap is ~170: no spill; occupancy is then LDS(32KB->5)/VGPR(~112->4) limited,
// i.e. 4 blocks/CU vs 3 for the P2-LDS version, with a shorter per-tile chain.
__global__ __launch_bounds__(256, 3) void flash_attn(
    const __hip_bfloat16* __restrict__ Q, const __hip_bfloat16* __restrict__ Kb,
    const __hip_bfloat16* __restrict__ Vt,
    __hip_bfloat16* __restrict__ Opart, float* __restrict__ Lpart)
{
  __shared__ short Ks[2][64 * 64];
  __shared__ short Vs[2][64 * 64];
  const int t = threadIdx.x;
  const int lane = t & 63, w = t >> 6;
  const int l15 = lane & 15, lg = lane >> 4;
  const int chunk = blockIdx.x, qblk = blockIdx.y, bh = blockIdx.z;
  const int q0 = qblk * 128;
  const int s_base = chunk * 512;
  if (s_base > q0 + 127) return;
  const int s_hi = (s_base + 512 < q0 + 128) ? s_base + 512 : q0 + 128;
  const int ntiles = (s_hi - s_base) >> 6;
  const int qw = q0 + w * 32;

  const __hip_bfloat16* Qbh = Q + (size_t)bh * 2048 * 64;
  const __hip_bfloat16* Kbh = Kb + (size_t)bh * 2048 * 64;
  const __hip_bfloat16* Vbh = Vt + (size_t)bh * 64 * 2048;

  bf16x8 qf[2][2];
#pragma unroll
  for (int fm = 0; fm < 2; ++fm)
#pragma unroll
    for (int kc = 0; kc < 2; ++kc)
      qf[fm][kc] = *(const bf16x8*)(Qbh + (size_t)(qw + fm * 16 + l15) * 64 + kc * 32 + lg * 8);

  const int srow = (w << 4) + (lane >> 3);
  const int schunk = ((lane & 7) ^ (lane >> 3)) * 8;

  auto STAGE = [&](int bufi, int s0) {
#pragma unroll
    for (int i = 0; i < 2; ++i) {
      const int r = srow + i * 8;
      const int dst = bufi * 8192 + w * 2048 + i * 1024 + lane * 16;
      gload_lds16(Kbh + (size_t)(s0 + r) * 64 + schunk, (char*)Ks + dst);
      gload_lds16(Vbh + (size_t)r * 2048 + s0 + schunk, (char*)Vs + dst);
    }
  };

  f32x4 o_acc[2][4];
  float lpart[2] = {0.f, 0.f};
#pragma unroll
  for (int fm = 0; fm < 2; ++fm)
#pragma unroll
    for (int fd = 0; fd < 4; ++fd)
#pragma unroll
      for (int e = 0; e < 4; ++e) o_acc[fm][fd][e] = 0.f;

  const float C = 0.18033688011112042f;   // 0.125 * log2(e)
  const int srcA = ((lg & 1) * 2) * 16 + l15;
  const int srcB = srcA + 16;
  const bool hiSel = (lg >= 2);

  STAGE(0, s_base);
  int cur = 0;
  for (int ti = 0; ti < ntiles; ++ti) {
    const int s0 = s_base + ti * 64;
    const int nxt = (ti + 1 < ntiles) ? s0 + 64 : s0;
    STAGE(cur ^ 1, nxt);
    asm volatile("s_waitcnt vmcnt(4)" ::: "memory");
    __builtin_amdgcn_s_barrier();
    asm volatile("" ::: "memory");

    if (s0 <= qw + 31) {
      // ---- S^T = K Q^T ----
      f32x4 s_acc[2][4];
#pragma unroll
      for (int fm = 0; fm < 2; ++fm)
#pragma unroll
        for (int fn = 0; fn < 4; ++fn)
#pragma unroll
          for (int e = 0; e < 4; ++e) s_acc[fm][fn][e] = 0.f;
#pragma unroll
      for (int kc = 0; kc < 2; ++kc)
#pragma unroll
        for (int fn = 0; fn < 4; ++fn) {
          const int r = fn * 16 + l15;
          bf16x8 kf = *(const bf16x8*)&Ks[cur][r * 64 + ((((kc << 2) | lg) ^ (l15 & 7)) << 3)];
          s_acc[0][fn] = __builtin_amdgcn_mfma_f32_16x16x32_bf16(kf, qf[0][kc], s_acc[0][fn], 0, 0, 0);
          s_acc[1][fn] = __builtin_amdgcn_mfma_f32_16x16x32_bf16(kf, qf[1][kc], s_acc[1][fn], 0, 0, 0);
        }

      // ---- fixed-base softmax -> packed bf16 pairs u[fm][fn] ----
      const bool needmask = (s0 + 63 > qw);
      uint2v u[2][4];
#pragma unroll
      for (int fm = 0; fm < 2; ++fm) {
        const int qv = qw + fm * 16 + l15;
#pragma unroll
        for (int fn = 0; fn < 4; ++fn) {
          float p[4];
#pragma unroll
          for (int rg = 0; rg < 4; ++rg) {
            float pv = exp2_fast(s_acc[fm][fn][rg] * C);
            if (needmask) {
              const int sg = s0 + fn * 16 + lg * 4 + rg;
              pv = (sg <= qv) ? pv : 0.f;
            }
            p[rg] = pv;
            lpart[fm] += pv;
          }
          u[fm][fn].x = cvt_pk_bf16(p[0], p[1]);
          u[fm][fn].y = cvt_pk_bf16(p[2], p[3]);
        }
      }

      // ---- C-layout -> B-fragment via lane permutation (register-only) ----
      bf16x8 pf[2][2];
#pragma unroll
      for (int fm = 0; fm < 2; ++fm)
#pragma unroll
        for (int kc = 0; kc < 2; ++kc) {
          const unsigned int ax = u[fm][2 * kc].x,  ay = u[fm][2 * kc].y;
          const unsigned int bx = u[fm][2 * kc + 1].x, by = u[fm][2 * kc + 1].y;
          const unsigned int r0a = (unsigned int)__shfl((int)ax, srcA);
          const unsigned int r0b = (unsigned int)__shfl((int)bx, srcA);
          const unsigned int r1a = (unsigned int)__shfl((int)ay, srcA);
          const unsigned int r1b = (unsigned int)__shfl((int)by, srcA);
          const unsigned int r2a = (unsigned int)__shfl((int)ax, srcB);
          const unsigned int r2b = (unsigned int)__shfl((int)bx, srcB);
          const unsigned int r3a = (unsigned int)__shfl((int)ay, srcB);
          const unsigned int r3b = (unsigned int)__shfl((int)by, srcB);
          uint4v rv;
          rv.x = hiSel ? r0b : r0a;
          rv.y = hiSel ? r1b : r1a;
          rv.z = hiSel ? r2b : r2a;
          rv.w = hiSel ? r3b : r3a;
          pf[fm][kc] = __builtin_bit_cast(bf16x8, rv);
        }

      // ---- O^T += V^T P^T ----
#pragma unroll
      for (int kc = 0; kc < 2; ++kc)
#pragma unroll
        for (int fd = 0; fd < 4; ++fd) {
          const int r = fd * 16 + l15;
          bf16x8 vf = *(const bf16x8*)&Vs[cur][r * 64 + ((((kc << 2) | lg) ^ (l15 & 7)) << 3)];
          o_acc[0][fd] = __builtin_amdgcn_mfma_f32_16x16x32_bf16(vf, pf[0][kc], o_acc[0][fd], 0, 0, 0);
          o_acc[1][fd] = __builtin_amdgcn_mfma_f32_16x16x32_bf16(vf, pf[1][kc], o_acc[1][fd], 0, 0, 0);
        }
    }

    asm volatile("" ::: "memory");
    __builtin_amdgcn_s_barrier();
    cur ^= 1;
  }

  const int pslot = ((bh * 16 + qblk) << 2) + chunk;
  __hip_bfloat16* op = Opart + (size_t)pslot * 8192;
#pragma unroll
  for (int fm = 0; fm < 2; ++fm) {
    float l = lpart[fm];
    l += __shfl_xor(l, 16);
    l += __shfl_xor(l, 32);
    const int qloc = w * 32 + fm * 16 + l15;
    if (lg == 0) Lpart[pslot * 128 + qloc] = l;
#pragma unroll
    for (int fd = 0; fd < 4; ++fd) {
      uint2v uo;
      uo.x = cvt_pk_bf16(o_acc[fm][fd][0], o_acc[fm][fd][1]);
      uo.y = cvt_pk_bf16(o_acc[fm][fd][2], o_acc[fm][fd][3]);
      *(uint2v*)(op + (size_t)qloc * 64 + fd * 16 + lg * 4) = uo;
    }
  }
}

// -------------------- launch --------------------
extern "C" void kernel_launch(void* const* d_in, const int* in_sizes, int n_in,
                              void* d_out, int out_size, void* d_ws, size_t ws_size,
                              hipStream_t stream) {
  const float* x    = (const float*)d_in[0];
  const float* wq   = (const float*)d_in[1];
  const float* bq   = (const float*)d_in[2];
  const float* wk   = (const float*)d_in[3];
  const float* bk   = (const float*)d_in[4];
  const float* wv   = (const float*)d_in[5];
  const float* bv   = (const float*)d_in[6];
  const float* ln1g = (const float*)d_in[7];
  const float* ln1b = (const float*)d_in[8];
  const float* ln2g = (const float*)d_in[9];
  const float* ln2b = (const float*)d_in[10];
  const float* w1   = (const float*)d_in[11];
  const float* b1   = (const float*)d_in[12];
  const float* w2   = (const float*)d_in[13];
  const float* b2   = (const float*)d_in[14];
  float* out = (float*)d_out;

  char* ws = (char*)d_ws;
  const size_t MB = 1024 * 1024;
  __hip_bfloat16* h_bf  = (__hip_bfloat16*)(ws + 0);
  float* z_f32          = (float*)(ws + 0);
  __hip_bfloat16* qb    = (__hip_bfloat16*)(ws + 8 * MB);
  __hip_bfloat16* kb    = (__hip_bfloat16*)(ws + 16 * MB);
  __hip_bfloat16* z_bf  = (__hip_bfloat16*)(ws + 16 * MB);
  __hip_bfloat16* vtb   = (__hip_bfloat16*)(ws + 24 * MB);
  __hip_bfloat16* ff1   = (__hip_bfloat16*)(ws + 24 * MB);
  float* h_f32          = (float*)(ws + 32 * MB);
  __hip_bfloat16* Opart = (__hip_bfloat16*)(ws + 48 * MB);
  float* p0             = (float*)(ws + 56 * MB);
  float* p1             = (float*)(ws + 72 * MB);
  float* Lpart          = (float*)(ws + 80 * MB);
  __hip_bfloat16* wqkvT = (__hip_bfloat16*)(ws + 88 * MB);
  float* p2             = (float*)(ws + 88 * MB);
  __hip_bfloat16* w1T   = (__hip_bfloat16*)(ws + 96 * MB);
  __hip_bfloat16* w2T   = (__hip_bfloat16*)(ws + 104 * MB);

  transpose_pack<<<dim3(1, 16, 16), 256, 0, stream>>>(wq, wqkvT + 0 * 1024 * 1024, 1024, 64, 1024, 65536, 64);
  transpose_pack<<<dim3(1, 16, 16), 256, 0, stream>>>(wk, wqkvT + 1 * 1024 * 1024, 1024, 64, 1024, 65536, 64);
  transpose_pack<<<dim3(1, 16, 16), 256, 0, stream>>>(wv, wqkvT + 2 * 1024 * 1024, 1024, 64, 1024, 65536, 64);
  transpose_pack<<<dim3(64, 16, 1), 256, 0, stream>>>(w1, w1T, 1024, 4096, 1024, 0, 0);
  transpose_pack<<<dim3(16, 64, 1), 256, 0, stream>>>(w2, w2T, 4096, 1024, 4096, 0, 0);

  ln_fused<<<4096, 256, 0, stream>>>(x, ln1g, ln1b, h_f32, h_bf);

  // QKV projection: M=4096, N=3072, K=1024  (grid 12*32=384, %8==0)
  gemm_bt<0><<<dim3(12, 32), 512, 0, stream>>>(h_bf, wqkvT, 3072, 1024, 1024,
      nullptr, bq, bk, bv, qb, kb, vtb, nullptr, nullptr, nullptr, nullptr);

  flash_attn<<<dim3(4, 16, 32), 256, 0, stream>>>(qb, kb, vtb, Opart, Lpart);

  // LN2 + KV-split merge fused: z = LN(h + sum(O)/sum(l))
  ln2_merge_fused<<<4096, 256, 0, stream>>>(h_f32, Opart, Lpart, ln2g, ln2b, z_f32, z_bf);

  // FFN1: relu(z @ w1 + b1), M=4096, N=4096, K=1024  (grid 16*32=512, %8==0)
  gemm_bt<1><<<dim3(16, 32), 512, 0, stream>>>(z_bf, w1T, 4096, 1024, 1024,
      b1, nullptr, nullptr, nullptr, nullptr, nullptr, nullptr, ff1, nullptr, nullptr, nullptr);

  // FFN2 split-K=3 (1376/1376/1344), f32 partials: M=4096, N=1024, K=4096 (4*32=128 %8==0)
  gemm_bt<2><<<dim3(4, 32, 3), 512, 0, stream>>>(ff1, w2T, 1024, 4096, 1376,
      nullptr, nullptr, nullptr, nullptr, nullptr, nullptr, nullptr, nullptr, p0, p1, p2);

  // out = z + b2 + p0 + p1 + p2
  ffn2_merge<<<4096, 256, 0, stream>>>(p0, p1, p2, z_f32, b2, out);
}

// Round 18
// 239.536 us; speedup vs baseline: 1.3765x; 1.0184x over previous
//
#include <hip/hip_runtime.h>
#include <hip/hip_bf16.h>
#include <cstdint>
#include <cstddef>

typedef __attribute__((ext_vector_type(8))) short bf16x8;
typedef __attribute__((ext_vector_type(4))) float f32x4;
typedef __attribute__((ext_vector_type(4))) short short4v;
typedef __attribute__((ext_vector_type(2))) unsigned int uint2v;

__device__ inline void gload_lds16(const void* g, void* l) {
  __builtin_amdgcn_global_load_lds((const __attribute__((address_space(1))) void*)g,
                                   (__attribute__((address_space(3))) void*)l, 16, 0, 0);
}

__device__ inline float exp2_fast(float x) {
  float r;
  asm volatile("v_exp_f32 %0, %1" : "=v"(r) : "v"(x));
  return r;
}

__device__ inline unsigned int cvt_pk_bf16(float lo, float hi) {
  unsigned int r;
  asm volatile("v_cvt_pk_bf16_f32 %0, %1, %2" : "=v"(r) : "v"(lo), "v"(hi));
  return r;
}

__device__ inline float bf2f(short s) {
  return __uint_as_float(((unsigned int)(unsigned short)s) << 16);
}

// -------------------- transpose fp32 [R][C] -> bf16 [C][R] --------------------
__global__ void transpose_pack(const float* __restrict__ src, __hip_bfloat16* __restrict__ dst,
                               int R, int C, int ldDst, long zSrcStride, int zDstRow)
{
  __shared__ float tile[64][65];
  src += (size_t)blockIdx.z * zSrcStride;
  const int r0 = blockIdx.y * 64, c0 = blockIdx.x * 64;
  const int t = threadIdx.x;
#pragma unroll
  for (int i = 0; i < 16; ++i) {
    int idx = i * 256 + t;
    int r = idx >> 6, c = idx & 63;
    tile[r][c] = src[(size_t)(r0 + r) * C + c0 + c];
  }
  __syncthreads();
  const int drow0 = blockIdx.z * zDstRow + c0;
#pragma unroll
  for (int i = 0; i < 16; ++i) {
    int idx = i * 256 + t;
    int cc = idx >> 6, rr = idx & 63;
    dst[(size_t)(drow0 + cc) * ldDst + r0 + rr] = __float2bfloat16(tile[rr][cc]);
  }
}

// -------------------- LN1: LayerNorm(x) -> f32 + bf16 --------------------
__global__ void ln_fused(const float* __restrict__ x,
                         const float* __restrict__ g, const float* __restrict__ bta,
                         float* __restrict__ of32, __hip_bfloat16* __restrict__ obf)
{
  const int row = blockIdx.x;
  const int t = threadIdx.x;
  float4 v = ((const float4*)(x + (size_t)row * 1024))[t];
  float s = v.x + v.y + v.z + v.w;
  float ss = v.x * v.x + v.y * v.y + v.z * v.z + v.w * v.w;
#pragma unroll
  for (int off = 1; off < 64; off <<= 1) {
    s += __shfl_xor(s, off);
    ss += __shfl_xor(ss, off);
  }
  __shared__ float sb[4], ssb[4];
  const int w = t >> 6, lane = t & 63;
  if (lane == 0) { sb[w] = s; ssb[w] = ss; }
  __syncthreads();
  s = sb[0] + sb[1] + sb[2] + sb[3];
  ss = ssb[0] + ssb[1] + ssb[2] + ssb[3];
  const float mu = s * (1.f / 1024.f);
  const float var = ss * (1.f / 1024.f) - mu * mu;
  const float rstd = rsqrtf(var + 1e-5f);
  float4 gv = ((const float4*)g)[t];
  float4 bv = ((const float4*)bta)[t];
  float4 o;
  o.x = (v.x - mu) * rstd * gv.x + bv.x;
  o.y = (v.y - mu) * rstd * gv.y + bv.y;
  o.z = (v.z - mu) * rstd * gv.z + bv.z;
  o.w = (v.w - mu) * rstd * gv.w + bv.w;
  ((float4*)(of32 + (size_t)row * 1024))[t] = o;
  __hip_bfloat16 hb[4] = { __float2bfloat16(o.x), __float2bfloat16(o.y),
                           __float2bfloat16(o.z), __float2bfloat16(o.w) };
  *(short4v*)(obf + (size_t)row * 1024 + t * 4) = *(const short4v*)hb;
}

// ---------- LN2 fused with KV-split merge: y = h + sum(O)/sum(l); z = LN(y) ----------
__global__ void ln2_merge_fused(const float* __restrict__ hres,
                                const __hip_bfloat16* __restrict__ Opart,
                                const float* __restrict__ Lpart,
                                const float* __restrict__ g, const float* __restrict__ bta,
                                float* __restrict__ of32, __hip_bfloat16* __restrict__ obf)
{
  const int row = blockIdx.x;            // b*2048 + t
  const int b = row >> 11, tt = row & 2047;
  const int qblk = tt >> 7, qloc = tt & 127;
  const int nch = (qblk >> 2) + 1;
  const int t = threadIdx.x;
  const int hd = t >> 4;                 // head (4 cols per thread, within one head)
  const int d0 = (t & 15) * 4;
  const int base = ((b * 16 + hd) * 16 + qblk) << 2;

  float4 v = ((const float4*)(hres + (size_t)row * 1024))[t];
  float l = 0.f;
  float o0 = 0.f, o1 = 0.f, o2 = 0.f, o3 = 0.f;
  for (int ch = 0; ch < nch; ++ch) {     // nch uniform per block (row)
    l += Lpart[(size_t)(base + ch) * 128 + qloc];
    short4v o4 = *(const short4v*)(Opart + (size_t)(base + ch) * 8192 + qloc * 64 + d0);
    o0 += bf2f(o4[0]); o1 += bf2f(o4[1]); o2 += bf2f(o4[2]); o3 += bf2f(o4[3]);
  }
  const float inv = 1.f / l;
  v.x += o0 * inv; v.y += o1 * inv; v.z += o2 * inv; v.w += o3 * inv;

  float s = v.x + v.y + v.z + v.w;
  float ss = v.x * v.x + v.y * v.y + v.z * v.z + v.w * v.w;
#pragma unroll
  for (int off = 1; off < 64; off <<= 1) {
    s += __shfl_xor(s, off);
    ss += __shfl_xor(ss, off);
  }
  __shared__ float sb[4], ssb[4];
  const int w = t >> 6, lane = t & 63;
  if (lane == 0) { sb[w] = s; ssb[w] = ss; }
  __syncthreads();
  s = sb[0] + sb[1] + sb[2] + sb[3];
  ss = ssb[0] + ssb[1] + ssb[2] + ssb[3];
  const float mu = s * (1.f / 1024.f);
  const float var = ss * (1.f / 1024.f) - mu * mu;
  const float rstd = rsqrtf(var + 1e-5f);
  float4 gv = ((const float4*)g)[t];
  float4 bv = ((const float4*)bta)[t];
  float4 o;
  o.x = (v.x - mu) * rstd * gv.x + bv.x;
  o.y = (v.y - mu) * rstd * gv.y + bv.y;
  o.z = (v.z - mu) * rstd * gv.z + bv.z;
  o.w = (v.w - mu) * rstd * gv.w + bv.w;
  ((float4*)(of32 + (size_t)row * 1024))[t] = o;
  __hip_bfloat16 hb[4] = { __float2bfloat16(o.x), __float2bfloat16(o.y),
                           __float2bfloat16(o.z), __float2bfloat16(o.w) };
  *(short4v*)(obf + (size_t)row * 1024 + t * 4) = *(const short4v*)hb;
}

// -------------------- GEMM (R14 green): 8 waves, BM=128 BN=256 BK=32 ------------------
// 2-deep dbuf + vmcnt(3), + T1 XCD-aware chunked blockIdx swizzle.
template<int EPI>
__global__ __launch_bounds__(512, 2) void gemm_bt(
    const __hip_bfloat16* __restrict__ A, const __hip_bfloat16* __restrict__ Bt,
    int N, int Kf, int kLen,
    const float* __restrict__ bias,
    const float* __restrict__ bq, const float* __restrict__ bk, const float* __restrict__ bv,
    __hip_bfloat16* __restrict__ oq, __hip_bfloat16* __restrict__ ok, __hip_bfloat16* __restrict__ ovt,
    __hip_bfloat16* __restrict__ obf,
    float* __restrict__ opart0, float* __restrict__ opart1, float* __restrict__ opart2)
{
  __shared__ short As[2][128 * 32];   //  8 KB per buf
  __shared__ short Bs[2][256 * 32];   // 16 KB per buf
  const int t = threadIdx.x;
  const int lane = t & 63;
  const int w = t >> 6;               // 0..7
  const int wm = w >> 2, wn = w & 3;  // 2 x 4 wave grid
  const int l15 = lane & 15, lg = lane >> 4;

  const int nwg = (int)(gridDim.x * gridDim.y);
  int wgid = (int)blockIdx.y * (int)gridDim.x + (int)blockIdx.x;
  wgid = (wgid & 7) * (nwg >> 3) + (wgid >> 3);
  const int bx = wgid % (int)gridDim.x;
  const int by = wgid / (int)gridDim.x;
  const int m0 = by * 128;
  const int n0 = bx * 256;
  const int kBase = (EPI == 2) ? (int)blockIdx.z * kLen : 0;
  const int kEnd0 = kBase + kLen;
  const int kEnd = (kEnd0 > Kf) ? Kf : kEnd0;

  f32x4 acc[4][4];
#pragma unroll
  for (int i = 0; i < 4; ++i)
#pragma unroll
    for (int j = 0; j < 4; ++j)
#pragma unroll
      for (int e = 0; e < 4; ++e) acc[i][j][e] = 0.f;

  auto STAGE = [&](int buf, int kk0) {
    {
      const int r = t >> 2, cc = t & 3;
      const int kk = (cc ^ ((r >> 1) & 3)) * 8;
      gload_lds16(A + (size_t)(m0 + r) * Kf + kk0 + kk, (char*)As + buf * 8192 + t * 16);
    }
#pragma unroll
    for (int i = 0; i < 2; ++i) {
      const int c = t + 512 * i;
      const int r = c >> 2, cc = c & 3;
      const int kk = (cc ^ ((r >> 1) & 3)) * 8;
      gload_lds16(Bt + (size_t)(n0 + r) * Kf + kk0 + kk, (char*)Bs + buf * 16384 + c * 16);
    }
  };

  STAGE(0, kBase);
  int buf = 0;
  for (int k0 = kBase; k0 < kEnd; k0 += 32) {
    const int knext = (k0 + 32 < kEnd) ? k0 + 32 : k0;
    STAGE(buf ^ 1, knext);
    asm volatile("s_waitcnt vmcnt(3)" ::: "memory");
    __builtin_amdgcn_s_barrier();
    asm volatile("" ::: "memory");

    bf16x8 af[4], bfr[4];
#pragma unroll
    for (int fm = 0; fm < 4; ++fm) {
      const int r = wm * 64 + fm * 16 + l15;
      const int kc = lg ^ ((r >> 1) & 3);
      af[fm] = *(const bf16x8*)&As[buf][r * 32 + kc * 8];
    }
#pragma unroll
    for (int fn = 0; fn < 4; ++fn) {
      const int r = wn * 64 + fn * 16 + l15;
      const int kc = lg ^ ((r >> 1) & 3);
      bfr[fn] = *(const bf16x8*)&Bs[buf][r * 32 + kc * 8];
    }
#pragma unroll
    for (int fm = 0; fm < 4; ++fm)
#pragma unroll
      for (int fn = 0; fn < 4; ++fn)
        acc[fm][fn] = __builtin_amdgcn_mfma_f32_16x16x32_bf16(af[fm], bfr[fn], acc[fm][fn], 0, 0, 0);

    asm volatile("" ::: "memory");
    __builtin_amdgcn_s_barrier();
    buf ^= 1;
  }

  // epilogue: C row = (lg*4 + rg), col = l15 within each 16x16 fragment
#pragma unroll
  for (int fm = 0; fm < 4; ++fm) {
    const int mbase = m0 + wm * 64 + fm * 16 + lg * 4;
#pragma unroll
    for (int fn = 0; fn < 4; ++fn) {
      const int n = n0 + wn * 64 + fn * 16 + l15;
      if (EPI == 0) {
        const int seg = n >> 10;
        const int cn = n & 1023;
        const int h = cn >> 6, d = cn & 63;
        const float* bp = (seg == 0) ? bq : (seg == 1) ? bk : bv;
        const float bias_v = bp[cn];
#pragma unroll
        for (int rg = 0; rg < 4; ++rg) {
          const int m = mbase + rg;
          const int b = m >> 11, tt = m & 2047;
          const size_t bh = (size_t)(b * 16 + h);
          const float val = acc[fm][fn][rg] + bias_v;
          if (seg == 0)      oq[(bh * 2048 + tt) * 64 + d] = __float2bfloat16(val);
          else if (seg == 1) ok[(bh * 2048 + tt) * 64 + d] = __float2bfloat16(val);
          else               ovt[(bh * 64 + d) * 2048 + tt] = __float2bfloat16(val);
        }
      } else if (EPI == 1) {
        const float bias_v = bias[n];
#pragma unroll
        for (int rg = 0; rg < 4; ++rg) {
          const int m = mbase + rg;
          float val = acc[fm][fn][rg] + bias_v;
          val = fmaxf(val, 0.f);
          obf[(size_t)m * N + n] = __float2bfloat16(val);
        }
      } else {
        float* op = (blockIdx.z == 0) ? opart0 : (blockIdx.z == 1) ? opart1 : opart2;
#pragma unroll
        for (int rg = 0; rg < 4; ++rg) {
          const int m = mbase + rg;
          op[(size_t)m * 1024 + n] = acc[fm][fn][rg];
        }
      }
    }
  }
}

// -------------------- FFN2 merge: out = z + b2 + p0 + p1 + p2 --------------------
__global__ void ffn2_merge(const float* __restrict__ p0, const float* __restrict__ p1,
                           const float* __restrict__ p2,
                           const float* __restrict__ z, const float* __restrict__ b2,
                           float* __restrict__ out)
{
  const size_t i = ((size_t)blockIdx.x * 256 + threadIdx.x) * 4;
  const float4 a = *(const float4*)(p0 + i);
  const float4 b = *(const float4*)(p1 + i);
  const float4 d = *(const float4*)(p2 + i);
  const float4 c = *(const float4*)(z + i);
  const float4 bb = *(const float4*)(b2 + (i & 1023));
  float4 o;
  o.x = c.x + bb.x + a.x + b.x + d.x;
  o.y = c.y + bb.y + a.y + b.y + d.y;
  o.z = c.z + bb.z + a.z + b.z + d.z;
  o.w = c.w + bb.w + a.w + b.w + d.w;
  *(float4*)(out + i) = o;
}

// ---------- flash attention (R14 green + T5 setprio around MFMA clusters) ------------
__global__ __launch_bounds__(256, 3) void flash_attn(
    const __hip_bfloat16* __restrict__ Q, const __hip_bfloat16* __restrict__ Kb,
    const __hip_bfloat16* __restrict__ Vt,
    __hip_bfloat16* __restrict__ Opart, float* __restrict__ Lpart)
{
  __shared__ short Ks[2][64 * 64];
  __shared__ short Vs[2][64 * 64];
  __shared__ short P2[4][32 * 72];
  const int t = threadIdx.x;
  const int lane = t & 63, w = t >> 6;
  const int l15 = lane & 15, lg = lane >> 4;
  const int chunk = blockIdx.x, qblk = blockIdx.y, bh = blockIdx.z;
  const int q0 = qblk * 128;
  const int s_base = chunk * 512;
  if (s_base > q0 + 127) return;
  const int s_hi = (s_base + 512 < q0 + 128) ? s_base + 512 : q0 + 128;
  const int ntiles = (s_hi - s_base) >> 6;
  const int qw = q0 + w * 32;

  const __hip_bfloat16* Qbh = Q + (size_t)bh * 2048 * 64;
  const __hip_bfloat16* Kbh = Kb + (size_t)bh * 2048 * 64;
  const __hip_bfloat16* Vbh = Vt + (size_t)bh * 64 * 2048;

  bf16x8 qf[2][2];
#pragma unroll
  for (int fm = 0; fm < 2; ++fm)
#pragma unroll
    for (int kc = 0; kc < 2; ++kc)
      qf[fm][kc] = *(const bf16x8*)(Qbh + (size_t)(qw + fm * 16 + l15) * 64 + kc * 32 + lg * 8);

  const int srow = (w << 4) + (lane >> 3);
  const int schunk = ((lane & 7) ^ (lane >> 3)) * 8;

  auto STAGE = [&](int bufi, int s0) {
#pragma unroll
    for (int i = 0; i < 2; ++i) {
      const int r = srow + i * 8;
      const int dst = bufi * 8192 + w * 2048 + i * 1024 + lane * 16;
      gload_lds16(Kbh + (size_t)(s0 + r) * 64 + schunk, (char*)Ks + dst);
      gload_lds16(Vbh + (size_t)r * 2048 + s0 + schunk, (char*)Vs + dst);
    }
  };

  f32x4 o_acc[2][4];
  float lpart[2] = {0.f, 0.f};
#pragma unroll
  for (int fm = 0; fm < 2; ++fm)
#pragma unroll
    for (int fd = 0; fd < 4; ++fd)
#pragma unroll
      for (int e = 0; e < 4; ++e) o_acc[fm][fd][e] = 0.f;

  const float C = 0.18033688011112042f;   // 0.125 * log2(e)

  STAGE(0, s_base);
  int cur = 0;
  for (int ti = 0; ti < ntiles; ++ti) {
    const int s0 = s_base + ti * 64;
    const int nxt = (ti + 1 < ntiles) ? s0 + 64 : s0;
    STAGE(cur ^ 1, nxt);
    asm volatile("s_waitcnt vmcnt(4)" ::: "memory");
    __builtin_amdgcn_s_barrier();
    asm volatile("" ::: "memory");

    if (s0 <= qw + 31) {
      f32x4 s_acc[2][4];
#pragma unroll
      for (int fm = 0; fm < 2; ++fm)
#pragma unroll
        for (int fn = 0; fn < 4; ++fn)
#pragma unroll
          for (int e = 0; e < 4; ++e) s_acc[fm][fn][e] = 0.f;
      __builtin_amdgcn_s_setprio(1);
#pragma unroll
      for (int kc = 0; kc < 2; ++kc)
#pragma unroll
        for (int fn = 0; fn < 4; ++fn) {
          const int r = fn * 16 + l15;
          bf16x8 kf = *(const bf16x8*)&Ks[cur][r * 64 + ((((kc << 2) | lg) ^ (l15 & 7)) << 3)];
          s_acc[0][fn] = __builtin_amdgcn_mfma_f32_16x16x32_bf16(kf, qf[0][kc], s_acc[0][fn], 0, 0, 0);
          s_acc[1][fn] = __builtin_amdgcn_mfma_f32_16x16x32_bf16(kf, qf[1][kc], s_acc[1][fn], 0, 0, 0);
        }
      __builtin_amdgcn_s_setprio(0);

      const bool needmask = (s0 + 63 > qw);
      float pr[2][4][4];
#pragma unroll
      for (int fm = 0; fm < 2; ++fm) {
        const int qv = qw + fm * 16 + l15;
#pragma unroll
        for (int fn = 0; fn < 4; ++fn)
#pragma unroll
          for (int rg = 0; rg < 4; ++rg) {
            float p = exp2_fast(s_acc[fm][fn][rg] * C);
            if (needmask) {
              const int sg = s0 + fn * 16 + lg * 4 + rg;
              p = (sg <= qv) ? p : 0.f;
            }
            pr[fm][fn][rg] = p;
            lpart[fm] += p;
          }
      }

#pragma unroll
      for (int fm = 0; fm < 2; ++fm)
#pragma unroll
        for (int fn = 0; fn < 4; ++fn) {
          uint2v u;
          u.x = cvt_pk_bf16(pr[fm][fn][0], pr[fm][fn][1]);
          u.y = cvt_pk_bf16(pr[fm][fn][2], pr[fm][fn][3]);
          *(uint2v*)&P2[w][(fm * 16 + l15) * 72 + fn * 16 + lg * 4] = u;
        }

      __builtin_amdgcn_s_setprio(1);
#pragma unroll
      for (int kc = 0; kc < 2; ++kc) {
        bf16x8 pf0 = *(const bf16x8*)&P2[w][(l15) * 72 + kc * 32 + lg * 8];
        bf16x8 pf1 = *(const bf16x8*)&P2[w][(16 + l15) * 72 + kc * 32 + lg * 8];
#pragma unroll
        for (int fd = 0; fd < 4; ++fd) {
          const int r = fd * 16 + l15;
          bf16x8 vf = *(const bf16x8*)&Vs[cur][r * 64 + ((((kc << 2) | lg) ^ (l15 & 7)) << 3)];
          o_acc[0][fd] = __builtin_amdgcn_mfma_f32_16x16x32_bf16(vf, pf0, o_acc[0][fd], 0, 0, 0);
          o_acc[1][fd] = __builtin_amdgcn_mfma_f32_16x16x32_bf16(vf, pf1, o_acc[1][fd], 0, 0, 0);
        }
      }
      __builtin_amdgcn_s_setprio(0);
    }

    asm volatile("" ::: "memory");
    __builtin_amdgcn_s_barrier();
    cur ^= 1;
  }

  const int pslot = ((bh * 16 + qblk) << 2) + chunk;
  __hip_bfloat16* op = Opart + (size_t)pslot * 8192;
#pragma unroll
  for (int fm = 0; fm < 2; ++fm) {
    float l = lpart[fm];
    l += __shfl_xor(l, 16);
    l += __shfl_xor(l, 32);
    const int qloc = w * 32 + fm * 16 + l15;
    if (lg == 0) Lpart[pslot * 128 + qloc] = l;
#pragma unroll
    for (int fd = 0; fd < 4; ++fd) {
      uint2v u;
      u.x = cvt_pk_bf16(o_acc[fm][fd][0], o_acc[fm][fd][1]);
      u.y = cvt_pk_bf16(o_acc[fm][fd][2], o_acc[fm][fd][3]);
      *(uint2v*)(op + (size_t)qloc * 64 + fd * 16 + lg * 4) = u;
    }
  }
}

// -------------------- launch --------------------
extern "C" void kernel_launch(void* const* d_in, const int* in_sizes, int n_in,
                              void* d_out, int out_size, void* d_ws, size_t ws_size,
                              hipStream_t stream) {
  const float* x    = (const float*)d_in[0];
  const float* wq   = (const float*)d_in[1];
  const float* bq   = (const float*)d_in[2];
  const float* wk   = (const float*)d_in[3];
  const float* bk   = (const float*)d_in[4];
  const float* wv   = (const float*)d_in[5];
  const float* bv   = (const float*)d_in[6];
  const float* ln1g = (const float*)d_in[7];
  const float* ln1b = (const float*)d_in[8];
  const float* ln2g = (const float*)d_in[9];
  const float* ln2b = (const float*)d_in[10];
  const float* w1   = (const float*)d_in[11];
  const float* b1   = (const float*)d_in[12];
  const float* w2   = (const float*)d_in[13];
  const float* b2   = (const float*)d_in[14];
  float* out = (float*)d_out;

  char* ws = (char*)d_ws;
  const size_t MB = 1024 * 1024;
  __hip_bfloat16* h_bf  = (__hip_bfloat16*)(ws + 0);
  float* z_f32          = (float*)(ws + 0);
  __hip_bfloat16* qb    = (__hip_bfloat16*)(ws + 8 * MB);
  __hip_bfloat16* kb    = (__hip_bfloat16*)(ws + 16 * MB);
  __hip_bfloat16* z_bf  = (__hip_bfloat16*)(ws + 16 * MB);
  __hip_bfloat16* vtb   = (__hip_bfloat16*)(ws + 24 * MB);
  __hip_bfloat16* ff1   = (__hip_bfloat16*)(ws + 24 * MB);
  float* h_f32          = (float*)(ws + 32 * MB);
  __hip_bfloat16* Opart = (__hip_bfloat16*)(ws + 48 * MB);
  float* p0             = (float*)(ws + 56 * MB);
  float* p1             = (float*)(ws + 72 * MB);
  float* Lpart          = (float*)(ws + 80 * MB);
  __hip_bfloat16* wqkvT = (__hip_bfloat16*)(ws + 88 * MB);
  float* p2             = (float*)(ws + 88 * MB);
  __hip_bfloat16* w1T   = (__hip_bfloat16*)(ws + 96 * MB);
  __hip_bfloat16* w2T   = (__hip_bfloat16*)(ws + 104 * MB);

  transpose_pack<<<dim3(1, 16, 16), 256, 0, stream>>>(wq, wqkvT + 0 * 1024 * 1024, 1024, 64, 1024, 65536, 64);
  transpose_pack<<<dim3(1, 16, 16), 256, 0, stream>>>(wk, wqkvT + 1 * 1024 * 1024, 1024, 64, 1024, 65536, 64);
  transpose_pack<<<dim3(1, 16, 16), 256, 0, stream>>>(wv, wqkvT + 2 * 1024 * 1024, 1024, 64, 1024, 65536, 64);
  transpose_pack<<<dim3(64, 16, 1), 256, 0, stream>>>(w1, w1T, 1024, 4096, 1024, 0, 0);
  transpose_pack<<<dim3(16, 64, 1), 256, 0, stream>>>(w2, w2T, 4096, 1024, 4096, 0, 0);

  ln_fused<<<4096, 256, 0, stream>>>(x, ln1g, ln1b, h_f32, h_bf);

  // QKV projection: M=4096, N=3072, K=1024  (grid 12*32=384, %8==0)
  gemm_bt<0><<<dim3(12, 32), 512, 0, stream>>>(h_bf, wqkvT, 3072, 1024, 1024,
      nullptr, bq, bk, bv, qb, kb, vtb, nullptr, nullptr, nullptr, nullptr);

  flash_attn<<<dim3(4, 16, 32), 256, 0, stream>>>(qb, kb, vtb, Opart, Lpart);

  // LN2 + KV-split merge fused: z = LN(h + sum(O)/sum(l))
  ln2_merge_fused<<<4096, 256, 0, stream>>>(h_f32, Opart, Lpart, ln2g, ln2b, z_f32, z_bf);

  // FFN1: relu(z @ w1 + b1), M=4096, N=4096, K=1024  (grid 16*32=512, %8==0)
  gemm_bt<1><<<dim3(16, 32), 512, 0, stream>>>(z_bf, w1T, 4096, 1024, 1024,
      b1, nullptr, nullptr, nullptr, nullptr, nullptr, nullptr, ff1, nullptr, nullptr, nullptr);

  // FFN2 split-K=3 (1376/1376/1344), f32 partials: M=4096, N=1024, K=4096 (4*32=128 %8==0)
  gemm_bt<2><<<dim3(4, 32, 3), 512, 0, stream>>>(ff1, w2T, 1024, 4096, 1376,
      nullptr, nullptr, nullptr, nullptr, nullptr, nullptr, nullptr, nullptr, p0, p1, p2);

  // out = z + b2 + p0 + p1 + p2
  ffn2_merge<<<4096, 256, 0, stream>>>(p0, p1, p2, z_f32, b2, out);
}

// Round 19
// 236.991 us; speedup vs baseline: 1.3913x; 1.0107x over previous
//
#include <hip/hip_runtime.h>
#include <hip/hip_bf16.h>
#include <cstdint>
#include <cstddef>

typedef __attribute__((ext_vector_type(8))) short bf16x8;
typedef __attribute__((ext_vector_type(4))) float f32x4;
typedef __attribute__((ext_vector_type(4))) short short4v;
typedef __attribute__((ext_vector_type(2))) unsigned int uint2v;

__device__ inline void gload_lds16(const void* g, void* l) {
  __builtin_amdgcn_global_load_lds((const __attribute__((address_space(1))) void*)g,
                                   (__attribute__((address_space(3))) void*)l, 16, 0, 0);
}

__device__ inline float exp2_fast(float x) {
  float r;
  asm volatile("v_exp_f32 %0, %1" : "=v"(r) : "v"(x));
  return r;
}

__device__ inline unsigned int cvt_pk_bf16(float lo, float hi) {
  unsigned int r;
  asm volatile("v_cvt_pk_bf16_f32 %0, %1, %2" : "=v"(r) : "v"(lo), "v"(hi));
  return r;
}

__device__ inline float bf2f(short s) {
  return __uint_as_float(((unsigned int)(unsigned short)s) << 16);
}

// -------------------- transpose fp32 [R][C] -> bf16 [C][R] --------------------
__global__ void transpose_pack(const float* __restrict__ src, __hip_bfloat16* __restrict__ dst,
                               int R, int C, int ldDst, long zSrcStride, int zDstRow)
{
  __shared__ float tile[64][65];
  src += (size_t)blockIdx.z * zSrcStride;
  const int r0 = blockIdx.y * 64, c0 = blockIdx.x * 64;
  const int t = threadIdx.x;
#pragma unroll
  for (int i = 0; i < 16; ++i) {
    int idx = i * 256 + t;
    int r = idx >> 6, c = idx & 63;
    tile[r][c] = src[(size_t)(r0 + r) * C + c0 + c];
  }
  __syncthreads();
  const int drow0 = blockIdx.z * zDstRow + c0;
#pragma unroll
  for (int i = 0; i < 16; ++i) {
    int idx = i * 256 + t;
    int cc = idx >> 6, rr = idx & 63;
    dst[(size_t)(drow0 + cc) * ldDst + r0 + rr] = __float2bfloat16(tile[rr][cc]);
  }
}

// ------------- merged QKV weight transpose: wq/wk/wv [16][1024][64] -> [3072][1024] ----
__global__ void transpose_qkv(const float* __restrict__ wq, const float* __restrict__ wk,
                              const float* __restrict__ wv, __hip_bfloat16* __restrict__ dst)
{
  __shared__ float tile[64][65];
  const int z = blockIdx.z;              // grid (1,16,48)
  const int seg = z >> 4, h = z & 15;
  const float* src = (seg == 0) ? wq : (seg == 1) ? wk : wv;
  src += (size_t)h * 65536;
  const int r0 = blockIdx.y * 64;
  const int t = threadIdx.x;
#pragma unroll
  for (int i = 0; i < 16; ++i) {
    int idx = i * 256 + t;
    int r = idx >> 6, c = idx & 63;
    tile[r][c] = src[(size_t)(r0 + r) * 64 + c];
  }
  __syncthreads();
  const int drow0 = seg * 1024 + h * 64;
#pragma unroll
  for (int i = 0; i < 16; ++i) {
    int idx = i * 256 + t;
    int cc = idx >> 6, rr = idx & 63;
    dst[(size_t)(drow0 + cc) * 1024 + r0 + rr] = __float2bfloat16(tile[rr][cc]);
  }
}

// -------------------- LN1: LayerNorm(x) -> f32 + bf16 --------------------
__global__ void ln_fused(const float* __restrict__ x,
                         const float* __restrict__ g, const float* __restrict__ bta,
                         float* __restrict__ of32, __hip_bfloat16* __restrict__ obf)
{
  const int row = blockIdx.x;
  const int t = threadIdx.x;
  float4 v = ((const float4*)(x + (size_t)row * 1024))[t];
  float s = v.x + v.y + v.z + v.w;
  float ss = v.x * v.x + v.y * v.y + v.z * v.z + v.w * v.w;
#pragma unroll
  for (int off = 1; off < 64; off <<= 1) {
    s += __shfl_xor(s, off);
    ss += __shfl_xor(ss, off);
  }
  __shared__ float sb[4], ssb[4];
  const int w = t >> 6, lane = t & 63;
  if (lane == 0) { sb[w] = s; ssb[w] = ss; }
  __syncthreads();
  s = sb[0] + sb[1] + sb[2] + sb[3];
  ss = ssb[0] + ssb[1] + ssb[2] + ssb[3];
  const float mu = s * (1.f / 1024.f);
  const float var = ss * (1.f / 1024.f) - mu * mu;
  const float rstd = rsqrtf(var + 1e-5f);
  float4 gv = ((const float4*)g)[t];
  float4 bv = ((const float4*)bta)[t];
  float4 o;
  o.x = (v.x - mu) * rstd * gv.x + bv.x;
  o.y = (v.y - mu) * rstd * gv.y + bv.y;
  o.z = (v.z - mu) * rstd * gv.z + bv.z;
  o.w = (v.w - mu) * rstd * gv.w + bv.w;
  ((float4*)(of32 + (size_t)row * 1024))[t] = o;
  __hip_bfloat16 hb[4] = { __float2bfloat16(o.x), __float2bfloat16(o.y),
                           __float2bfloat16(o.z), __float2bfloat16(o.w) };
  *(short4v*)(obf + (size_t)row * 1024 + t * 4) = *(const short4v*)hb;
}

// ---------- LN2 fused with KV-split merge: y = h + sum(O)/sum(l); z = LN(y) ----------
__global__ void ln2_merge_fused(const float* __restrict__ hres,
                                const __hip_bfloat16* __restrict__ Opart,
                                const float* __restrict__ Lpart,
                                const float* __restrict__ g, const float* __restrict__ bta,
                                float* __restrict__ of32, __hip_bfloat16* __restrict__ obf)
{
  const int row = blockIdx.x;            // b*2048 + t
  const int b = row >> 11, tt = row & 2047;
  const int qblk = tt >> 7, qloc = tt & 127;
  const int nch = (qblk >> 2) + 1;
  const int t = threadIdx.x;
  const int hd = t >> 4;                 // head (4 cols per thread, within one head)
  const int d0 = (t & 15) * 4;
  const int base = ((b * 16 + hd) * 16 + qblk) << 2;

  float4 v = ((const float4*)(hres + (size_t)row * 1024))[t];
  float l = 0.f;
  float o0 = 0.f, o1 = 0.f, o2 = 0.f, o3 = 0.f;
  for (int ch = 0; ch < nch; ++ch) {     // nch uniform per block (row)
    l += Lpart[(size_t)(base + ch) * 128 + qloc];
    short4v o4 = *(const short4v*)(Opart + (size_t)(base + ch) * 8192 + qloc * 64 + d0);
    o0 += bf2f(o4[0]); o1 += bf2f(o4[1]); o2 += bf2f(o4[2]); o3 += bf2f(o4[3]);
  }
  const float inv = 1.f / l;
  v.x += o0 * inv; v.y += o1 * inv; v.z += o2 * inv; v.w += o3 * inv;

  float s = v.x + v.y + v.z + v.w;
  float ss = v.x * v.x + v.y * v.y + v.z * v.z + v.w * v.w;
#pragma unroll
  for (int off = 1; off < 64; off <<= 1) {
    s += __shfl_xor(s, off);
    ss += __shfl_xor(ss, off);
  }
  __shared__ float sb[4], ssb[4];
  const int w = t >> 6, lane = t & 63;
  if (lane == 0) { sb[w] = s; ssb[w] = ss; }
  __syncthreads();
  s = sb[0] + sb[1] + sb[2] + sb[3];
  ss = ssb[0] + ssb[1] + ssb[2] + ssb[3];
  const float mu = s * (1.f / 1024.f);
  const float var = ss * (1.f / 1024.f) - mu * mu;
  const float rstd = rsqrtf(var + 1e-5f);
  float4 gv = ((const float4*)g)[t];
  float4 bv = ((const float4*)bta)[t];
  float4 o;
  o.x = (v.x - mu) * rstd * gv.x + bv.x;
  o.y = (v.y - mu) * rstd * gv.y + bv.y;
  o.z = (v.z - mu) * rstd * gv.z + bv.z;
  o.w = (v.w - mu) * rstd * gv.w + bv.w;
  ((float4*)(of32 + (size_t)row * 1024))[t] = o;
  __hip_bfloat16 hb[4] = { __float2bfloat16(o.x), __float2bfloat16(o.y),
                           __float2bfloat16(o.z), __float2bfloat16(o.w) };
  *(short4v*)(obf + (size_t)row * 1024 + t * 4) = *(const short4v*)hb;
}

// -------------------- GEMM (R14 green): 8 waves, BM=128 BN=256 BK=32 ------------------
// 2-deep dbuf + vmcnt(3), + T1 XCD-aware chunked blockIdx swizzle.
template<int EPI>
__global__ __launch_bounds__(512, 2) void gemm_bt(
    const __hip_bfloat16* __restrict__ A, const __hip_bfloat16* __restrict__ Bt,
    int N, int Kf, int kLen,
    const float* __restrict__ bias,
    const float* __restrict__ bq, const float* __restrict__ bk, const float* __restrict__ bv,
    __hip_bfloat16* __restrict__ oq, __hip_bfloat16* __restrict__ ok, __hip_bfloat16* __restrict__ ovt,
    __hip_bfloat16* __restrict__ obf,
    float* __restrict__ opart0, float* __restrict__ opart1,
    float* __restrict__ opart2, float* __restrict__ opart3)
{
  __shared__ short As[2][128 * 32];   //  8 KB per buf
  __shared__ short Bs[2][256 * 32];   // 16 KB per buf
  const int t = threadIdx.x;
  const int lane = t & 63;
  const int w = t >> 6;               // 0..7
  const int wm = w >> 2, wn = w & 3;  // 2 x 4 wave grid
  const int l15 = lane & 15, lg = lane >> 4;

  const int nwg = (int)(gridDim.x * gridDim.y);
  int wgid = (int)blockIdx.y * (int)gridDim.x + (int)blockIdx.x;
  wgid = (wgid & 7) * (nwg >> 3) + (wgid >> 3);
  const int bx = wgid % (int)gridDim.x;
  const int by = wgid / (int)gridDim.x;
  const int m0 = by * 128;
  const int n0 = bx * 256;
  const int kBase = (EPI == 2) ? (int)blockIdx.z * kLen : 0;
  const int kEnd0 = kBase + kLen;
  const int kEnd = (kEnd0 > Kf) ? Kf : kEnd0;

  f32x4 acc[4][4];
#pragma unroll
  for (int i = 0; i < 4; ++i)
#pragma unroll
    for (int j = 0; j < 4; ++j)
#pragma unroll
      for (int e = 0; e < 4; ++e) acc[i][j][e] = 0.f;

  auto STAGE = [&](int buf, int kk0) {
    {
      const int r = t >> 2, cc = t & 3;
      const int kk = (cc ^ ((r >> 1) & 3)) * 8;
      gload_lds16(A + (size_t)(m0 + r) * Kf + kk0 + kk, (char*)As + buf * 8192 + t * 16);
    }
#pragma unroll
    for (int i = 0; i < 2; ++i) {
      const int c = t + 512 * i;
      const int r = c >> 2, cc = c & 3;
      const int kk = (cc ^ ((r >> 1) & 3)) * 8;
      gload_lds16(Bt + (size_t)(n0 + r) * Kf + kk0 + kk, (char*)Bs + buf * 16384 + c * 16);
    }
  };

  STAGE(0, kBase);
  int buf = 0;
  for (int k0 = kBase; k0 < kEnd; k0 += 32) {
    const int knext = (k0 + 32 < kEnd) ? k0 + 32 : k0;
    STAGE(buf ^ 1, knext);
    asm volatile("s_waitcnt vmcnt(3)" ::: "memory");
    __builtin_amdgcn_s_barrier();
    asm volatile("" ::: "memory");

    bf16x8 af[4], bfr[4];
#pragma unroll
    for (int fm = 0; fm < 4; ++fm) {
      const int r = wm * 64 + fm * 16 + l15;
      const int kc = lg ^ ((r >> 1) & 3);
      af[fm] = *(const bf16x8*)&As[buf][r * 32 + kc * 8];
    }
#pragma unroll
    for (int fn = 0; fn < 4; ++fn) {
      const int r = wn * 64 + fn * 16 + l15;
      const int kc = lg ^ ((r >> 1) & 3);
      bfr[fn] = *(const bf16x8*)&Bs[buf][r * 32 + kc * 8];
    }
#pragma unroll
    for (int fm = 0; fm < 4; ++fm)
#pragma unroll
      for (int fn = 0; fn < 4; ++fn)
        acc[fm][fn] = __builtin_amdgcn_mfma_f32_16x16x32_bf16(af[fm], bfr[fn], acc[fm][fn], 0, 0, 0);

    asm volatile("" ::: "memory");
    __builtin_amdgcn_s_barrier();
    buf ^= 1;
  }

  // epilogue: C row = (lg*4 + rg), col = l15 within each 16x16 fragment
#pragma unroll
  for (int fm = 0; fm < 4; ++fm) {
    const int mbase = m0 + wm * 64 + fm * 16 + lg * 4;
#pragma unroll
    for (int fn = 0; fn < 4; ++fn) {
      const int n = n0 + wn * 64 + fn * 16 + l15;
      if (EPI == 0) {
        const int seg = n >> 10;
        const int cn = n & 1023;
        const int h = cn >> 6, d = cn & 63;
        const float* bp = (seg == 0) ? bq : (seg == 1) ? bk : bv;
        const float bias_v = bp[cn];
#pragma unroll
        for (int rg = 0; rg < 4; ++rg) {
          const int m = mbase + rg;
          const int b = m >> 11, tt = m & 2047;
          const size_t bh = (size_t)(b * 16 + h);
          const float val = acc[fm][fn][rg] + bias_v;
          if (seg == 0)      oq[(bh * 2048 + tt) * 64 + d] = __float2bfloat16(val);
          else if (seg == 1) ok[(bh * 2048 + tt) * 64 + d] = __float2bfloat16(val);
          else               ovt[(bh * 64 + d) * 2048 + tt] = __float2bfloat16(val);
        }
      } else if (EPI == 1) {
        const float bias_v = bias[n];
#pragma unroll
        for (int rg = 0; rg < 4; ++rg) {
          const int m = mbase + rg;
          float val = acc[fm][fn][rg] + bias_v;
          val = fmaxf(val, 0.f);
          obf[(size_t)m * N + n] = __float2bfloat16(val);
        }
      } else {
        float* op = (blockIdx.z == 0) ? opart0 : (blockIdx.z == 1) ? opart1
                  : (blockIdx.z == 2) ? opart2 : opart3;
#pragma unroll
        for (int rg = 0; rg < 4; ++rg) {
          const int m = mbase + rg;
          op[(size_t)m * 1024 + n] = acc[fm][fn][rg];
        }
      }
    }
  }
}

// -------------------- FFN2 merge: out = z + b2 + p0 + p1 + p2 + p3 --------------------
__global__ void ffn2_merge(const float* __restrict__ p0, const float* __restrict__ p1,
                           const float* __restrict__ p2, const float* __restrict__ p3,
                           const float* __restrict__ z, const float* __restrict__ b2,
                           float* __restrict__ out)
{
  const size_t i = ((size_t)blockIdx.x * 256 + threadIdx.x) * 4;
  const float4 a = *(const float4*)(p0 + i);
  const float4 b = *(const float4*)(p1 + i);
  const float4 d = *(const float4*)(p2 + i);
  const float4 e = *(const float4*)(p3 + i);
  const float4 c = *(const float4*)(z + i);
  const float4 bb = *(const float4*)(b2 + (i & 1023));
  float4 o;
  o.x = c.x + bb.x + a.x + b.x + d.x + e.x;
  o.y = c.y + bb.y + a.y + b.y + d.y + e.y;
  o.z = c.z + bb.z + a.z + b.z + d.z + e.z;
  o.w = c.w + bb.w + a.w + b.w + d.w + e.w;
  *(float4*)(out + i) = o;
}

// ---------- flash attention (R14 green + T5 setprio around MFMA clusters) ------------
__global__ __launch_bounds__(256, 3) void flash_attn(
    const __hip_bfloat16* __restrict__ Q, const __hip_bfloat16* __restrict__ Kb,
    const __hip_bfloat16* __restrict__ Vt,
    __hip_bfloat16* __restrict__ Opart, float* __restrict__ Lpart)
{
  __shared__ short Ks[2][64 * 64];
  __shared__ short Vs[2][64 * 64];
  __shared__ short P2[4][32 * 72];
  const int t = threadIdx.x;
  const int lane = t & 63, w = t >> 6;
  const int l15 = lane & 15, lg = lane >> 4;
  const int chunk = blockIdx.x, qblk = blockIdx.y, bh = blockIdx.z;
  const int q0 = qblk * 128;
  const int s_base = chunk * 512;
  if (s_base > q0 + 127) return;
  const int s_hi = (s_base + 512 < q0 + 128) ? s_base + 512 : q0 + 128;
  const int ntiles = (s_hi - s_base) >> 6;
  const int qw = q0 + w * 32;

  const __hip_bfloat16* Qbh = Q + (size_t)bh * 2048 * 64;
  const __hip_bfloat16* Kbh = Kb + (size_t)bh * 2048 * 64;
  const __hip_bfloat16* Vbh = Vt + (size_t)bh * 64 * 2048;

  bf16x8 qf[2][2];
#pragma unroll
  for (int fm = 0; fm < 2; ++fm)
#pragma unroll
    for (int kc = 0; kc < 2; ++kc)
      qf[fm][kc] = *(const bf16x8*)(Qbh + (size_t)(qw + fm * 16 + l15) * 64 + kc * 32 + lg * 8);

  const int srow = (w << 4) + (lane >> 3);
  const int schunk = ((lane & 7) ^ (lane >> 3)) * 8;

  auto STAGE = [&](int bufi, int s0) {
#pragma unroll
    for (int i = 0; i < 2; ++i) {
      const int r = srow + i * 8;
      const int dst = bufi * 8192 + w * 2048 + i * 1024 + lane * 16;
      gload_lds16(Kbh + (size_t)(s0 + r) * 64 + schunk, (char*)Ks + dst);
      gload_lds16(Vbh + (size_t)r * 2048 + s0 + schunk, (char*)Vs + dst);
    }
  };

  f32x4 o_acc[2][4];
  float lpart[2] = {0.f, 0.f};
#pragma unroll
  for (int fm = 0; fm < 2; ++fm)
#pragma unroll
    for (int fd = 0; fd < 4; ++fd)
#pragma unroll
      for (int e = 0; e < 4; ++e) o_acc[fm][fd][e] = 0.f;

  const float C = 0.18033688011112042f;   // 0.125 * log2(e)

  STAGE(0, s_base);
  int cur = 0;
  for (int ti = 0; ti < ntiles; ++ti) {
    const int s0 = s_base + ti * 64;
    const int nxt = (ti + 1 < ntiles) ? s0 + 64 : s0;
    STAGE(cur ^ 1, nxt);
    asm volatile("s_waitcnt vmcnt(4)" ::: "memory");
    __builtin_amdgcn_s_barrier();
    asm volatile("" ::: "memory");

    if (s0 <= qw + 31) {
      f32x4 s_acc[2][4];
#pragma unroll
      for (int fm = 0; fm < 2; ++fm)
#pragma unroll
        for (int fn = 0; fn < 4; ++fn)
#pragma unroll
          for (int e = 0; e < 4; ++e) s_acc[fm][fn][e] = 0.f;
      __builtin_amdgcn_s_setprio(1);
#pragma unroll
      for (int kc = 0; kc < 2; ++kc)
#pragma unroll
        for (int fn = 0; fn < 4; ++fn) {
          const int r = fn * 16 + l15;
          bf16x8 kf = *(const bf16x8*)&Ks[cur][r * 64 + ((((kc << 2) | lg) ^ (l15 & 7)) << 3)];
          s_acc[0][fn] = __builtin_amdgcn_mfma_f32_16x16x32_bf16(kf, qf[0][kc], s_acc[0][fn], 0, 0, 0);
          s_acc[1][fn] = __builtin_amdgcn_mfma_f32_16x16x32_bf16(kf, qf[1][kc], s_acc[1][fn], 0, 0, 0);
        }
      __builtin_amdgcn_s_setprio(0);

      const bool needmask = (s0 + 63 > qw);
      float pr[2][4][4];
#pragma unroll
      for (int fm = 0; fm < 2; ++fm) {
        const int qv = qw + fm * 16 + l15;
#pragma unroll
        for (int fn = 0; fn < 4; ++fn)
#pragma unroll
          for (int rg = 0; rg < 4; ++rg) {
            float p = exp2_fast(s_acc[fm][fn][rg] * C);
            if (needmask) {
              const int sg = s0 + fn * 16 + lg * 4 + rg;
              p = (sg <= qv) ? p : 0.f;
            }
            pr[fm][fn][rg] = p;
            lpart[fm] += p;
          }
      }

#pragma unroll
      for (int fm = 0; fm < 2; ++fm)
#pragma unroll
        for (int fn = 0; fn < 4; ++fn) {
          uint2v u;
          u.x = cvt_pk_bf16(pr[fm][fn][0], pr[fm][fn][1]);
          u.y = cvt_pk_bf16(pr[fm][fn][2], pr[fm][fn][3]);
          *(uint2v*)&P2[w][(fm * 16 + l15) * 72 + fn * 16 + lg * 4] = u;
        }

      __builtin_amdgcn_s_setprio(1);
#pragma unroll
      for (int kc = 0; kc < 2; ++kc) {
        bf16x8 pf0 = *(const bf16x8*)&P2[w][(l15) * 72 + kc * 32 + lg * 8];
        bf16x8 pf1 = *(const bf16x8*)&P2[w][(16 + l15) * 72 + kc * 32 + lg * 8];
#pragma unroll
        for (int fd = 0; fd < 4; ++fd) {
          const int r = fd * 16 + l15;
          bf16x8 vf = *(const bf16x8*)&Vs[cur][r * 64 + ((((kc << 2) | lg) ^ (l15 & 7)) << 3)];
          o_acc[0][fd] = __builtin_amdgcn_mfma_f32_16x16x32_bf16(vf, pf0, o_acc[0][fd], 0, 0, 0);
          o_acc[1][fd] = __builtin_amdgcn_mfma_f32_16x16x32_bf16(vf, pf1, o_acc[1][fd], 0, 0, 0);
        }
      }
      __builtin_amdgcn_s_setprio(0);
    }

    asm volatile("" ::: "memory");
    __builtin_amdgcn_s_barrier();
    cur ^= 1;
  }

  const int pslot = ((bh * 16 + qblk) << 2) + chunk;
  __hip_bfloat16* op = Opart + (size_t)pslot * 8192;
#pragma unroll
  for (int fm = 0; fm < 2; ++fm) {
    float l = lpart[fm];
    l += __shfl_xor(l, 16);
    l += __shfl_xor(l, 32);
    const int qloc = w * 32 + fm * 16 + l15;
    if (lg == 0) Lpart[pslot * 128 + qloc] = l;
#pragma unroll
    for (int fd = 0; fd < 4; ++fd) {
      uint2v u;
      u.x = cvt_pk_bf16(o_acc[fm][fd][0], o_acc[fm][fd][1]);
      u.y = cvt_pk_bf16(o_acc[fm][fd][2], o_acc[fm][fd][3]);
      *(uint2v*)(op + (size_t)qloc * 64 + fd * 16 + lg * 4) = u;
    }
  }
}

// -------------------- launch --------------------
extern "C" void kernel_launch(void* const* d_in, const int* in_sizes, int n_in,
                              void* d_out, int out_size, void* d_ws, size_t ws_size,
                              hipStream_t stream) {
  const float* x    = (const float*)d_in[0];
  const float* wq   = (const float*)d_in[1];
  const float* bq   = (const float*)d_in[2];
  const float* wk   = (const float*)d_in[3];
  const float* bk   = (const float*)d_in[4];
  const float* wv   = (const float*)d_in[5];
  const float* bv   = (const float*)d_in[6];
  const float* ln1g = (const float*)d_in[7];
  const float* ln1b = (const float*)d_in[8];
  const float* ln2g = (const float*)d_in[9];
  const float* ln2b = (const float*)d_in[10];
  const float* w1   = (const float*)d_in[11];
  const float* b1   = (const float*)d_in[12];
  const float* w2   = (const float*)d_in[13];
  const float* b2   = (const float*)d_in[14];
  float* out = (float*)d_out;

  char* ws = (char*)d_ws;
  const size_t MB = 1024 * 1024;
  // Phase-checked layout (MB offsets):
  // h_bf  [0,8)    LN1->QKV          z_f32 [0,16)   LN2->ffn2_merge (h_bf,qb dead)
  // qb[8,16) kb[16,24) vtb[24,32)    QKV->flash     z_bf [16,24)  LN2->FFN1 (kb dead)
  // h_f32 [32,48)  LN1->LN2 (dead after -> FFN2 partial p3)
  // Opart [48,80)  flash->LN2        p0[56,72) p1[72,88) p2[88,104)  FFN2->merge
  // Lpart [80,81)  flash->LN2        ff1 [24,56) FFN1->FFN2
  // wqkvT [88,96)  ->QKV   w1T [96,104) ->FFN1   w2T [104,112) ->FFN2
  __hip_bfloat16* h_bf  = (__hip_bfloat16*)(ws + 0);
  float* z_f32          = (float*)(ws + 0);
  __hip_bfloat16* qb    = (__hip_bfloat16*)(ws + 8 * MB);
  __hip_bfloat16* kb    = (__hip_bfloat16*)(ws + 16 * MB);
  __hip_bfloat16* z_bf  = (__hip_bfloat16*)(ws + 16 * MB);
  __hip_bfloat16* vtb   = (__hip_bfloat16*)(ws + 24 * MB);
  __hip_bfloat16* ff1   = (__hip_bfloat16*)(ws + 24 * MB);
  float* h_f32          = (float*)(ws + 32 * MB);
  float* p3             = (float*)(ws + 32 * MB);
  __hip_bfloat16* Opart = (__hip_bfloat16*)(ws + 48 * MB);
  float* p0             = (float*)(ws + 56 * MB);
  float* p1             = (float*)(ws + 72 * MB);
  float* Lpart          = (float*)(ws + 80 * MB);
  __hip_bfloat16* wqkvT = (__hip_bfloat16*)(ws + 88 * MB);
  float* p2             = (float*)(ws + 88 * MB);
  __hip_bfloat16* w1T   = (__hip_bfloat16*)(ws + 96 * MB);
  __hip_bfloat16* w2T   = (__hip_bfloat16*)(ws + 104 * MB);

  transpose_qkv<<<dim3(1, 16, 48), 256, 0, stream>>>(wq, wk, wv, wqkvT);
  transpose_pack<<<dim3(64, 16, 1), 256, 0, stream>>>(w1, w1T, 1024, 4096, 1024, 0, 0);
  transpose_pack<<<dim3(16, 64, 1), 256, 0, stream>>>(w2, w2T, 4096, 1024, 4096, 0, 0);

  ln_fused<<<4096, 256, 0, stream>>>(x, ln1g, ln1b, h_f32, h_bf);

  // QKV projection: M=4096, N=3072, K=1024  (grid 12*32=384, %8==0)
  gemm_bt<0><<<dim3(12, 32), 512, 0, stream>>>(h_bf, wqkvT, 3072, 1024, 1024,
      nullptr, bq, bk, bv, qb, kb, vtb, nullptr, nullptr, nullptr, nullptr, nullptr);

  flash_attn<<<dim3(4, 16, 32), 256, 0, stream>>>(qb, kb, vtb, Opart, Lpart);

  // LN2 + KV-split merge fused: z = LN(h + sum(O)/sum(l))
  ln2_merge_fused<<<4096, 256, 0, stream>>>(h_f32, Opart, Lpart, ln2g, ln2b, z_f32, z_bf);

  // FFN1: relu(z @ w1 + b1), M=4096, N=4096, K=1024  (grid 16*32=512, %8==0)
  gemm_bt<1><<<dim3(16, 32), 512, 0, stream>>>(z_bf, w1T, 4096, 1024, 1024,
      b1, nullptr, nullptr, nullptr, nullptr, nullptr, nullptr, ff1, nullptr, nullptr, nullptr, nullptr);

  // FFN2 split-K=4 (1024 each), f32 partials: M=4096, N=1024, K=4096 (grid 4*32*4=512)
  gemm_bt<2><<<dim3(4, 32, 4), 512, 0, stream>>>(ff1, w2T, 1024, 4096, 1024,
      nullptr, nullptr, nullptr, nullptr, nullptr, nullptr, nullptr, nullptr, p0, p1, p2, p3);

  // out = z + b2 + p0 + p1 + p2 + p3
  ffn2_merge<<<4096, 256, 0, stream>>>(p0, p1, p2, p3, z_f32, b2, out);
}

// Round 20
// 229.153 us; speedup vs baseline: 1.4389x; 1.0342x over previous
//
#include <hip/hip_runtime.h>
#include <hip/hip_bf16.h>
#include <cstdint>
#include <cstddef>

typedef __attribute__((ext_vector_type(8))) short bf16x8;
typedef __attribute__((ext_vector_type(4))) float f32x4;
typedef __attribute__((ext_vector_type(4))) short short4v;
typedef __attribute__((ext_vector_type(2))) unsigned int uint2v;

__device__ inline void gload_lds16(const void* g, void* l) {
  __builtin_amdgcn_global_load_lds((const __attribute__((address_space(1))) void*)g,
                                   (__attribute__((address_space(3))) void*)l, 16, 0, 0);
}

__device__ inline float exp2_fast(float x) {
  float r;
  asm volatile("v_exp_f32 %0, %1" : "=v"(r) : "v"(x));
  return r;
}

__device__ inline unsigned int cvt_pk_bf16(float lo, float hi) {
  unsigned int r;
  asm volatile("v_cvt_pk_bf16_f32 %0, %1, %2" : "=v"(r) : "v"(lo), "v"(hi));
  return r;
}

__device__ inline float bf2f(short s) {
  return __uint_as_float(((unsigned int)(unsigned short)s) << 16);
}

// -------------------- transpose fp32 [R][C] -> bf16 [C][R] --------------------
__global__ void transpose_pack(const float* __restrict__ src, __hip_bfloat16* __restrict__ dst,
                               int R, int C, int ldDst, long zSrcStride, int zDstRow)
{
  __shared__ float tile[64][65];
  src += (size_t)blockIdx.z * zSrcStride;
  const int r0 = blockIdx.y * 64, c0 = blockIdx.x * 64;
  const int t = threadIdx.x;
#pragma unroll
  for (int i = 0; i < 16; ++i) {
    int idx = i * 256 + t;
    int r = idx >> 6, c = idx & 63;
    tile[r][c] = src[(size_t)(r0 + r) * C + c0 + c];
  }
  __syncthreads();
  const int drow0 = blockIdx.z * zDstRow + c0;
#pragma unroll
  for (int i = 0; i < 16; ++i) {
    int idx = i * 256 + t;
    int cc = idx >> 6, rr = idx & 63;
    dst[(size_t)(drow0 + cc) * ldDst + r0 + rr] = __float2bfloat16(tile[rr][cc]);
  }
}

// ------------- merged QKV weight transpose: wq/wk/wv [16][1024][64] -> [3072][1024] ----
__global__ void transpose_qkv(const float* __restrict__ wq, const float* __restrict__ wk,
                              const float* __restrict__ wv, __hip_bfloat16* __restrict__ dst)
{
  __shared__ float tile[64][65];
  const int z = blockIdx.z;              // grid (1,16,48)
  const int seg = z >> 4, h = z & 15;
  const float* src = (seg == 0) ? wq : (seg == 1) ? wk : wv;
  src += (size_t)h * 65536;
  const int r0 = blockIdx.y * 64;
  const int t = threadIdx.x;
#pragma unroll
  for (int i = 0; i < 16; ++i) {
    int idx = i * 256 + t;
    int r = idx >> 6, c = idx & 63;
    tile[r][c] = src[(size_t)(r0 + r) * 64 + c];
  }
  __syncthreads();
  const int drow0 = seg * 1024 + h * 64;
#pragma unroll
  for (int i = 0; i < 16; ++i) {
    int idx = i * 256 + t;
    int cc = idx >> 6, rr = idx & 63;
    dst[(size_t)(drow0 + cc) * 1024 + r0 + rr] = __float2bfloat16(tile[rr][cc]);
  }
}

// -------------------- LN1: LayerNorm(x) -> f32 + bf16 --------------------
__global__ void ln_fused(const float* __restrict__ x,
                         const float* __restrict__ g, const float* __restrict__ bta,
                         float* __restrict__ of32, __hip_bfloat16* __restrict__ obf)
{
  const int row = blockIdx.x;
  const int t = threadIdx.x;
  float4 v = ((const float4*)(x + (size_t)row * 1024))[t];
  float s = v.x + v.y + v.z + v.w;
  float ss = v.x * v.x + v.y * v.y + v.z * v.z + v.w * v.w;
#pragma unroll
  for (int off = 1; off < 64; off <<= 1) {
    s += __shfl_xor(s, off);
    ss += __shfl_xor(ss, off);
  }
  __shared__ float sb[4], ssb[4];
  const int w = t >> 6, lane = t & 63;
  if (lane == 0) { sb[w] = s; ssb[w] = ss; }
  __syncthreads();
  s = sb[0] + sb[1] + sb[2] + sb[3];
  ss = ssb[0] + ssb[1] + ssb[2] + ssb[3];
  const float mu = s * (1.f / 1024.f);
  const float var = ss * (1.f / 1024.f) - mu * mu;
  const float rstd = rsqrtf(var + 1e-5f);
  float4 gv = ((const float4*)g)[t];
  float4 bv = ((const float4*)bta)[t];
  float4 o;
  o.x = (v.x - mu) * rstd * gv.x + bv.x;
  o.y = (v.y - mu) * rstd * gv.y + bv.y;
  o.z = (v.z - mu) * rstd * gv.z + bv.z;
  o.w = (v.w - mu) * rstd * gv.w + bv.w;
  ((float4*)(of32 + (size_t)row * 1024))[t] = o;
  __hip_bfloat16 hb[4] = { __float2bfloat16(o.x), __float2bfloat16(o.y),
                           __float2bfloat16(o.z), __float2bfloat16(o.w) };
  *(short4v*)(obf + (size_t)row * 1024 + t * 4) = *(const short4v*)hb;
}

// ---------- LN2 fused with KV-split merge: y = h + sum(O)/sum(l); z = LN(y) ----------
__global__ void ln2_merge_fused(const float* __restrict__ hres,
                                const __hip_bfloat16* __restrict__ Opart,
                                const float* __restrict__ Lpart,
                                const float* __restrict__ g, const float* __restrict__ bta,
                                float* __restrict__ of32, __hip_bfloat16* __restrict__ obf)
{
  const int row = blockIdx.x;            // b*2048 + t
  const int b = row >> 11, tt = row & 2047;
  const int qblk = tt >> 7, qloc = tt & 127;
  const int nch = (qblk >> 2) + 1;
  const int t = threadIdx.x;
  const int hd = t >> 4;                 // head (4 cols per thread, within one head)
  const int d0 = (t & 15) * 4;
  const int base = ((b * 16 + hd) * 16 + qblk) << 2;

  float4 v = ((const float4*)(hres + (size_t)row * 1024))[t];
  float l = 0.f;
  float o0 = 0.f, o1 = 0.f, o2 = 0.f, o3 = 0.f;
  for (int ch = 0; ch < nch; ++ch) {     // nch uniform per block (row)
    l += Lpart[(size_t)(base + ch) * 128 + qloc];
    short4v o4 = *(const short4v*)(Opart + (size_t)(base + ch) * 8192 + qloc * 64 + d0);
    o0 += bf2f(o4[0]); o1 += bf2f(o4[1]); o2 += bf2f(o4[2]); o3 += bf2f(o4[3]);
  }
  const float inv = 1.f / l;
  v.x += o0 * inv; v.y += o1 * inv; v.z += o2 * inv; v.w += o3 * inv;

  float s = v.x + v.y + v.z + v.w;
  float ss = v.x * v.x + v.y * v.y + v.z * v.z + v.w * v.w;
#pragma unroll
  for (int off = 1; off < 64; off <<= 1) {
    s += __shfl_xor(s, off);
    ss += __shfl_xor(ss, off);
  }
  __shared__ float sb[4], ssb[4];
  const int w = t >> 6, lane = t & 63;
  if (lane == 0) { sb[w] = s; ssb[w] = ss; }
  __syncthreads();
  s = sb[0] + sb[1] + sb[2] + sb[3];
  ss = ssb[0] + ssb[1] + ssb[2] + ssb[3];
  const float mu = s * (1.f / 1024.f);
  const float var = ss * (1.f / 1024.f) - mu * mu;
  const float rstd = rsqrtf(var + 1e-5f);
  float4 gv = ((const float4*)g)[t];
  float4 bv = ((const float4*)bta)[t];
  float4 o;
  o.x = (v.x - mu) * rstd * gv.x + bv.x;
  o.y = (v.y - mu) * rstd * gv.y + bv.y;
  o.z = (v.z - mu) * rstd * gv.z + bv.z;
  o.w = (v.w - mu) * rstd * gv.w + bv.w;
  ((float4*)(of32 + (size_t)row * 1024))[t] = o;
  __hip_bfloat16 hb[4] = { __float2bfloat16(o.x), __float2bfloat16(o.y),
                           __float2bfloat16(o.z), __float2bfloat16(o.w) };
  *(short4v*)(obf + (size_t)row * 1024 + t * 4) = *(const short4v*)hb;
}

// -------------------- GEMM (R14 green): 8 waves, BM=128 BN=256 BK=32 ------------------
// 2-deep dbuf + vmcnt(3), + T1 XCD-aware chunked blockIdx swizzle.
// EPI 2 now writes bf16 partials (halves FFN2-merge read traffic).
template<int EPI>
__global__ __launch_bounds__(512, 2) void gemm_bt(
    const __hip_bfloat16* __restrict__ A, const __hip_bfloat16* __restrict__ Bt,
    int N, int Kf, int kLen,
    const float* __restrict__ bias,
    const float* __restrict__ bq, const float* __restrict__ bk, const float* __restrict__ bv,
    __hip_bfloat16* __restrict__ oq, __hip_bfloat16* __restrict__ ok, __hip_bfloat16* __restrict__ ovt,
    __hip_bfloat16* __restrict__ obf,
    __hip_bfloat16* __restrict__ opart0, __hip_bfloat16* __restrict__ opart1,
    __hip_bfloat16* __restrict__ opart2, __hip_bfloat16* __restrict__ opart3)
{
  __shared__ short As[2][128 * 32];   //  8 KB per buf
  __shared__ short Bs[2][256 * 32];   // 16 KB per buf
  const int t = threadIdx.x;
  const int lane = t & 63;
  const int w = t >> 6;               // 0..7
  const int wm = w >> 2, wn = w & 3;  // 2 x 4 wave grid
  const int l15 = lane & 15, lg = lane >> 4;

  const int nwg = (int)(gridDim.x * gridDim.y);
  int wgid = (int)blockIdx.y * (int)gridDim.x + (int)blockIdx.x;
  wgid = (wgid & 7) * (nwg >> 3) + (wgid >> 3);
  const int bx = wgid % (int)gridDim.x;
  const int by = wgid / (int)gridDim.x;
  const int m0 = by * 128;
  const int n0 = bx * 256;
  const int kBase = (EPI == 2) ? (int)blockIdx.z * kLen : 0;
  const int kEnd0 = kBase + kLen;
  const int kEnd = (kEnd0 > Kf) ? Kf : kEnd0;

  f32x4 acc[4][4];
#pragma unroll
  for (int i = 0; i < 4; ++i)
#pragma unroll
    for (int j = 0; j < 4; ++j)
#pragma unroll
      for (int e = 0; e < 4; ++e) acc[i][j][e] = 0.f;

  auto STAGE = [&](int buf, int kk0) {
    {
      const int r = t >> 2, cc = t & 3;
      const int kk = (cc ^ ((r >> 1) & 3)) * 8;
      gload_lds16(A + (size_t)(m0 + r) * Kf + kk0 + kk, (char*)As + buf * 8192 + t * 16);
    }
#pragma unroll
    for (int i = 0; i < 2; ++i) {
      const int c = t + 512 * i;
      const int r = c >> 2, cc = c & 3;
      const int kk = (cc ^ ((r >> 1) & 3)) * 8;
      gload_lds16(Bt + (size_t)(n0 + r) * Kf + kk0 + kk, (char*)Bs + buf * 16384 + c * 16);
    }
  };

  STAGE(0, kBase);
  int buf = 0;
  for (int k0 = kBase; k0 < kEnd; k0 += 32) {
    const int knext = (k0 + 32 < kEnd) ? k0 + 32 : k0;
    STAGE(buf ^ 1, knext);
    asm volatile("s_waitcnt vmcnt(3)" ::: "memory");
    __builtin_amdgcn_s_barrier();
    asm volatile("" ::: "memory");

    bf16x8 af[4], bfr[4];
#pragma unroll
    for (int fm = 0; fm < 4; ++fm) {
      const int r = wm * 64 + fm * 16 + l15;
      const int kc = lg ^ ((r >> 1) & 3);
      af[fm] = *(const bf16x8*)&As[buf][r * 32 + kc * 8];
    }
#pragma unroll
    for (int fn = 0; fn < 4; ++fn) {
      const int r = wn * 64 + fn * 16 + l15;
      const int kc = lg ^ ((r >> 1) & 3);
      bfr[fn] = *(const bf16x8*)&Bs[buf][r * 32 + kc * 8];
    }
#pragma unroll
    for (int fm = 0; fm < 4; ++fm)
#pragma unroll
      for (int fn = 0; fn < 4; ++fn)
        acc[fm][fn] = __builtin_amdgcn_mfma_f32_16x16x32_bf16(af[fm], bfr[fn], acc[fm][fn], 0, 0, 0);

    asm volatile("" ::: "memory");
    __builtin_amdgcn_s_barrier();
    buf ^= 1;
  }

  // epilogue: C row = (lg*4 + rg), col = l15 within each 16x16 fragment
#pragma unroll
  for (int fm = 0; fm < 4; ++fm) {
    const int mbase = m0 + wm * 64 + fm * 16 + lg * 4;
#pragma unroll
    for (int fn = 0; fn < 4; ++fn) {
      const int n = n0 + wn * 64 + fn * 16 + l15;
      if (EPI == 0) {
        const int seg = n >> 10;
        const int cn = n & 1023;
        const int h = cn >> 6, d = cn & 63;
        const float* bp = (seg == 0) ? bq : (seg == 1) ? bk : bv;
        const float bias_v = bp[cn];
#pragma unroll
        for (int rg = 0; rg < 4; ++rg) {
          const int m = mbase + rg;
          const int b = m >> 11, tt = m & 2047;
          const size_t bh = (size_t)(b * 16 + h);
          const float val = acc[fm][fn][rg] + bias_v;
          if (seg == 0)      oq[(bh * 2048 + tt) * 64 + d] = __float2bfloat16(val);
          else if (seg == 1) ok[(bh * 2048 + tt) * 64 + d] = __float2bfloat16(val);
          else               ovt[(bh * 64 + d) * 2048 + tt] = __float2bfloat16(val);
        }
      } else if (EPI == 1) {
        const float bias_v = bias[n];
#pragma unroll
        for (int rg = 0; rg < 4; ++rg) {
          const int m = mbase + rg;
          float val = acc[fm][fn][rg] + bias_v;
          val = fmaxf(val, 0.f);
          obf[(size_t)m * N + n] = __float2bfloat16(val);
        }
      } else {
        __hip_bfloat16* op = (blockIdx.z == 0) ? opart0 : (blockIdx.z == 1) ? opart1
                           : (blockIdx.z == 2) ? opart2 : opart3;
#pragma unroll
        for (int rg = 0; rg < 4; ++rg) {
          const int m = mbase + rg;
          op[(size_t)m * 1024 + n] = __float2bfloat16(acc[fm][fn][rg]);
        }
      }
    }
  }
}

// -------------------- FFN2 merge: out = z + b2 + p0 + p1 + p2 + p3 (bf16 partials) ----
__global__ void ffn2_merge(const __hip_bfloat16* __restrict__ p0, const __hip_bfloat16* __restrict__ p1,
                           const __hip_bfloat16* __restrict__ p2, const __hip_bfloat16* __restrict__ p3,
                           const float* __restrict__ z, const float* __restrict__ b2,
                           float* __restrict__ out)
{
  const size_t i = ((size_t)blockIdx.x * 256 + threadIdx.x) * 4;
  const float4 c = *(const float4*)(z + i);
  const float4 bb = *(const float4*)(b2 + (i & 1023));
  float o0 = c.x + bb.x, o1 = c.y + bb.y, o2 = c.z + bb.z, o3 = c.w + bb.w;
  short4v a0 = *(const short4v*)(p0 + i);
  short4v a1 = *(const short4v*)(p1 + i);
  short4v a2 = *(const short4v*)(p2 + i);
  short4v a3 = *(const short4v*)(p3 + i);
  o0 += bf2f(a0[0]) + bf2f(a1[0]) + bf2f(a2[0]) + bf2f(a3[0]);
  o1 += bf2f(a0[1]) + bf2f(a1[1]) + bf2f(a2[1]) + bf2f(a3[1]);
  o2 += bf2f(a0[2]) + bf2f(a1[2]) + bf2f(a2[2]) + bf2f(a3[2]);
  o3 += bf2f(a0[3]) + bf2f(a1[3]) + bf2f(a2[3]) + bf2f(a3[3]);
  float4 o; o.x = o0; o.y = o1; o.z = o2; o.w = o3;
  *(float4*)(out + i) = o;
}

// ---------- flash attention (R14 green + T5 setprio + heavy-first qblk order) --------
__global__ __launch_bounds__(256, 3) void flash_attn(
    const __hip_bfloat16* __restrict__ Q, const __hip_bfloat16* __restrict__ Kb,
    const __hip_bfloat16* __restrict__ Vt,
    __hip_bfloat16* __restrict__ Opart, float* __restrict__ Lpart)
{
  __shared__ short Ks[2][64 * 64];
  __shared__ short Vs[2][64 * 64];
  __shared__ short P2[4][32 * 72];
  const int t = threadIdx.x;
  const int lane = t & 63, w = t >> 6;
  const int l15 = lane & 15, lg = lane >> 4;
  const int chunk = blockIdx.x, bh = blockIdx.z;
  const int qblk = 15 - (int)blockIdx.y;   // heavy blocks (large qblk) dispatch first
  const int q0 = qblk * 128;
  const int s_base = chunk * 512;
  if (s_base > q0 + 127) return;
  const int s_hi = (s_base + 512 < q0 + 128) ? s_base + 512 : q0 + 128;
  const int ntiles = (s_hi - s_base) >> 6;
  const int qw = q0 + w * 32;

  const __hip_bfloat16* Qbh = Q + (size_t)bh * 2048 * 64;
  const __hip_bfloat16* Kbh = Kb + (size_t)bh * 2048 * 64;
  const __hip_bfloat16* Vbh = Vt + (size_t)bh * 64 * 2048;

  bf16x8 qf[2][2];
#pragma unroll
  for (int fm = 0; fm < 2; ++fm)
#pragma unroll
    for (int kc = 0; kc < 2; ++kc)
      qf[fm][kc] = *(const bf16x8*)(Qbh + (size_t)(qw + fm * 16 + l15) * 64 + kc * 32 + lg * 8);

  const int srow = (w << 4) + (lane >> 3);
  const int schunk = ((lane & 7) ^ (lane >> 3)) * 8;

  auto STAGE = [&](int bufi, int s0) {
#pragma unroll
    for (int i = 0; i < 2; ++i) {
      const int r = srow + i * 8;
      const int dst = bufi * 8192 + w * 2048 + i * 1024 + lane * 16;
      gload_lds16(Kbh + (size_t)(s0 + r) * 64 + schunk, (char*)Ks + dst);
      gload_lds16(Vbh + (size_t)r * 2048 + s0 + schunk, (char*)Vs + dst);
    }
  };

  f32x4 o_acc[2][4];
  float lpart[2] = {0.f, 0.f};
#pragma unroll
  for (int fm = 0; fm < 2; ++fm)
#pragma unroll
    for (int fd = 0; fd < 4; ++fd)
#pragma unroll
      for (int e = 0; e < 4; ++e) o_acc[fm][fd][e] = 0.f;

  const float C = 0.18033688011112042f;   // 0.125 * log2(e)

  STAGE(0, s_base);
  int cur = 0;
  for (int ti = 0; ti < ntiles; ++ti) {
    const int s0 = s_base + ti * 64;
    const int nxt = (ti + 1 < ntiles) ? s0 + 64 : s0;
    STAGE(cur ^ 1, nxt);
    asm volatile("s_waitcnt vmcnt(4)" ::: "memory");
    __builtin_amdgcn_s_barrier();
    asm volatile("" ::: "memory");

    if (s0 <= qw + 31) {
      f32x4 s_acc[2][4];
#pragma unroll
      for (int fm = 0; fm < 2; ++fm)
#pragma unroll
        for (int fn = 0; fn < 4; ++fn)
#pragma unroll
          for (int e = 0; e < 4; ++e) s_acc[fm][fn][e] = 0.f;
      __builtin_amdgcn_s_setprio(1);
#pragma unroll
      for (int kc = 0; kc < 2; ++kc)
#pragma unroll
        for (int fn = 0; fn < 4; ++fn) {
          const int r = fn * 16 + l15;
          bf16x8 kf = *(const bf16x8*)&Ks[cur][r * 64 + ((((kc << 2) | lg) ^ (l15 & 7)) << 3)];
          s_acc[0][fn] = __builtin_amdgcn_mfma_f32_16x16x32_bf16(kf, qf[0][kc], s_acc[0][fn], 0, 0, 0);
          s_acc[1][fn] = __builtin_amdgcn_mfma_f32_16x16x32_bf16(kf, qf[1][kc], s_acc[1][fn], 0, 0, 0);
        }
      __builtin_amdgcn_s_setprio(0);

      const bool needmask = (s0 + 63 > qw);
      float pr[2][4][4];
#pragma unroll
      for (int fm = 0; fm < 2; ++fm) {
        const int qv = qw + fm * 16 + l15;
#pragma unroll
        for (int fn = 0; fn < 4; ++fn)
#pragma unroll
          for (int rg = 0; rg < 4; ++rg) {
            float p = exp2_fast(s_acc[fm][fn][rg] * C);
            if (needmask) {
              const int sg = s0 + fn * 16 + lg * 4 + rg;
              p = (sg <= qv) ? p : 0.f;
            }
            pr[fm][fn][rg] = p;
            lpart[fm] += p;
          }
      }

#pragma unroll
      for (int fm = 0; fm < 2; ++fm)
#pragma unroll
        for (int fn = 0; fn < 4; ++fn) {
          uint2v u;
          u.x = cvt_pk_bf16(pr[fm][fn][0], pr[fm][fn][1]);
          u.y = cvt_pk_bf16(pr[fm][fn][2], pr[fm][fn][3]);
          *(uint2v*)&P2[w][(fm * 16 + l15) * 72 + fn * 16 + lg * 4] = u;
        }

      __builtin_amdgcn_s_setprio(1);
#pragma unroll
      for (int kc = 0; kc < 2; ++kc) {
        bf16x8 pf0 = *(const bf16x8*)&P2[w][(l15) * 72 + kc * 32 + lg * 8];
        bf16x8 pf1 = *(const bf16x8*)&P2[w][(16 + l15) * 72 + kc * 32 + lg * 8];
#pragma unroll
        for (int fd = 0; fd < 4; ++fd) {
          const int r = fd * 16 + l15;
          bf16x8 vf = *(const bf16x8*)&Vs[cur][r * 64 + ((((kc << 2) | lg) ^ (l15 & 7)) << 3)];
          o_acc[0][fd] = __builtin_amdgcn_mfma_f32_16x16x32_bf16(vf, pf0, o_acc[0][fd], 0, 0, 0);
          o_acc[1][fd] = __builtin_amdgcn_mfma_f32_16x16x32_bf16(vf, pf1, o_acc[1][fd], 0, 0, 0);
        }
      }
      __builtin_amdgcn_s_setprio(0);
    }

    asm volatile("" ::: "memory");
    __builtin_amdgcn_s_barrier();
    cur ^= 1;
  }

  const int pslot = ((bh * 16 + qblk) << 2) + chunk;
  __hip_bfloat16* op = Opart + (size_t)pslot * 8192;
#pragma unroll
  for (int fm = 0; fm < 2; ++fm) {
    float l = lpart[fm];
    l += __shfl_xor(l, 16);
    l += __shfl_xor(l, 32);
    const int qloc = w * 32 + fm * 16 + l15;
    if (lg == 0) Lpart[pslot * 128 + qloc] = l;
#pragma unroll
    for (int fd = 0; fd < 4; ++fd) {
      uint2v u;
      u.x = cvt_pk_bf16(o_acc[fm][fd][0], o_acc[fm][fd][1]);
      u.y = cvt_pk_bf16(o_acc[fm][fd][2], o_acc[fm][fd][3]);
      *(uint2v*)(op + (size_t)qloc * 64 + fd * 16 + lg * 4) = u;
    }
  }
}

// -------------------- launch --------------------
extern "C" void kernel_launch(void* const* d_in, const int* in_sizes, int n_in,
                              void* d_out, int out_size, void* d_ws, size_t ws_size,
                              hipStream_t stream) {
  const float* x    = (const float*)d_in[0];
  const float* wq   = (const float*)d_in[1];
  const float* bq   = (const float*)d_in[2];
  const float* wk   = (const float*)d_in[3];
  const float* bk   = (const float*)d_in[4];
  const float* wv   = (const float*)d_in[5];
  const float* bv   = (const float*)d_in[6];
  const float* ln1g = (const float*)d_in[7];
  const float* ln1b = (const float*)d_in[8];
  const float* ln2g = (const float*)d_in[9];
  const float* ln2b = (const float*)d_in[10];
  const float* w1   = (const float*)d_in[11];
  const float* b1   = (const float*)d_in[12];
  const float* w2   = (const float*)d_in[13];
  const float* b2   = (const float*)d_in[14];
  float* out = (float*)d_out;

  char* ws = (char*)d_ws;
  const size_t MB = 1024 * 1024;
  // Phase-checked layout (MB offsets):
  // h_bf  [0,8)    LN1->QKV          z_f32 [0,16)   LN2->ffn2_merge (h_bf,qb dead)
  // qb[8,16) kb[16,24) vtb[24,32)    QKV->flash     z_bf [16,24)  LN2->FFN1 (kb dead)
  // h_f32 [32,48)  LN1->LN2 (dead after LN2)
  // Opart [48,80)  flash->LN2 (dead after LN2 -> bf16 FFN2 partials p0..p3 [48,80))
  // Lpart [80,81)  flash->LN2        ff1 [24,56)?  NO: ff1 [24,56) overlaps p0!
  //   -> ff1 stays [24,56)... p0..p3 must avoid ff1 (live until FFN2 done):
  //      p0[48,56) overlaps ff1 [24,56) tail! ff1 is 4096*4096*2 = 32 MB = [24,56).
  //      So p0 goes [56,64), p1[64,72), p2[72,80), p3[32,40) (h_f32 dead region).
  __hip_bfloat16* h_bf  = (__hip_bfloat16*)(ws + 0);
  float* z_f32          = (float*)(ws + 0);
  __hip_bfloat16* qb    = (__hip_bfloat16*)(ws + 8 * MB);
  __hip_bfloat16* kb    = (__hip_bfloat16*)(ws + 16 * MB);
  __hip_bfloat16* z_bf  = (__hip_bfloat16*)(ws + 16 * MB);
  __hip_bfloat16* vtb   = (__hip_bfloat16*)(ws + 24 * MB);
  __hip_bfloat16* ff1   = (__hip_bfloat16*)(ws + 24 * MB);
  float* h_f32          = (float*)(ws + 32 * MB);
  __hip_bfloat16* p3    = (__hip_bfloat16*)(ws + 32 * MB);
  __hip_bfloat16* Opart = (__hip_bfloat16*)(ws + 48 * MB);
  __hip_bfloat16* p0    = (__hip_bfloat16*)(ws + 56 * MB);
  __hip_bfloat16* p1    = (__hip_bfloat16*)(ws + 64 * MB);
  __hip_bfloat16* p2    = (__hip_bfloat16*)(ws + 72 * MB);
  float* Lpart          = (float*)(ws + 80 * MB);
  __hip_bfloat16* wqkvT = (__hip_bfloat16*)(ws + 88 * MB);
  __hip_bfloat16* w1T   = (__hip_bfloat16*)(ws + 96 * MB);
  __hip_bfloat16* w2T   = (__hip_bfloat16*)(ws + 104 * MB);

  transpose_qkv<<<dim3(1, 16, 48), 256, 0, stream>>>(wq, wk, wv, wqkvT);
  transpose_pack<<<dim3(64, 16, 1), 256, 0, stream>>>(w1, w1T, 1024, 4096, 1024, 0, 0);
  transpose_pack<<<dim3(16, 64, 1), 256, 0, stream>>>(w2, w2T, 4096, 1024, 4096, 0, 0);

  ln_fused<<<4096, 256, 0, stream>>>(x, ln1g, ln1b, h_f32, h_bf);

  // QKV projection: M=4096, N=3072, K=1024  (grid 12*32=384, %8==0)
  gemm_bt<0><<<dim3(12, 32), 512, 0, stream>>>(h_bf, wqkvT, 3072, 1024, 1024,
      nullptr, bq, bk, bv, qb, kb, vtb, nullptr, nullptr, nullptr, nullptr, nullptr);

  flash_attn<<<dim3(4, 16, 32), 256, 0, stream>>>(qb, kb, vtb, Opart, Lpart);

  // LN2 + KV-split merge fused: z = LN(h + sum(O)/sum(l))
  ln2_merge_fused<<<4096, 256, 0, stream>>>(h_f32, Opart, Lpart, ln2g, ln2b, z_f32, z_bf);

  // FFN1: relu(z @ w1 + b1), M=4096, N=4096, K=1024  (grid 16*32=512, %8==0)
  gemm_bt<1><<<dim3(16, 32), 512, 0, stream>>>(z_bf, w1T, 4096, 1024, 1024,
      b1, nullptr, nullptr, nullptr, nullptr, nullptr, nullptr, ff1, nullptr, nullptr, nullptr, nullptr);

  // FFN2 split-K=4 (1024 each), bf16 partials: M=4096, N=1024, K=4096 (grid 4*32*4=512)
  gemm_bt<2><<<dim3(4, 32, 4), 512, 0, stream>>>(ff1, w2T, 1024, 4096, 1024,
      nullptr, nullptr, nullptr, nullptr, nullptr, nullptr, nullptr, nullptr, p0, p1, p2, p3);

  // out = z + b2 + p0 + p1 + p2 + p3
  ffn2_merge<<<4096, 256, 0, stream>>>(p0, p1, p2, p3, z_f32, b2, out);
}

// Round 21
// 226.427 us; speedup vs baseline: 1.4562x; 1.0120x over previous
//
#include <hip/hip_runtime.h>
#include <hip/hip_bf16.h>
#include <cstdint>
#include <cstddef>

typedef __attribute__((ext_vector_type(8))) short bf16x8;
typedef __attribute__((ext_vector_type(4))) float f32x4;
typedef __attribute__((ext_vector_type(4))) short short4v;
typedef __attribute__((ext_vector_type(2))) unsigned int uint2v;

__device__ inline void gload_lds16(const void* g, void* l) {
  __builtin_amdgcn_global_load_lds((const __attribute__((address_space(1))) void*)g,
                                   (__attribute__((address_space(3))) void*)l, 16, 0, 0);
}

__device__ inline float exp2_fast(float x) {
  float r;
  asm volatile("v_exp_f32 %0, %1" : "=v"(r) : "v"(x));
  return r;
}

__device__ inline unsigned int cvt_pk_bf16(float lo, float hi) {
  unsigned int r;
  asm volatile("v_cvt_pk_bf16_f32 %0, %1, %2" : "=v"(r) : "v"(lo), "v"(hi));
  return r;
}

__device__ inline float bf2f(short s) {
  return __uint_as_float(((unsigned int)(unsigned short)s) << 16);
}

// -------------------- transpose fp32 [R][C] -> bf16 [C][R] --------------------
__global__ void transpose_pack(const float* __restrict__ src, __hip_bfloat16* __restrict__ dst,
                               int R, int C, int ldDst, long zSrcStride, int zDstRow)
{
  __shared__ float tile[64][65];
  src += (size_t)blockIdx.z * zSrcStride;
  const int r0 = blockIdx.y * 64, c0 = blockIdx.x * 64;
  const int t = threadIdx.x;
#pragma unroll
  for (int i = 0; i < 16; ++i) {
    int idx = i * 256 + t;
    int r = idx >> 6, c = idx & 63;
    tile[r][c] = src[(size_t)(r0 + r) * C + c0 + c];
  }
  __syncthreads();
  const int drow0 = blockIdx.z * zDstRow + c0;
#pragma unroll
  for (int i = 0; i < 16; ++i) {
    int idx = i * 256 + t;
    int cc = idx >> 6, rr = idx & 63;
    dst[(size_t)(drow0 + cc) * ldDst + r0 + rr] = __float2bfloat16(tile[rr][cc]);
  }
}

// ------------- merged QKV weight transpose: wq/wk/wv [16][1024][64] -> [3072][1024] ----
__global__ void transpose_qkv(const float* __restrict__ wq, const float* __restrict__ wk,
                              const float* __restrict__ wv, __hip_bfloat16* __restrict__ dst)
{
  __shared__ float tile[64][65];
  const int z = blockIdx.z;              // grid (1,16,48)
  const int seg = z >> 4, h = z & 15;
  const float* src = (seg == 0) ? wq : (seg == 1) ? wk : wv;
  src += (size_t)h * 65536;
  const int r0 = blockIdx.y * 64;
  const int t = threadIdx.x;
#pragma unroll
  for (int i = 0; i < 16; ++i) {
    int idx = i * 256 + t;
    int r = idx >> 6, c = idx & 63;
    tile[r][c] = src[(size_t)(r0 + r) * 64 + c];
  }
  __syncthreads();
  const int drow0 = seg * 1024 + h * 64;
#pragma unroll
  for (int i = 0; i < 16; ++i) {
    int idx = i * 256 + t;
    int cc = idx >> 6, rr = idx & 63;
    dst[(size_t)(drow0 + cc) * 1024 + r0 + rr] = __float2bfloat16(tile[rr][cc]);
  }
}

// -------------------- LN1: LayerNorm(x) -> f32 + bf16 --------------------
__global__ void ln_fused(const float* __restrict__ x,
                         const float* __restrict__ g, const float* __restrict__ bta,
                         float* __restrict__ of32, __hip_bfloat16* __restrict__ obf)
{
  const int row = blockIdx.x;
  const int t = threadIdx.x;
  float4 v = ((const float4*)(x + (size_t)row * 1024))[t];
  float s = v.x + v.y + v.z + v.w;
  float ss = v.x * v.x + v.y * v.y + v.z * v.z + v.w * v.w;
#pragma unroll
  for (int off = 1; off < 64; off <<= 1) {
    s += __shfl_xor(s, off);
    ss += __shfl_xor(ss, off);
  }
  __shared__ float sb[4], ssb[4];
  const int w = t >> 6, lane = t & 63;
  if (lane == 0) { sb[w] = s; ssb[w] = ss; }
  __syncthreads();
  s = sb[0] + sb[1] + sb[2] + sb[3];
  ss = ssb[0] + ssb[1] + ssb[2] + ssb[3];
  const float mu = s * (1.f / 1024.f);
  const float var = ss * (1.f / 1024.f) - mu * mu;
  const float rstd = rsqrtf(var + 1e-5f);
  float4 gv = ((const float4*)g)[t];
  float4 bv = ((const float4*)bta)[t];
  float4 o;
  o.x = (v.x - mu) * rstd * gv.x + bv.x;
  o.y = (v.y - mu) * rstd * gv.y + bv.y;
  o.z = (v.z - mu) * rstd * gv.z + bv.z;
  o.w = (v.w - mu) * rstd * gv.w + bv.w;
  ((float4*)(of32 + (size_t)row * 1024))[t] = o;
  __hip_bfloat16 hb[4] = { __float2bfloat16(o.x), __float2bfloat16(o.y),
                           __float2bfloat16(o.z), __float2bfloat16(o.w) };
  *(short4v*)(obf + (size_t)row * 1024 + t * 4) = *(const short4v*)hb;
}

// ---------- LN2 fused with KV-split merge: y = h + sum(O)/sum(l); z = LN(y) ----------
__global__ void ln2_merge_fused(const float* __restrict__ hres,
                                const __hip_bfloat16* __restrict__ Opart,
                                const float* __restrict__ Lpart,
                                const float* __restrict__ g, const float* __restrict__ bta,
                                float* __restrict__ of32, __hip_bfloat16* __restrict__ obf)
{
  const int row = blockIdx.x;            // b*2048 + t
  const int b = row >> 11, tt = row & 2047;
  const int qblk = tt >> 7, qloc = tt & 127;
  const int nch = (qblk >> 2) + 1;
  const int t = threadIdx.x;
  const int hd = t >> 4;                 // head (4 cols per thread, within one head)
  const int d0 = (t & 15) * 4;
  const int base = ((b * 16 + hd) * 16 + qblk) << 2;

  float4 v = ((const float4*)(hres + (size_t)row * 1024))[t];
  float l = 0.f;
  float o0 = 0.f, o1 = 0.f, o2 = 0.f, o3 = 0.f;
  for (int ch = 0; ch < nch; ++ch) {     // nch uniform per block (row)
    l += Lpart[(size_t)(base + ch) * 128 + qloc];
    short4v o4 = *(const short4v*)(Opart + (size_t)(base + ch) * 8192 + qloc * 64 + d0);
    o0 += bf2f(o4[0]); o1 += bf2f(o4[1]); o2 += bf2f(o4[2]); o3 += bf2f(o4[3]);
  }
  const float inv = 1.f / l;
  v.x += o0 * inv; v.y += o1 * inv; v.z += o2 * inv; v.w += o3 * inv;

  float s = v.x + v.y + v.z + v.w;
  float ss = v.x * v.x + v.y * v.y + v.z * v.z + v.w * v.w;
#pragma unroll
  for (int off = 1; off < 64; off <<= 1) {
    s += __shfl_xor(s, off);
    ss += __shfl_xor(ss, off);
  }
  __shared__ float sb[4], ssb[4];
  const int w = t >> 6, lane = t & 63;
  if (lane == 0) { sb[w] = s; ssb[w] = ss; }
  __syncthreads();
  s = sb[0] + sb[1] + sb[2] + sb[3];
  ss = ssb[0] + ssb[1] + ssb[2] + ssb[3];
  const float mu = s * (1.f / 1024.f);
  const float var = ss * (1.f / 1024.f) - mu * mu;
  const float rstd = rsqrtf(var + 1e-5f);
  float4 gv = ((const float4*)g)[t];
  float4 bv = ((const float4*)bta)[t];
  float4 o;
  o.x = (v.x - mu) * rstd * gv.x + bv.x;
  o.y = (v.y - mu) * rstd * gv.y + bv.y;
  o.z = (v.z - mu) * rstd * gv.z + bv.z;
  o.w = (v.w - mu) * rstd * gv.w + bv.w;
  ((float4*)(of32 + (size_t)row * 1024))[t] = o;
  __hip_bfloat16 hb[4] = { __float2bfloat16(o.x), __float2bfloat16(o.y),
                           __float2bfloat16(o.z), __float2bfloat16(o.w) };
  *(short4v*)(obf + (size_t)row * 1024 + t * 4) = *(const short4v*)hb;
}

// -------------------- GEMM (R14 green): 8 waves, BM=128 BN=256 BK=32 ------------------
// 2-deep dbuf + vmcnt(3), + T1 XCD-aware chunked blockIdx swizzle. EPI2: bf16 partials.
template<int EPI>
__global__ __launch_bounds__(512, 2) void gemm_bt(
    const __hip_bfloat16* __restrict__ A, const __hip_bfloat16* __restrict__ Bt,
    int N, int Kf, int kLen,
    const float* __restrict__ bias,
    const float* __restrict__ bq, const float* __restrict__ bk, const float* __restrict__ bv,
    __hip_bfloat16* __restrict__ oq, __hip_bfloat16* __restrict__ ok, __hip_bfloat16* __restrict__ ovt,
    __hip_bfloat16* __restrict__ obf,
    __hip_bfloat16* __restrict__ opart0, __hip_bfloat16* __restrict__ opart1,
    __hip_bfloat16* __restrict__ opart2, __hip_bfloat16* __restrict__ opart3)
{
  __shared__ short As[2][128 * 32];   //  8 KB per buf
  __shared__ short Bs[2][256 * 32];   // 16 KB per buf
  const int t = threadIdx.x;
  const int lane = t & 63;
  const int w = t >> 6;               // 0..7
  const int wm = w >> 2, wn = w & 3;  // 2 x 4 wave grid
  const int l15 = lane & 15, lg = lane >> 4;

  const int nwg = (int)(gridDim.x * gridDim.y);
  int wgid = (int)blockIdx.y * (int)gridDim.x + (int)blockIdx.x;
  wgid = (wgid & 7) * (nwg >> 3) + (wgid >> 3);
  const int bx = wgid % (int)gridDim.x;
  const int by = wgid / (int)gridDim.x;
  const int m0 = by * 128;
  const int n0 = bx * 256;
  const int kBase = (EPI == 2) ? (int)blockIdx.z * kLen : 0;
  const int kEnd0 = kBase + kLen;
  const int kEnd = (kEnd0 > Kf) ? Kf : kEnd0;

  f32x4 acc[4][4];
#pragma unroll
  for (int i = 0; i < 4; ++i)
#pragma unroll
    for (int j = 0; j < 4; ++j)
#pragma unroll
      for (int e = 0; e < 4; ++e) acc[i][j][e] = 0.f;

  auto STAGE = [&](int buf, int kk0) {
    {
      const int r = t >> 2, cc = t & 3;
      const int kk = (cc ^ ((r >> 1) & 3)) * 8;
      gload_lds16(A + (size_t)(m0 + r) * Kf + kk0 + kk, (char*)As + buf * 8192 + t * 16);
    }
#pragma unroll
    for (int i = 0; i < 2; ++i) {
      const int c = t + 512 * i;
      const int r = c >> 2, cc = c & 3;
      const int kk = (cc ^ ((r >> 1) & 3)) * 8;
      gload_lds16(Bt + (size_t)(n0 + r) * Kf + kk0 + kk, (char*)Bs + buf * 16384 + c * 16);
    }
  };

  STAGE(0, kBase);
  int buf = 0;
  for (int k0 = kBase; k0 < kEnd; k0 += 32) {
    const int knext = (k0 + 32 < kEnd) ? k0 + 32 : k0;
    STAGE(buf ^ 1, knext);
    asm volatile("s_waitcnt vmcnt(3)" ::: "memory");
    __builtin_amdgcn_s_barrier();
    asm volatile("" ::: "memory");

    bf16x8 af[4], bfr[4];
#pragma unroll
    for (int fm = 0; fm < 4; ++fm) {
      const int r = wm * 64 + fm * 16 + l15;
      const int kc = lg ^ ((r >> 1) & 3);
      af[fm] = *(const bf16x8*)&As[buf][r * 32 + kc * 8];
    }
#pragma unroll
    for (int fn = 0; fn < 4; ++fn) {
      const int r = wn * 64 + fn * 16 + l15;
      const int kc = lg ^ ((r >> 1) & 3);
      bfr[fn] = *(const bf16x8*)&Bs[buf][r * 32 + kc * 8];
    }
#pragma unroll
    for (int fm = 0; fm < 4; ++fm)
#pragma unroll
      for (int fn = 0; fn < 4; ++fn)
        acc[fm][fn] = __builtin_amdgcn_mfma_f32_16x16x32_bf16(af[fm], bfr[fn], acc[fm][fn], 0, 0, 0);

    asm volatile("" ::: "memory");
    __builtin_amdgcn_s_barrier();
    buf ^= 1;
  }

  // epilogue: C row = (lg*4 + rg), col = l15 within each 16x16 fragment
#pragma unroll
  for (int fm = 0; fm < 4; ++fm) {
    const int mbase = m0 + wm * 64 + fm * 16 + lg * 4;
#pragma unroll
    for (int fn = 0; fn < 4; ++fn) {
      const int n = n0 + wn * 64 + fn * 16 + l15;
      if (EPI == 0) {
        const int seg = n >> 10;
        const int cn = n & 1023;
        const int h = cn >> 6, d = cn & 63;
        const float* bp = (seg == 0) ? bq : (seg == 1) ? bk : bv;
        const float bias_v = bp[cn];
#pragma unroll
        for (int rg = 0; rg < 4; ++rg) {
          const int m = mbase + rg;
          const int b = m >> 11, tt = m & 2047;
          const size_t bh = (size_t)(b * 16 + h);
          const float val = acc[fm][fn][rg] + bias_v;
          if (seg == 0)      oq[(bh * 2048 + tt) * 64 + d] = __float2bfloat16(val);
          else if (seg == 1) ok[(bh * 2048 + tt) * 64 + d] = __float2bfloat16(val);
          else               ovt[(bh * 64 + d) * 2048 + tt] = __float2bfloat16(val);
        }
      } else if (EPI == 1) {
        const float bias_v = bias[n];
#pragma unroll
        for (int rg = 0; rg < 4; ++rg) {
          const int m = mbase + rg;
          float val = acc[fm][fn][rg] + bias_v;
          val = fmaxf(val, 0.f);
          obf[(size_t)m * N + n] = __float2bfloat16(val);
        }
      } else {
        __hip_bfloat16* op = (blockIdx.z == 0) ? opart0 : (blockIdx.z == 1) ? opart1
                           : (blockIdx.z == 2) ? opart2 : opart3;
#pragma unroll
        for (int rg = 0; rg < 4; ++rg) {
          const int m = mbase + rg;
          op[(size_t)m * 1024 + n] = __float2bfloat16(acc[fm][fn][rg]);
        }
      }
    }
  }
}

// -------------------- FFN2 merge: out = z + b2 + p0 + p1 + p2 + p3 (bf16 partials) ----
__global__ void ffn2_merge(const __hip_bfloat16* __restrict__ p0, const __hip_bfloat16* __restrict__ p1,
                           const __hip_bfloat16* __restrict__ p2, const __hip_bfloat16* __restrict__ p3,
                           const float* __restrict__ z, const float* __restrict__ b2,
                           float* __restrict__ out)
{
  const size_t i = ((size_t)blockIdx.x * 256 + threadIdx.x) * 4;
  const float4 c = *(const float4*)(z + i);
  const float4 bb = *(const float4*)(b2 + (i & 1023));
  float o0 = c.x + bb.x, o1 = c.y + bb.y, o2 = c.z + bb.z, o3 = c.w + bb.w;
  short4v a0 = *(const short4v*)(p0 + i);
  short4v a1 = *(const short4v*)(p1 + i);
  short4v a2 = *(const short4v*)(p2 + i);
  short4v a3 = *(const short4v*)(p3 + i);
  o0 += bf2f(a0[0]) + bf2f(a1[0]) + bf2f(a2[0]) + bf2f(a3[0]);
  o1 += bf2f(a0[1]) + bf2f(a1[1]) + bf2f(a2[1]) + bf2f(a3[1]);
  o2 += bf2f(a0[2]) + bf2f(a1[2]) + bf2f(a2[2]) + bf2f(a3[2]);
  o3 += bf2f(a0[3]) + bf2f(a1[3]) + bf2f(a2[3]) + bf2f(a3[3]);
  float4 o; o.x = o0; o.y = o1; o.z = o2; o.w = o3;
  *(float4*)(out + i) = o;
}

// ---------- flash attention v8: 8 waves x 16 q-rows, same 2-deep sync skeleton -------
// LDS unchanged (51.2KB, 3 blocks/CU) but 24 waves/CU (was 12): 2x TLP for latency
// hiding; per-wave MFMA/softmax chain halves. STAGE: 1 K-load + 1 V-load per thread
// (512 thr x 16B = 8KB tile each), so counted wait becomes vmcnt(2).
__global__ __launch_bounds__(512, 3) void flash_attn(
    const __hip_bfloat16* __restrict__ Q, const __hip_bfloat16* __restrict__ Kb,
    const __hip_bfloat16* __restrict__ Vt,
    __hip_bfloat16* __restrict__ Opart, float* __restrict__ Lpart)
{
  __shared__ short Ks[2][64 * 64];
  __shared__ short Vs[2][64 * 64];
  __shared__ short P2[8][16 * 72];
  const int t = threadIdx.x;
  const int lane = t & 63, w = t >> 6;     // 8 waves, 16 q-rows each
  const int l15 = lane & 15, lg = lane >> 4;
  const int chunk = blockIdx.x, bh = blockIdx.z;
  const int qblk = 15 - (int)blockIdx.y;   // heavy blocks dispatch first
  const int q0 = qblk * 128;
  const int s_base = chunk * 512;
  if (s_base > q0 + 127) return;
  const int s_hi = (s_base + 512 < q0 + 128) ? s_base + 512 : q0 + 128;
  const int ntiles = (s_hi - s_base) >> 6;
  const int qw = q0 + w * 16;

  const __hip_bfloat16* Qbh = Q + (size_t)bh * 2048 * 64;
  const __hip_bfloat16* Kbh = Kb + (size_t)bh * 2048 * 64;
  const __hip_bfloat16* Vbh = Vt + (size_t)bh * 64 * 2048;

  bf16x8 qf[2];
#pragma unroll
  for (int kc = 0; kc < 2; ++kc)
    qf[kc] = *(const bf16x8*)(Qbh + (size_t)(qw + l15) * 64 + kc * 32 + lg * 8);

  // staging: thread t covers row srow = t>>3 (0..63), 16B chunk (t&7), swizzled source
  const int srow = t >> 3;
  const int schunk = ((t & 7) ^ (srow & 7)) * 8;

  auto STAGE = [&](int bufi, int s0) {
    const int dst = bufi * 8192 + t * 16;
    gload_lds16(Kbh + (size_t)(s0 + srow) * 64 + schunk, (char*)Ks + dst);
    gload_lds16(Vbh + (size_t)srow * 2048 + s0 + schunk, (char*)Vs + dst);
  };

  f32x4 o_acc[4];
  float lpart = 0.f;
#pragma unroll
  for (int fd = 0; fd < 4; ++fd)
#pragma unroll
    for (int e = 0; e < 4; ++e) o_acc[fd][e] = 0.f;

  const float C = 0.18033688011112042f;   // 0.125 * log2(e)

  STAGE(0, s_base);
  int cur = 0;
  for (int ti = 0; ti < ntiles; ++ti) {
    const int s0 = s_base + ti * 64;
    const int nxt = (ti + 1 < ntiles) ? s0 + 64 : s0;
    STAGE(cur ^ 1, nxt);
    asm volatile("s_waitcnt vmcnt(2)" ::: "memory");
    __builtin_amdgcn_s_barrier();
    asm volatile("" ::: "memory");

    if (s0 <= qw + 15) {
      f32x4 s_acc[4];
#pragma unroll
      for (int fn = 0; fn < 4; ++fn)
#pragma unroll
        for (int e = 0; e < 4; ++e) s_acc[fn][e] = 0.f;
      __builtin_amdgcn_s_setprio(1);
#pragma unroll
      for (int kc = 0; kc < 2; ++kc)
#pragma unroll
        for (int fn = 0; fn < 4; ++fn) {
          const int r = fn * 16 + l15;
          bf16x8 kf = *(const bf16x8*)&Ks[cur][r * 64 + ((((kc << 2) | lg) ^ (l15 & 7)) << 3)];
          s_acc[fn] = __builtin_amdgcn_mfma_f32_16x16x32_bf16(kf, qf[kc], s_acc[fn], 0, 0, 0);
        }
      __builtin_amdgcn_s_setprio(0);

      const bool needmask = (s0 + 63 > qw);
      const int qv = qw + l15;
#pragma unroll
      for (int fn = 0; fn < 4; ++fn) {
        float p[4];
#pragma unroll
        for (int rg = 0; rg < 4; ++rg) {
          float pv = exp2_fast(s_acc[fn][rg] * C);
          if (needmask) {
            const int sg = s0 + fn * 16 + lg * 4 + rg;
            pv = (sg <= qv) ? pv : 0.f;
          }
          p[rg] = pv;
          lpart += pv;
        }
        uint2v u;
        u.x = cvt_pk_bf16(p[0], p[1]);
        u.y = cvt_pk_bf16(p[2], p[3]);
        *(uint2v*)&P2[w][l15 * 72 + fn * 16 + lg * 4] = u;
      }

      __builtin_amdgcn_s_setprio(1);
#pragma unroll
      for (int kc = 0; kc < 2; ++kc) {
        bf16x8 pf = *(const bf16x8*)&P2[w][l15 * 72 + kc * 32 + lg * 8];
#pragma unroll
        for (int fd = 0; fd < 4; ++fd) {
          const int r = fd * 16 + l15;
          bf16x8 vf = *(const bf16x8*)&Vs[cur][r * 64 + ((((kc << 2) | lg) ^ (l15 & 7)) << 3)];
          o_acc[fd] = __builtin_amdgcn_mfma_f32_16x16x32_bf16(vf, pf, o_acc[fd], 0, 0, 0);
        }
      }
      __builtin_amdgcn_s_setprio(0);
    }

    asm volatile("" ::: "memory");
    __builtin_amdgcn_s_barrier();
    cur ^= 1;
  }

  const int pslot = ((bh * 16 + qblk) << 2) + chunk;
  __hip_bfloat16* op = Opart + (size_t)pslot * 8192;
  {
    float l = lpart;
    l += __shfl_xor(l, 16);
    l += __shfl_xor(l, 32);
    const int qloc = w * 16 + l15;
    if (lg == 0) Lpart[pslot * 128 + qloc] = l;
#pragma unroll
    for (int fd = 0; fd < 4; ++fd) {
      uint2v u;
      u.x = cvt_pk_bf16(o_acc[fd][0], o_acc[fd][1]);
      u.y = cvt_pk_bf16(o_acc[fd][2], o_acc[fd][3]);
      *(uint2v*)(op + (size_t)qloc * 64 + fd * 16 + lg * 4) = u;
    }
  }
}

// -------------------- launch --------------------
extern "C" void kernel_launch(void* const* d_in, const int* in_sizes, int n_in,
                              void* d_out, int out_size, void* d_ws, size_t ws_size,
                              hipStream_t stream) {
  const float* x    = (const float*)d_in[0];
  const float* wq   = (const float*)d_in[1];
  const float* bq   = (const float*)d_in[2];
  const float* wk   = (const float*)d_in[3];
  const float* bk   = (const float*)d_in[4];
  const float* wv   = (const float*)d_in[5];
  const float* bv   = (const float*)d_in[6];
  const float* ln1g = (const float*)d_in[7];
  const float* ln1b = (const float*)d_in[8];
  const float* ln2g = (const float*)d_in[9];
  const float* ln2b = (const float*)d_in[10];
  const float* w1   = (const float*)d_in[11];
  const float* b1   = (const float*)d_in[12];
  const float* w2   = (const float*)d_in[13];
  const float* b2   = (const float*)d_in[14];
  float* out = (float*)d_out;

  char* ws = (char*)d_ws;
  const size_t MB = 1024 * 1024;
  __hip_bfloat16* h_bf  = (__hip_bfloat16*)(ws + 0);
  float* z_f32          = (float*)(ws + 0);
  __hip_bfloat16* qb    = (__hip_bfloat16*)(ws + 8 * MB);
  __hip_bfloat16* kb    = (__hip_bfloat16*)(ws + 16 * MB);
  __hip_bfloat16* z_bf  = (__hip_bfloat16*)(ws + 16 * MB);
  __hip_bfloat16* vtb   = (__hip_bfloat16*)(ws + 24 * MB);
  __hip_bfloat16* ff1   = (__hip_bfloat16*)(ws + 24 * MB);
  float* h_f32          = (float*)(ws + 32 * MB);
  __hip_bfloat16* p3    = (__hip_bfloat16*)(ws + 32 * MB);
  __hip_bfloat16* Opart = (__hip_bfloat16*)(ws + 48 * MB);
  __hip_bfloat16* p0    = (__hip_bfloat16*)(ws + 56 * MB);
  __hip_bfloat16* p1    = (__hip_bfloat16*)(ws + 64 * MB);
  __hip_bfloat16* p2    = (__hip_bfloat16*)(ws + 72 * MB);
  float* Lpart          = (float*)(ws + 80 * MB);
  __hip_bfloat16* wqkvT = (__hip_bfloat16*)(ws + 88 * MB);
  __hip_bfloat16* w1T   = (__hip_bfloat16*)(ws + 96 * MB);
  __hip_bfloat16* w2T   = (__hip_bfloat16*)(ws + 104 * MB);

  transpose_qkv<<<dim3(1, 16, 48), 256, 0, stream>>>(wq, wk, wv, wqkvT);
  transpose_pack<<<dim3(64, 16, 1), 256, 0, stream>>>(w1, w1T, 1024, 4096, 1024, 0, 0);
  transpose_pack<<<dim3(16, 64, 1), 256, 0, stream>>>(w2, w2T, 4096, 1024, 4096, 0, 0);

  ln_fused<<<4096, 256, 0, stream>>>(x, ln1g, ln1b, h_f32, h_bf);

  // QKV projection: M=4096, N=3072, K=1024  (grid 12*32=384, %8==0)
  gemm_bt<0><<<dim3(12, 32), 512, 0, stream>>>(h_bf, wqkvT, 3072, 1024, 1024,
      nullptr, bq, bk, bv, qb, kb, vtb, nullptr, nullptr, nullptr, nullptr, nullptr);

  flash_attn<<<dim3(4, 16, 32), 512, 0, stream>>>(qb, kb, vtb, Opart, Lpart);

  // LN2 + KV-split merge fused: z = LN(h + sum(O)/sum(l))
  ln2_merge_fused<<<4096, 256, 0, stream>>>(h_f32, Opart, Lpart, ln2g, ln2b, z_f32, z_bf);

  // FFN1: relu(z @ w1 + b1), M=4096, N=4096, K=1024  (grid 16*32=512, %8==0)
  gemm_bt<1><<<dim3(16, 32), 512, 0, stream>>>(z_bf, w1T, 4096, 1024, 1024,
      b1, nullptr, nullptr, nullptr, nullptr, nullptr, nullptr, ff1, nullptr, nullptr, nullptr, nullptr);

  // FFN2 split-K=4 (1024 each), bf16 partials: M=4096, N=1024, K=4096 (grid 4*32*4=512)
  gemm_bt<2><<<dim3(4, 32, 4), 512, 0, stream>>>(ff1, w2T, 1024, 4096, 1024,
      nullptr, nullptr, nullptr, nullptr, nullptr, nullptr, nullptr, nullptr, p0, p1, p2, p3);

  // out = z + b2 + p0 + p1 + p2 + p3
  ffn2_merge<<<4096, 256, 0, stream>>>(p0, p1, p2, p3, z_f32, b2, out);
}

// Round 22
// 226.407 us; speedup vs baseline: 1.4563x; 1.0001x over previous
//
#include <hip/hip_runtime.h>
#include <hip/hip_bf16.h>
#include <cstdint>
#include <cstddef>

typedef __attribute__((ext_vector_type(8))) short bf16x8;
typedef __attribute__((ext_vector_type(4))) float f32x4;
typedef __attribute__((ext_vector_type(4))) short short4v;
typedef __attribute__((ext_vector_type(2))) unsigned int uint2v;

__device__ inline void gload_lds16(const void* g, void* l) {
  __builtin_amdgcn_global_load_lds((const __attribute__((address_space(1))) void*)g,
                                   (__attribute__((address_space(3))) void*)l, 16, 0, 0);
}

__device__ inline float exp2_fast(float x) {
  float r;
  asm volatile("v_exp_f32 %0, %1" : "=v"(r) : "v"(x));
  return r;
}

__device__ inline unsigned int cvt_pk_bf16(float lo, float hi) {
  unsigned int r;
  asm volatile("v_cvt_pk_bf16_f32 %0, %1, %2" : "=v"(r) : "v"(lo), "v"(hi));
  return r;
}

__device__ inline float bf2f(short s) {
  return __uint_as_float(((unsigned int)(unsigned short)s) << 16);
}

// -------------------- transpose fp32 [R][C] -> bf16 [C][R] --------------------
__global__ void transpose_pack(const float* __restrict__ src, __hip_bfloat16* __restrict__ dst,
                               int R, int C, int ldDst, long zSrcStride, int zDstRow)
{
  __shared__ float tile[64][65];
  src += (size_t)blockIdx.z * zSrcStride;
  const int r0 = blockIdx.y * 64, c0 = blockIdx.x * 64;
  const int t = threadIdx.x;
#pragma unroll
  for (int i = 0; i < 16; ++i) {
    int idx = i * 256 + t;
    int r = idx >> 6, c = idx & 63;
    tile[r][c] = src[(size_t)(r0 + r) * C + c0 + c];
  }
  __syncthreads();
  const int drow0 = blockIdx.z * zDstRow + c0;
#pragma unroll
  for (int i = 0; i < 16; ++i) {
    int idx = i * 256 + t;
    int cc = idx >> 6, rr = idx & 63;
    dst[(size_t)(drow0 + cc) * ldDst + r0 + rr] = __float2bfloat16(tile[rr][cc]);
  }
}

// ------------- merged QKV weight transpose: wq/wk/wv [16][1024][64] -> [3072][1024] ----
__global__ void transpose_qkv(const float* __restrict__ wq, const float* __restrict__ wk,
                              const float* __restrict__ wv, __hip_bfloat16* __restrict__ dst)
{
  __shared__ float tile[64][65];
  const int z = blockIdx.z;              // grid (1,16,48)
  const int seg = z >> 4, h = z & 15;
  const float* src = (seg == 0) ? wq : (seg == 1) ? wk : wv;
  src += (size_t)h * 65536;
  const int r0 = blockIdx.y * 64;
  const int t = threadIdx.x;
#pragma unroll
  for (int i = 0; i < 16; ++i) {
    int idx = i * 256 + t;
    int r = idx >> 6, c = idx & 63;
    tile[r][c] = src[(size_t)(r0 + r) * 64 + c];
  }
  __syncthreads();
  const int drow0 = seg * 1024 + h * 64;
#pragma unroll
  for (int i = 0; i < 16; ++i) {
    int idx = i * 256 + t;
    int cc = idx >> 6, rr = idx & 63;
    dst[(size_t)(drow0 + cc) * 1024 + r0 + rr] = __float2bfloat16(tile[rr][cc]);
  }
}

// -------------------- LN1: LayerNorm(x) -> f32 + bf16 --------------------
__global__ void ln_fused(const float* __restrict__ x,
                         const float* __restrict__ g, const float* __restrict__ bta,
                         float* __restrict__ of32, __hip_bfloat16* __restrict__ obf)
{
  const int row = blockIdx.x;
  const int t = threadIdx.x;
  float4 v = ((const float4*)(x + (size_t)row * 1024))[t];
  float s = v.x + v.y + v.z + v.w;
  float ss = v.x * v.x + v.y * v.y + v.z * v.z + v.w * v.w;
#pragma unroll
  for (int off = 1; off < 64; off <<= 1) {
    s += __shfl_xor(s, off);
    ss += __shfl_xor(ss, off);
  }
  __shared__ float sb[4], ssb[4];
  const int w = t >> 6, lane = t & 63;
  if (lane == 0) { sb[w] = s; ssb[w] = ss; }
  __syncthreads();
  s = sb[0] + sb[1] + sb[2] + sb[3];
  ss = ssb[0] + ssb[1] + ssb[2] + ssb[3];
  const float mu = s * (1.f / 1024.f);
  const float var = ss * (1.f / 1024.f) - mu * mu;
  const float rstd = rsqrtf(var + 1e-5f);
  float4 gv = ((const float4*)g)[t];
  float4 bv = ((const float4*)bta)[t];
  float4 o;
  o.x = (v.x - mu) * rstd * gv.x + bv.x;
  o.y = (v.y - mu) * rstd * gv.y + bv.y;
  o.z = (v.z - mu) * rstd * gv.z + bv.z;
  o.w = (v.w - mu) * rstd * gv.w + bv.w;
  ((float4*)(of32 + (size_t)row * 1024))[t] = o;
  __hip_bfloat16 hb[4] = { __float2bfloat16(o.x), __float2bfloat16(o.y),
                           __float2bfloat16(o.z), __float2bfloat16(o.w) };
  *(short4v*)(obf + (size_t)row * 1024 + t * 4) = *(const short4v*)hb;
}

// ---------- LN2 fused with KV-split merge: y = h + sum(O)/sum(l); z = LN(y) ----------
// Flash v9 geometry: 8 qblks of 256 rows, 4 chunk slots each; nch = qblk/2 + 1.
__global__ void ln2_merge_fused(const float* __restrict__ hres,
                                const __hip_bfloat16* __restrict__ Opart,
                                const float* __restrict__ Lpart,
                                const float* __restrict__ g, const float* __restrict__ bta,
                                float* __restrict__ of32, __hip_bfloat16* __restrict__ obf)
{
  const int row = blockIdx.x;            // b*2048 + t
  const int b = row >> 11, tt = row & 2047;
  const int qblk = tt >> 8, qloc = tt & 255;
  const int nch = (qblk >> 1) + 1;
  const int t = threadIdx.x;
  const int hd = t >> 4;                 // head (4 cols per thread, within one head)
  const int d0 = (t & 15) * 4;
  const int base = (((b * 16 + hd) * 8 + qblk) << 2);

  float4 v = ((const float4*)(hres + (size_t)row * 1024))[t];
  float l = 0.f;
  float o0 = 0.f, o1 = 0.f, o2 = 0.f, o3 = 0.f;
  for (int ch = 0; ch < nch; ++ch) {     // nch uniform per block (row)
    l += Lpart[(size_t)(base + ch) * 256 + qloc];
    short4v o4 = *(const short4v*)(Opart + (size_t)(base + ch) * 16384 + qloc * 64 + d0);
    o0 += bf2f(o4[0]); o1 += bf2f(o4[1]); o2 += bf2f(o4[2]); o3 += bf2f(o4[3]);
  }
  const float inv = 1.f / l;
  v.x += o0 * inv; v.y += o1 * inv; v.z += o2 * inv; v.w += o3 * inv;

  float s = v.x + v.y + v.z + v.w;
  float ss = v.x * v.x + v.y * v.y + v.z * v.z + v.w * v.w;
#pragma unroll
  for (int off = 1; off < 64; off <<= 1) {
    s += __shfl_xor(s, off);
    ss += __shfl_xor(ss, off);
  }
  __shared__ float sb[4], ssb[4];
  const int w = t >> 6, lane = t & 63;
  if (lane == 0) { sb[w] = s; ssb[w] = ss; }
  __syncthreads();
  s = sb[0] + sb[1] + sb[2] + sb[3];
  ss = ssb[0] + ssb[1] + ssb[2] + ssb[3];
  const float mu = s * (1.f / 1024.f);
  const float var = ss * (1.f / 1024.f) - mu * mu;
  const float rstd = rsqrtf(var + 1e-5f);
  float4 gv = ((const float4*)g)[t];
  float4 bv = ((const float4*)bta)[t];
  float4 o;
  o.x = (v.x - mu) * rstd * gv.x + bv.x;
  o.y = (v.y - mu) * rstd * gv.y + bv.y;
  o.z = (v.z - mu) * rstd * gv.z + bv.z;
  o.w = (v.w - mu) * rstd * gv.w + bv.w;
  ((float4*)(of32 + (size_t)row * 1024))[t] = o;
  __hip_bfloat16 hb[4] = { __float2bfloat16(o.x), __float2bfloat16(o.y),
                           __float2bfloat16(o.z), __float2bfloat16(o.w) };
  *(short4v*)(obf + (size_t)row * 1024 + t * 4) = *(const short4v*)hb;
}

// -------------------- GEMM (R14 green): 8 waves, BM=128 BN=256 BK=32 ------------------
// 2-deep dbuf + vmcnt(3), + T1 XCD-aware chunked blockIdx swizzle. EPI2: bf16 partials.
template<int EPI>
__global__ __launch_bounds__(512, 2) void gemm_bt(
    const __hip_bfloat16* __restrict__ A, const __hip_bfloat16* __restrict__ Bt,
    int N, int Kf, int kLen,
    const float* __restrict__ bias,
    const float* __restrict__ bq, const float* __restrict__ bk, const float* __restrict__ bv,
    __hip_bfloat16* __restrict__ oq, __hip_bfloat16* __restrict__ ok, __hip_bfloat16* __restrict__ ovt,
    __hip_bfloat16* __restrict__ obf,
    __hip_bfloat16* __restrict__ opart0, __hip_bfloat16* __restrict__ opart1,
    __hip_bfloat16* __restrict__ opart2, __hip_bfloat16* __restrict__ opart3)
{
  __shared__ short As[2][128 * 32];   //  8 KB per buf
  __shared__ short Bs[2][256 * 32];   // 16 KB per buf
  const int t = threadIdx.x;
  const int lane = t & 63;
  const int w = t >> 6;               // 0..7
  const int wm = w >> 2, wn = w & 3;  // 2 x 4 wave grid
  const int l15 = lane & 15, lg = lane >> 4;

  const int nwg = (int)(gridDim.x * gridDim.y);
  int wgid = (int)blockIdx.y * (int)gridDim.x + (int)blockIdx.x;
  wgid = (wgid & 7) * (nwg >> 3) + (wgid >> 3);
  const int bx = wgid % (int)gridDim.x;
  const int by = wgid / (int)gridDim.x;
  const int m0 = by * 128;
  const int n0 = bx * 256;
  const int kBase = (EPI == 2) ? (int)blockIdx.z * kLen : 0;
  const int kEnd0 = kBase + kLen;
  const int kEnd = (kEnd0 > Kf) ? Kf : kEnd0;

  f32x4 acc[4][4];
#pragma unroll
  for (int i = 0; i < 4; ++i)
#pragma unroll
    for (int j = 0; j < 4; ++j)
#pragma unroll
      for (int e = 0; e < 4; ++e) acc[i][j][e] = 0.f;

  auto STAGE = [&](int buf, int kk0) {
    {
      const int r = t >> 2, cc = t & 3;
      const int kk = (cc ^ ((r >> 1) & 3)) * 8;
      gload_lds16(A + (size_t)(m0 + r) * Kf + kk0 + kk, (char*)As + buf * 8192 + t * 16);
    }
#pragma unroll
    for (int i = 0; i < 2; ++i) {
      const int c = t + 512 * i;
      const int r = c >> 2, cc = c & 3;
      const int kk = (cc ^ ((r >> 1) & 3)) * 8;
      gload_lds16(Bt + (size_t)(n0 + r) * Kf + kk0 + kk, (char*)Bs + buf * 16384 + c * 16);
    }
  };

  STAGE(0, kBase);
  int buf = 0;
  for (int k0 = kBase; k0 < kEnd; k0 += 32) {
    const int knext = (k0 + 32 < kEnd) ? k0 + 32 : k0;
    STAGE(buf ^ 1, knext);
    asm volatile("s_waitcnt vmcnt(3)" ::: "memory");
    __builtin_amdgcn_s_barrier();
    asm volatile("" ::: "memory");

    bf16x8 af[4], bfr[4];
#pragma unroll
    for (int fm = 0; fm < 4; ++fm) {
      const int r = wm * 64 + fm * 16 + l15;
      const int kc = lg ^ ((r >> 1) & 3);
      af[fm] = *(const bf16x8*)&As[buf][r * 32 + kc * 8];
    }
#pragma unroll
    for (int fn = 0; fn < 4; ++fn) {
      const int r = wn * 64 + fn * 16 + l15;
      const int kc = lg ^ ((r >> 1) & 3);
      bfr[fn] = *(const bf16x8*)&Bs[buf][r * 32 + kc * 8];
    }
#pragma unroll
    for (int fm = 0; fm < 4; ++fm)
#pragma unroll
      for (int fn = 0; fn < 4; ++fn)
        acc[fm][fn] = __builtin_amdgcn_mfma_f32_16x16x32_bf16(af[fm], bfr[fn], acc[fm][fn], 0, 0, 0);

    asm volatile("" ::: "memory");
    __builtin_amdgcn_s_barrier();
    buf ^= 1;
  }

  // epilogue: C row = (lg*4 + rg), col = l15 within each 16x16 fragment
#pragma unroll
  for (int fm = 0; fm < 4; ++fm) {
    const int mbase = m0 + wm * 64 + fm * 16 + lg * 4;
#pragma unroll
    for (int fn = 0; fn < 4; ++fn) {
      const int n = n0 + wn * 64 + fn * 16 + l15;
      if (EPI == 0) {
        const int seg = n >> 10;
        const int cn = n & 1023;
        const int h = cn >> 6, d = cn & 63;
        const float* bp = (seg == 0) ? bq : (seg == 1) ? bk : bv;
        const float bias_v = bp[cn];
#pragma unroll
        for (int rg = 0; rg < 4; ++rg) {
          const int m = mbase + rg;
          const int b = m >> 11, tt = m & 2047;
          const size_t bh = (size_t)(b * 16 + h);
          const float val = acc[fm][fn][rg] + bias_v;
          if (seg == 0)      oq[(bh * 2048 + tt) * 64 + d] = __float2bfloat16(val);
          else if (seg == 1) ok[(bh * 2048 + tt) * 64 + d] = __float2bfloat16(val);
          else               ovt[(bh * 64 + d) * 2048 + tt] = __float2bfloat16(val);
        }
      } else if (EPI == 1) {
        const float bias_v = bias[n];
#pragma unroll
        for (int rg = 0; rg < 4; ++rg) {
          const int m = mbase + rg;
          float val = acc[fm][fn][rg] + bias_v;
          val = fmaxf(val, 0.f);
          obf[(size_t)m * N + n] = __float2bfloat16(val);
        }
      } else {
        __hip_bfloat16* op = (blockIdx.z == 0) ? opart0 : (blockIdx.z == 1) ? opart1
                           : (blockIdx.z == 2) ? opart2 : opart3;
#pragma unroll
        for (int rg = 0; rg < 4; ++rg) {
          const int m = mbase + rg;
          op[(size_t)m * 1024 + n] = __float2bfloat16(acc[fm][fn][rg]);
        }
      }
    }
  }
}

// -------------------- FFN2 merge: out = z + b2 + p0 + p1 + p2 + p3 (bf16 partials) ----
__global__ void ffn2_merge(const __hip_bfloat16* __restrict__ p0, const __hip_bfloat16* __restrict__ p1,
                           const __hip_bfloat16* __restrict__ p2, const __hip_bfloat16* __restrict__ p3,
                           const float* __restrict__ z, const float* __restrict__ b2,
                           float* __restrict__ out)
{
  const size_t i = ((size_t)blockIdx.x * 256 + threadIdx.x) * 4;
  const float4 c = *(const float4*)(z + i);
  const float4 bb = *(const float4*)(b2 + (i & 1023));
  float o0 = c.x + bb.x, o1 = c.y + bb.y, o2 = c.z + bb.z, o3 = c.w + bb.w;
  short4v a0 = *(const short4v*)(p0 + i);
  short4v a1 = *(const short4v*)(p1 + i);
  short4v a2 = *(const short4v*)(p2 + i);
  short4v a3 = *(const short4v*)(p3 + i);
  o0 += bf2f(a0[0]) + bf2f(a1[0]) + bf2f(a2[0]) + bf2f(a3[0]);
  o1 += bf2f(a0[1]) + bf2f(a1[1]) + bf2f(a2[1]) + bf2f(a3[1]);
  o2 += bf2f(a0[2]) + bf2f(a1[2]) + bf2f(a2[2]) + bf2f(a3[2]);
  o3 += bf2f(a0[3]) + bf2f(a1[3]) + bf2f(a2[3]) + bf2f(a3[3]);
  float4 o; o.x = o0; o.y = o1; o.z = o2; o.w = o3;
  *(float4*)(out + i) = o;
}

// ---------- flash attention v9: 8 waves x 32 q-rows (QBLK=256), 2-deep skeleton ------
// Halves tile-iterations (8704 -> 4608): per-tile fixed cost (stage wait + 2 barriers)
// amortized over 2x MFMA. Same swizzles/sync as green R18/R21 kernels.
__global__ __launch_bounds__(512, 2) void flash_attn(
    const __hip_bfloat16* __restrict__ Q, const __hip_bfloat16* __restrict__ Kb,
    const __hip_bfloat16* __restrict__ Vt,
    __hip_bfloat16* __restrict__ Opart, float* __restrict__ Lpart)
{
  __shared__ short Ks[2][64 * 64];
  __shared__ short Vs[2][64 * 64];
  __shared__ short P2[8][32 * 72];
  const int t = threadIdx.x;
  const int lane = t & 63, w = t >> 6;     // 8 waves, 32 q-rows each
  const int l15 = lane & 15, lg = lane >> 4;
  const int chunk = blockIdx.x, bh = blockIdx.z;
  const int qblk = 7 - (int)blockIdx.y;    // heavy blocks dispatch first
  const int q0 = qblk * 256;
  const int s_base = chunk * 512;
  if (s_base > q0 + 255) return;
  const int s_hi = (s_base + 512 < q0 + 256) ? s_base + 512 : q0 + 256;
  const int ntiles = (s_hi - s_base) >> 6;
  const int qw = q0 + w * 32;

  const __hip_bfloat16* Qbh = Q + (size_t)bh * 2048 * 64;
  const __hip_bfloat16* Kbh = Kb + (size_t)bh * 2048 * 64;
  const __hip_bfloat16* Vbh = Vt + (size_t)bh * 64 * 2048;

  bf16x8 qf[2][2];
#pragma unroll
  for (int fm = 0; fm < 2; ++fm)
#pragma unroll
    for (int kc = 0; kc < 2; ++kc)
      qf[fm][kc] = *(const bf16x8*)(Qbh + (size_t)(qw + fm * 16 + l15) * 64 + kc * 32 + lg * 8);

  // staging: thread t covers row srow = t>>3 (0..63), 16B chunk (t&7), swizzled source
  const int srow = t >> 3;
  const int schunk = ((t & 7) ^ (srow & 7)) * 8;

  auto STAGE = [&](int bufi, int s0) {
    const int dst = bufi * 8192 + t * 16;
    gload_lds16(Kbh + (size_t)(s0 + srow) * 64 + schunk, (char*)Ks + dst);
    gload_lds16(Vbh + (size_t)srow * 2048 + s0 + schunk, (char*)Vs + dst);
  };

  f32x4 o_acc[2][4];
  float lpart[2] = {0.f, 0.f};
#pragma unroll
  for (int fm = 0; fm < 2; ++fm)
#pragma unroll
    for (int fd = 0; fd < 4; ++fd)
#pragma unroll
      for (int e = 0; e < 4; ++e) o_acc[fm][fd][e] = 0.f;

  const float C = 0.18033688011112042f;   // 0.125 * log2(e)

  STAGE(0, s_base);
  int cur = 0;
  for (int ti = 0; ti < ntiles; ++ti) {
    const int s0 = s_base + ti * 64;
    const int nxt = (ti + 1 < ntiles) ? s0 + 64 : s0;
    STAGE(cur ^ 1, nxt);
    asm volatile("s_waitcnt vmcnt(2)" ::: "memory");
    __builtin_amdgcn_s_barrier();
    asm volatile("" ::: "memory");

    if (s0 <= qw + 31) {
      f32x4 s_acc[2][4];
#pragma unroll
      for (int fm = 0; fm < 2; ++fm)
#pragma unroll
        for (int fn = 0; fn < 4; ++fn)
#pragma unroll
          for (int e = 0; e < 4; ++e) s_acc[fm][fn][e] = 0.f;
      __builtin_amdgcn_s_setprio(1);
#pragma unroll
      for (int kc = 0; kc < 2; ++kc)
#pragma unroll
        for (int fn = 0; fn < 4; ++fn) {
          const int r = fn * 16 + l15;
          bf16x8 kf = *(const bf16x8*)&Ks[cur][r * 64 + ((((kc << 2) | lg) ^ (l15 & 7)) << 3)];
          s_acc[0][fn] = __builtin_amdgcn_mfma_f32_16x16x32_bf16(kf, qf[0][kc], s_acc[0][fn], 0, 0, 0);
          s_acc[1][fn] = __builtin_amdgcn_mfma_f32_16x16x32_bf16(kf, qf[1][kc], s_acc[1][fn], 0, 0, 0);
        }
      __builtin_amdgcn_s_setprio(0);

      const bool needmask = (s0 + 63 > qw);
      float pr[2][4][4];
#pragma unroll
      for (int fm = 0; fm < 2; ++fm) {
        const int qv = qw + fm * 16 + l15;
#pragma unroll
        for (int fn = 0; fn < 4; ++fn)
#pragma unroll
          for (int rg = 0; rg < 4; ++rg) {
            float p = exp2_fast(s_acc[fm][fn][rg] * C);
            if (needmask) {
              const int sg = s0 + fn * 16 + lg * 4 + rg;
              p = (sg <= qv) ? p : 0.f;
            }
            pr[fm][fn][rg] = p;
            lpart[fm] += p;
          }
      }

#pragma unroll
      for (int fm = 0; fm < 2; ++fm)
#pragma unroll
        for (int fn = 0; fn < 4; ++fn) {
          uint2v u;
          u.x = cvt_pk_bf16(pr[fm][fn][0], pr[fm][fn][1]);
          u.y = cvt_pk_bf16(pr[fm][fn][2], pr[fm][fn][3]);
          *(uint2v*)&P2[w][(fm * 16 + l15) * 72 + fn * 16 + lg * 4] = u;
        }

      __builtin_amdgcn_s_setprio(1);
#pragma unroll
      for (int kc = 0; kc < 2; ++kc) {
        bf16x8 pf0 = *(const bf16x8*)&P2[w][(l15) * 72 + kc * 32 + lg * 8];
        bf16x8 pf1 = *(const bf16x8*)&P2[w][(16 + l15) * 72 + kc * 32 + lg * 8];
#pragma unroll
        for (int fd = 0; fd < 4; ++fd) {
          const int r = fd * 16 + l15;
          bf16x8 vf = *(const bf16x8*)&Vs[cur][r * 64 + ((((kc << 2) | lg) ^ (l15 & 7)) << 3)];
          o_acc[0][fd] = __builtin_amdgcn_mfma_f32_16x16x32_bf16(vf, pf0, o_acc[0][fd], 0, 0, 0);
          o_acc[1][fd] = __builtin_amdgcn_mfma_f32_16x16x32_bf16(vf, pf1, o_acc[1][fd], 0, 0, 0);
        }
      }
      __builtin_amdgcn_s_setprio(0);
    }

    asm volatile("" ::: "memory");
    __builtin_amdgcn_s_barrier();
    cur ^= 1;
  }

  const int pslot = ((bh * 8 + qblk) << 2) + chunk;
  __hip_bfloat16* op = Opart + (size_t)pslot * 16384;
#pragma unroll
  for (int fm = 0; fm < 2; ++fm) {
    float l = lpart[fm];
    l += __shfl_xor(l, 16);
    l += __shfl_xor(l, 32);
    const int qloc = w * 32 + fm * 16 + l15;
    if (lg == 0) Lpart[(size_t)pslot * 256 + qloc] = l;
#pragma unroll
    for (int fd = 0; fd < 4; ++fd) {
      uint2v u;
      u.x = cvt_pk_bf16(o_acc[fm][fd][0], o_acc[fm][fd][1]);
      u.y = cvt_pk_bf16(o_acc[fm][fd][2], o_acc[fm][fd][3]);
      *(uint2v*)(op + (size_t)qloc * 64 + fd * 16 + lg * 4) = u;
    }
  }
}

// -------------------- launch --------------------
extern "C" void kernel_launch(void* const* d_in, const int* in_sizes, int n_in,
                              void* d_out, int out_size, void* d_ws, size_t ws_size,
                              hipStream_t stream) {
  const float* x    = (const float*)d_in[0];
  const float* wq   = (const float*)d_in[1];
  const float* bq   = (const float*)d_in[2];
  const float* wk   = (const float*)d_in[3];
  const float* bk   = (const float*)d_in[4];
  const float* wv   = (const float*)d_in[5];
  const float* bv   = (const float*)d_in[6];
  const float* ln1g = (const float*)d_in[7];
  const float* ln1b = (const float*)d_in[8];
  const float* ln2g = (const float*)d_in[9];
  const float* ln2b = (const float*)d_in[10];
  const float* w1   = (const float*)d_in[11];
  const float* b1   = (const float*)d_in[12];
  const float* w2   = (const float*)d_in[13];
  const float* b2   = (const float*)d_in[14];
  float* out = (float*)d_out;

  char* ws = (char*)d_ws;
  const size_t MB = 1024 * 1024;
  // Layout: h_bf[0,8) / z_f32[0,16); qb[8,16); kb/z_bf[16,24); vtb/ff1[24,56);
  // h_f32[32,48) dead after LN2 -> p3[32,40); Opart[48,80) (32MB, 1024x16384 bf16)
  // dead after LN2 -> p0[56,64) p1[64,72) p2[72,80); Lpart[80,81) (1MB);
  // wqkvT[88,96); w1T[96,104); w2T[104,112).
  __hip_bfloat16* h_bf  = (__hip_bfloat16*)(ws + 0);
  float* z_f32          = (float*)(ws + 0);
  __hip_bfloat16* qb    = (__hip_bfloat16*)(ws + 8 * MB);
  __hip_bfloat16* kb    = (__hip_bfloat16*)(ws + 16 * MB);
  __hip_bfloat16* z_bf  = (__hip_bfloat16*)(ws + 16 * MB);
  __hip_bfloat16* vtb   = (__hip_bfloat16*)(ws + 24 * MB);
  __hip_bfloat16* ff1   = (__hip_bfloat16*)(ws + 24 * MB);
  float* h_f32          = (float*)(ws + 32 * MB);
  __hip_bfloat16* p3    = (__hip_bfloat16*)(ws + 32 * MB);
  __hip_bfloat16* Opart = (__hip_bfloat16*)(ws + 48 * MB);
  __hip_bfloat16* p0    = (__hip_bfloat16*)(ws + 56 * MB);
  __hip_bfloat16* p1    = (__hip_bfloat16*)(ws + 64 * MB);
  __hip_bfloat16* p2    = (__hip_bfloat16*)(ws + 72 * MB);
  float* Lpart          = (float*)(ws + 80 * MB);
  __hip_bfloat16* wqkvT = (__hip_bfloat16*)(ws + 88 * MB);
  __hip_bfloat16* w1T   = (__hip_bfloat16*)(ws + 96 * MB);
  __hip_bfloat16* w2T   = (__hip_bfloat16*)(ws + 104 * MB);

  transpose_qkv<<<dim3(1, 16, 48), 256, 0, stream>>>(wq, wk, wv, wqkvT);
  transpose_pack<<<dim3(64, 16, 1), 256, 0, stream>>>(w1, w1T, 1024, 4096, 1024, 0, 0);
  transpose_pack<<<dim3(16, 64, 1), 256, 0, stream>>>(w2, w2T, 4096, 1024, 4096, 0, 0);

  ln_fused<<<4096, 256, 0, stream>>>(x, ln1g, ln1b, h_f32, h_bf);

  // QKV projection: M=4096, N=3072, K=1024  (grid 12*32=384, %8==0)
  gemm_bt<0><<<dim3(12, 32), 512, 0, stream>>>(h_bf, wqkvT, 3072, 1024, 1024,
      nullptr, bq, bk, bv, qb, kb, vtb, nullptr, nullptr, nullptr, nullptr, nullptr);

  // flash v9: grid (chunk 4, qblk 8, bh 32)
  flash_attn<<<dim3(4, 8, 32), 512, 0, stream>>>(qb, kb, vtb, Opart, Lpart);

  // LN2 + KV-split merge fused: z = LN(h + sum(O)/sum(l))
  ln2_merge_fused<<<4096, 256, 0, stream>>>(h_f32, Opart, Lpart, ln2g, ln2b, z_f32, z_bf);

  // FFN1: relu(z @ w1 + b1), M=4096, N=4096, K=1024  (grid 16*32=512, %8==0)
  gemm_bt<1><<<dim3(16, 32), 512, 0, stream>>>(z_bf, w1T, 4096, 1024, 1024,
      b1, nullptr, nullptr, nullptr, nullptr, nullptr, nullptr, ff1, nullptr, nullptr, nullptr, nullptr);

  // FFN2 split-K=4 (1024 each), bf16 partials: M=4096, N=1024, K=4096 (grid 4*32*4=512)
  gemm_bt<2><<<dim3(4, 32, 4), 512, 0, stream>>>(ff1, w2T, 1024, 4096, 1024,
      nullptr, nullptr, nullptr, nullptr, nullptr, nullptr, nullptr, nullptr, p0, p1, p2, p3);

  // out = z + b2 + p0 + p1 + p2 + p3
  ffn2_merge<<<4096, 256, 0, stream>>>(p0, p1, p2, p3, z_f32, b2, out);
}

// Round 23
// 218.355 us; speedup vs baseline: 1.5100x; 1.0369x over previous
//
#include <hip/hip_runtime.h>
#include <hip/hip_bf16.h>
#include <cstdint>
#include <cstddef>

typedef __attribute__((ext_vector_type(8))) short bf16x8;
typedef __attribute__((ext_vector_type(4))) float f32x4;
typedef __attribute__((ext_vector_type(4))) short short4v;
typedef __attribute__((ext_vector_type(2))) unsigned int uint2v;

__device__ inline void gload_lds16(const void* g, void* l) {
  __builtin_amdgcn_global_load_lds((const __attribute__((address_space(1))) void*)g,
                                   (__attribute__((address_space(3))) void*)l, 16, 0, 0);
}

__device__ inline float exp2_fast(float x) {
  float r;
  asm volatile("v_exp_f32 %0, %1" : "=v"(r) : "v"(x));
  return r;
}

__device__ inline unsigned int cvt_pk_bf16(float lo, float hi) {
  unsigned int r;
  asm volatile("v_cvt_pk_bf16_f32 %0, %1, %2" : "=v"(r) : "v"(lo), "v"(hi));
  return r;
}

__device__ inline float bf2f(short s) {
  return __uint_as_float(((unsigned int)(unsigned short)s) << 16);
}

// ---------- fused prep: QKV/W1/W2 weight transposes + LN1, one launch ----------
// blocks [0,768): wqkv transpose; [768,1792): w1T; [1792,2816): w2T; [2816,6912): LN1.
// Each block takes exactly one uniform branch (blockIdx-based) -> barriers uniform.
__global__ void prep_all(const float* __restrict__ wq, const float* __restrict__ wk,
                         const float* __restrict__ wv, const float* __restrict__ w1,
                         const float* __restrict__ w2,
                         const float* __restrict__ x, const float* __restrict__ ln1g,
                         const float* __restrict__ ln1b,
                         __hip_bfloat16* __restrict__ wqkvT, __hip_bfloat16* __restrict__ w1T,
                         __hip_bfloat16* __restrict__ w2T,
                         float* __restrict__ h_f32, __hip_bfloat16* __restrict__ h_bf)
{
  __shared__ float tile[64][65];
  __shared__ float sb[4], ssb[4];
  const int b = blockIdx.x;
  const int t = threadIdx.x;

  if (b < 768) {
    // QKV weights: [16][1024][64] fp32 -> [3072][1024] bf16
    const int y = b & 15, z = b >> 4;       // y: row-block of 1024, z: 0..47
    const int seg = z >> 4, h = z & 15;
    const float* src = (seg == 0) ? wq : (seg == 1) ? wk : wv;
    src += (size_t)h * 65536;
    const int r0 = y * 64;
#pragma unroll
    for (int i = 0; i < 16; ++i) {
      int idx = i * 256 + t;
      int r = idx >> 6, c = idx & 63;
      tile[r][c] = src[(size_t)(r0 + r) * 64 + c];
    }
    __syncthreads();
    const int drow0 = seg * 1024 + h * 64;
#pragma unroll
    for (int i = 0; i < 16; ++i) {
      int idx = i * 256 + t;
      int cc = idx >> 6, rr = idx & 63;
      wqkvT[(size_t)(drow0 + cc) * 1024 + r0 + rr] = __float2bfloat16(tile[rr][cc]);
    }
  } else if (b < 1792) {
    // w1 [1024][4096] fp32 -> w1T [4096][1024] bf16
    const int bb = b - 768;
    const int xb = bb & 63, yb = bb >> 6;   // xb over C=4096, yb over R=1024
    const int c0 = xb * 64, r0 = yb * 64;
#pragma unroll
    for (int i = 0; i < 16; ++i) {
      int idx = i * 256 + t;
      int r = idx >> 6, c = idx & 63;
      tile[r][c] = w1[(size_t)(r0 + r) * 4096 + c0 + c];
    }
    __syncthreads();
#pragma unroll
    for (int i = 0; i < 16; ++i) {
      int idx = i * 256 + t;
      int cc = idx >> 6, rr = idx & 63;
      w1T[(size_t)(c0 + cc) * 1024 + r0 + rr] = __float2bfloat16(tile[rr][cc]);
    }
  } else if (b < 2816) {
    // w2 [4096][1024] fp32 -> w2T [1024][4096] bf16
    const int bb = b - 1792;
    const int xb = bb & 15, yb = bb >> 4;   // xb over C=1024, yb over R=4096
    const int c0 = xb * 64, r0 = yb * 64;
#pragma unroll
    for (int i = 0; i < 16; ++i) {
      int idx = i * 256 + t;
      int r = idx >> 6, c = idx & 63;
      tile[r][c] = w2[(size_t)(r0 + r) * 1024 + c0 + c];
    }
    __syncthreads();
#pragma unroll
    for (int i = 0; i < 16; ++i) {
      int idx = i * 256 + t;
      int cc = idx >> 6, rr = idx & 63;
      w2T[(size_t)(c0 + cc) * 4096 + r0 + rr] = __float2bfloat16(tile[rr][cc]);
    }
  } else {
    // LN1: one row per block
    const int row = b - 2816;
    float4 v = ((const float4*)(x + (size_t)row * 1024))[t];
    float s = v.x + v.y + v.z + v.w;
    float ss = v.x * v.x + v.y * v.y + v.z * v.z + v.w * v.w;
#pragma unroll
    for (int off = 1; off < 64; off <<= 1) {
      s += __shfl_xor(s, off);
      ss += __shfl_xor(ss, off);
    }
    const int w = t >> 6, lane = t & 63;
    if (lane == 0) { sb[w] = s; ssb[w] = ss; }
    __syncthreads();
    s = sb[0] + sb[1] + sb[2] + sb[3];
    ss = ssb[0] + ssb[1] + ssb[2] + ssb[3];
    const float mu = s * (1.f / 1024.f);
    const float var = ss * (1.f / 1024.f) - mu * mu;
    const float rstd = rsqrtf(var + 1e-5f);
    float4 gv = ((const float4*)ln1g)[t];
    float4 bv = ((const float4*)ln1b)[t];
    float4 o;
    o.x = (v.x - mu) * rstd * gv.x + bv.x;
    o.y = (v.y - mu) * rstd * gv.y + bv.y;
    o.z = (v.z - mu) * rstd * gv.z + bv.z;
    o.w = (v.w - mu) * rstd * gv.w + bv.w;
    ((float4*)(h_f32 + (size_t)row * 1024))[t] = o;
    __hip_bfloat16 hb[4] = { __float2bfloat16(o.x), __float2bfloat16(o.y),
                             __float2bfloat16(o.z), __float2bfloat16(o.w) };
    *(short4v*)(h_bf + (size_t)row * 1024 + t * 4) = *(const short4v*)hb;
  }
}

// ---------- LN2 fused with KV-split merge: y = h + sum(O)/sum(l); z = LN(y) ----------
// Flash v9 geometry: 8 qblks of 256 rows, 4 chunk slots each; nch = qblk/2 + 1.
__global__ void ln2_merge_fused(const float* __restrict__ hres,
                                const __hip_bfloat16* __restrict__ Opart,
                                const float* __restrict__ Lpart,
                                const float* __restrict__ g, const float* __restrict__ bta,
                                float* __restrict__ of32, __hip_bfloat16* __restrict__ obf)
{
  const int row = blockIdx.x;            // b*2048 + t
  const int b = row >> 11, tt = row & 2047;
  const int qblk = tt >> 8, qloc = tt & 255;
  const int nch = (qblk >> 1) + 1;
  const int t = threadIdx.x;
  const int hd = t >> 4;                 // head (4 cols per thread, within one head)
  const int d0 = (t & 15) * 4;
  const int base = (((b * 16 + hd) * 8 + qblk) << 2);

  float4 v = ((const float4*)(hres + (size_t)row * 1024))[t];
  float l = 0.f;
  float o0 = 0.f, o1 = 0.f, o2 = 0.f, o3 = 0.f;
  for (int ch = 0; ch < nch; ++ch) {     // nch uniform per block (row)
    l += Lpart[(size_t)(base + ch) * 256 + qloc];
    short4v o4 = *(const short4v*)(Opart + (size_t)(base + ch) * 16384 + qloc * 64 + d0);
    o0 += bf2f(o4[0]); o1 += bf2f(o4[1]); o2 += bf2f(o4[2]); o3 += bf2f(o4[3]);
  }
  const float inv = 1.f / l;
  v.x += o0 * inv; v.y += o1 * inv; v.z += o2 * inv; v.w += o3 * inv;

  float s = v.x + v.y + v.z + v.w;
  float ss = v.x * v.x + v.y * v.y + v.z * v.z + v.w * v.w;
#pragma unroll
  for (int off = 1; off < 64; off <<= 1) {
    s += __shfl_xor(s, off);
    ss += __shfl_xor(ss, off);
  }
  __shared__ float sb[4], ssb[4];
  const int w = t >> 6, lane = t & 63;
  if (lane == 0) { sb[w] = s; ssb[w] = ss; }
  __syncthreads();
  s = sb[0] + sb[1] + sb[2] + sb[3];
  ss = ssb[0] + ssb[1] + ssb[2] + ssb[3];
  const float mu = s * (1.f / 1024.f);
  const float var = ss * (1.f / 1024.f) - mu * mu;
  const float rstd = rsqrtf(var + 1e-5f);
  float4 gv = ((const float4*)g)[t];
  float4 bv = ((const float4*)bta)[t];
  float4 o;
  o.x = (v.x - mu) * rstd * gv.x + bv.x;
  o.y = (v.y - mu) * rstd * gv.y + bv.y;
  o.z = (v.z - mu) * rstd * gv.z + bv.z;
  o.w = (v.w - mu) * rstd * gv.w + bv.w;
  ((float4*)(of32 + (size_t)row * 1024))[t] = o;
  __hip_bfloat16 hb[4] = { __float2bfloat16(o.x), __float2bfloat16(o.y),
                           __float2bfloat16(o.z), __float2bfloat16(o.w) };
  *(short4v*)(obf + (size_t)row * 1024 + t * 4) = *(const short4v*)hb;
}

// -------------------- GEMM (R14 green): 8 waves, BM=128 BN=256 BK=32 ------------------
// 2-deep dbuf + vmcnt(3), + T1 XCD-aware chunked blockIdx swizzle. EPI2: bf16 partials.
template<int EPI>
__global__ __launch_bounds__(512, 2) void gemm_bt(
    const __hip_bfloat16* __restrict__ A, const __hip_bfloat16* __restrict__ Bt,
    int N, int Kf, int kLen,
    const float* __restrict__ bias,
    const float* __restrict__ bq, const float* __restrict__ bk, const float* __restrict__ bv,
    __hip_bfloat16* __restrict__ oq, __hip_bfloat16* __restrict__ ok, __hip_bfloat16* __restrict__ ovt,
    __hip_bfloat16* __restrict__ obf,
    __hip_bfloat16* __restrict__ opart0, __hip_bfloat16* __restrict__ opart1,
    __hip_bfloat16* __restrict__ opart2, __hip_bfloat16* __restrict__ opart3)
{
  __shared__ short As[2][128 * 32];   //  8 KB per buf
  __shared__ short Bs[2][256 * 32];   // 16 KB per buf
  const int t = threadIdx.x;
  const int lane = t & 63;
  const int w = t >> 6;               // 0..7
  const int wm = w >> 2, wn = w & 3;  // 2 x 4 wave grid
  const int l15 = lane & 15, lg = lane >> 4;

  const int nwg = (int)(gridDim.x * gridDim.y);
  int wgid = (int)blockIdx.y * (int)gridDim.x + (int)blockIdx.x;
  wgid = (wgid & 7) * (nwg >> 3) + (wgid >> 3);
  const int bx = wgid % (int)gridDim.x;
  const int by = wgid / (int)gridDim.x;
  const int m0 = by * 128;
  const int n0 = bx * 256;
  const int kBase = (EPI == 2) ? (int)blockIdx.z * kLen : 0;
  const int kEnd0 = kBase + kLen;
  const int kEnd = (kEnd0 > Kf) ? Kf : kEnd0;

  f32x4 acc[4][4];
#pragma unroll
  for (int i = 0; i < 4; ++i)
#pragma unroll
    for (int j = 0; j < 4; ++j)
#pragma unroll
      for (int e = 0; e < 4; ++e) acc[i][j][e] = 0.f;

  auto STAGE = [&](int buf, int kk0) {
    {
      const int r = t >> 2, cc = t & 3;
      const int kk = (cc ^ ((r >> 1) & 3)) * 8;
      gload_lds16(A + (size_t)(m0 + r) * Kf + kk0 + kk, (char*)As + buf * 8192 + t * 16);
    }
#pragma unroll
    for (int i = 0; i < 2; ++i) {
      const int c = t + 512 * i;
      const int r = c >> 2, cc = c & 3;
      const int kk = (cc ^ ((r >> 1) & 3)) * 8;
      gload_lds16(Bt + (size_t)(n0 + r) * Kf + kk0 + kk, (char*)Bs + buf * 16384 + c * 16);
    }
  };

  STAGE(0, kBase);
  int buf = 0;
  for (int k0 = kBase; k0 < kEnd; k0 += 32) {
    const int knext = (k0 + 32 < kEnd) ? k0 + 32 : k0;
    STAGE(buf ^ 1, knext);
    asm volatile("s_waitcnt vmcnt(3)" ::: "memory");
    __builtin_amdgcn_s_barrier();
    asm volatile("" ::: "memory");

    bf16x8 af[4], bfr[4];
#pragma unroll
    for (int fm = 0; fm < 4; ++fm) {
      const int r = wm * 64 + fm * 16 + l15;
      const int kc = lg ^ ((r >> 1) & 3);
      af[fm] = *(const bf16x8*)&As[buf][r * 32 + kc * 8];
    }
#pragma unroll
    for (int fn = 0; fn < 4; ++fn) {
      const int r = wn * 64 + fn * 16 + l15;
      const int kc = lg ^ ((r >> 1) & 3);
      bfr[fn] = *(const bf16x8*)&Bs[buf][r * 32 + kc * 8];
    }
#pragma unroll
    for (int fm = 0; fm < 4; ++fm)
#pragma unroll
      for (int fn = 0; fn < 4; ++fn)
        acc[fm][fn] = __builtin_amdgcn_mfma_f32_16x16x32_bf16(af[fm], bfr[fn], acc[fm][fn], 0, 0, 0);

    asm volatile("" ::: "memory");
    __builtin_amdgcn_s_barrier();
    buf ^= 1;
  }

  // epilogue: C row = (lg*4 + rg), col = l15 within each 16x16 fragment
#pragma unroll
  for (int fm = 0; fm < 4; ++fm) {
    const int mbase = m0 + wm * 64 + fm * 16 + lg * 4;
#pragma unroll
    for (int fn = 0; fn < 4; ++fn) {
      const int n = n0 + wn * 64 + fn * 16 + l15;
      if (EPI == 0) {
        const int seg = n >> 10;
        const int cn = n & 1023;
        const int h = cn >> 6, d = cn & 63;
        const float* bp = (seg == 0) ? bq : (seg == 1) ? bk : bv;
        const float bias_v = bp[cn];
#pragma unroll
        for (int rg = 0; rg < 4; ++rg) {
          const int m = mbase + rg;
          const int b = m >> 11, tt = m & 2047;
          const size_t bh = (size_t)(b * 16 + h);
          const float val = acc[fm][fn][rg] + bias_v;
          if (seg == 0)      oq[(bh * 2048 + tt) * 64 + d] = __float2bfloat16(val);
          else if (seg == 1) ok[(bh * 2048 + tt) * 64 + d] = __float2bfloat16(val);
          else               ovt[(bh * 64 + d) * 2048 + tt] = __float2bfloat16(val);
        }
      } else if (EPI == 1) {
        const float bias_v = bias[n];
#pragma unroll
        for (int rg = 0; rg < 4; ++rg) {
          const int m = mbase + rg;
          float val = acc[fm][fn][rg] + bias_v;
          val = fmaxf(val, 0.f);
          obf[(size_t)m * N + n] = __float2bfloat16(val);
        }
      } else {
        __hip_bfloat16* op = (blockIdx.z == 0) ? opart0 : (blockIdx.z == 1) ? opart1
                           : (blockIdx.z == 2) ? opart2 : opart3;
#pragma unroll
        for (int rg = 0; rg < 4; ++rg) {
          const int m = mbase + rg;
          op[(size_t)m * 1024 + n] = __float2bfloat16(acc[fm][fn][rg]);
        }
      }
    }
  }
}

// -------------------- FFN2 merge: out = z + b2 + p0 + p1 + p2 + p3 (bf16 partials) ----
__global__ void ffn2_merge(const __hip_bfloat16* __restrict__ p0, const __hip_bfloat16* __restrict__ p1,
                           const __hip_bfloat16* __restrict__ p2, const __hip_bfloat16* __restrict__ p3,
                           const float* __restrict__ z, const float* __restrict__ b2,
                           float* __restrict__ out)
{
  const size_t i = ((size_t)blockIdx.x * 256 + threadIdx.x) * 4;
  const float4 c = *(const float4*)(z + i);
  const float4 bb = *(const float4*)(b2 + (i & 1023));
  float o0 = c.x + bb.x, o1 = c.y + bb.y, o2 = c.z + bb.z, o3 = c.w + bb.w;
  short4v a0 = *(const short4v*)(p0 + i);
  short4v a1 = *(const short4v*)(p1 + i);
  short4v a2 = *(const short4v*)(p2 + i);
  short4v a3 = *(const short4v*)(p3 + i);
  o0 += bf2f(a0[0]) + bf2f(a1[0]) + bf2f(a2[0]) + bf2f(a3[0]);
  o1 += bf2f(a0[1]) + bf2f(a1[1]) + bf2f(a2[1]) + bf2f(a3[1]);
  o2 += bf2f(a0[2]) + bf2f(a1[2]) + bf2f(a2[2]) + bf2f(a3[2]);
  o3 += bf2f(a0[3]) + bf2f(a1[3]) + bf2f(a2[3]) + bf2f(a3[3]);
  float4 o; o.x = o0; o.y = o1; o.z = o2; o.w = o3;
  *(float4*)(out + i) = o;
}

// ---------- flash attention v9: 8 waves x 32 q-rows (QBLK=256), 2-deep skeleton ------
__global__ __launch_bounds__(512, 2) void flash_attn(
    const __hip_bfloat16* __restrict__ Q, const __hip_bfloat16* __restrict__ Kb,
    const __hip_bfloat16* __restrict__ Vt,
    __hip_bfloat16* __restrict__ Opart, float* __restrict__ Lpart)
{
  __shared__ short Ks[2][64 * 64];
  __shared__ short Vs[2][64 * 64];
  __shared__ short P2[8][32 * 72];
  const int t = threadIdx.x;
  const int lane = t & 63, w = t >> 6;     // 8 waves, 32 q-rows each
  const int l15 = lane & 15, lg = lane >> 4;
  const int chunk = blockIdx.x, bh = blockIdx.z;
  const int qblk = 7 - (int)blockIdx.y;    // heavy blocks dispatch first
  const int q0 = qblk * 256;
  const int s_base = chunk * 512;
  if (s_base > q0 + 255) return;
  const int s_hi = (s_base + 512 < q0 + 256) ? s_base + 512 : q0 + 256;
  const int ntiles = (s_hi - s_base) >> 6;
  const int qw = q0 + w * 32;

  const __hip_bfloat16* Qbh = Q + (size_t)bh * 2048 * 64;
  const __hip_bfloat16* Kbh = Kb + (size_t)bh * 2048 * 64;
  const __hip_bfloat16* Vbh = Vt + (size_t)bh * 64 * 2048;

  bf16x8 qf[2][2];
#pragma unroll
  for (int fm = 0; fm < 2; ++fm)
#pragma unroll
    for (int kc = 0; kc < 2; ++kc)
      qf[fm][kc] = *(const bf16x8*)(Qbh + (size_t)(qw + fm * 16 + l15) * 64 + kc * 32 + lg * 8);

  const int srow = t >> 3;
  const int schunk = ((t & 7) ^ (srow & 7)) * 8;

  auto STAGE = [&](int bufi, int s0) {
    const int dst = bufi * 8192 + t * 16;
    gload_lds16(Kbh + (size_t)(s0 + srow) * 64 + schunk, (char*)Ks + dst);
    gload_lds16(Vbh + (size_t)srow * 2048 + s0 + schunk, (char*)Vs + dst);
  };

  f32x4 o_acc[2][4];
  float lpart[2] = {0.f, 0.f};
#pragma unroll
  for (int fm = 0; fm < 2; ++fm)
#pragma unroll
    for (int fd = 0; fd < 4; ++fd)
#pragma unroll
      for (int e = 0; e < 4; ++e) o_acc[fm][fd][e] = 0.f;

  const float C = 0.18033688011112042f;   // 0.125 * log2(e)

  STAGE(0, s_base);
  int cur = 0;
  for (int ti = 0; ti < ntiles; ++ti) {
    const int s0 = s_base + ti * 64;
    const int nxt = (ti + 1 < ntiles) ? s0 + 64 : s0;
    STAGE(cur ^ 1, nxt);
    asm volatile("s_waitcnt vmcnt(2)" ::: "memory");
    __builtin_amdgcn_s_barrier();
    asm volatile("" ::: "memory");

    if (s0 <= qw + 31) {
      f32x4 s_acc[2][4];
#pragma unroll
      for (int fm = 0; fm < 2; ++fm)
#pragma unroll
        for (int fn = 0; fn < 4; ++fn)
#pragma unroll
          for (int e = 0; e < 4; ++e) s_acc[fm][fn][e] = 0.f;
      __builtin_amdgcn_s_setprio(1);
#pragma unroll
      for (int kc = 0; kc < 2; ++kc)
#pragma unroll
        for (int fn = 0; fn < 4; ++fn) {
          const int r = fn * 16 + l15;
          bf16x8 kf = *(const bf16x8*)&Ks[cur][r * 64 + ((((kc << 2) | lg) ^ (l15 & 7)) << 3)];
          s_acc[0][fn] = __builtin_amdgcn_mfma_f32_16x16x32_bf16(kf, qf[0][kc], s_acc[0][fn], 0, 0, 0);
          s_acc[1][fn] = __builtin_amdgcn_mfma_f32_16x16x32_bf16(kf, qf[1][kc], s_acc[1][fn], 0, 0, 0);
        }
      __builtin_amdgcn_s_setprio(0);

      const bool needmask = (s0 + 63 > qw);
      float pr[2][4][4];
#pragma unroll
      for (int fm = 0; fm < 2; ++fm) {
        const int qv = qw + fm * 16 + l15;
#pragma unroll
        for (int fn = 0; fn < 4; ++fn)
#pragma unroll
          for (int rg = 0; rg < 4; ++rg) {
            float p = exp2_fast(s_acc[fm][fn][rg] * C);
            if (needmask) {
              const int sg = s0 + fn * 16 + lg * 4 + rg;
              p = (sg <= qv) ? p : 0.f;
            }
            pr[fm][fn][rg] = p;
            lpart[fm] += p;
          }
      }

#pragma unroll
      for (int fm = 0; fm < 2; ++fm)
#pragma unroll
        for (int fn = 0; fn < 4; ++fn) {
          uint2v u;
          u.x = cvt_pk_bf16(pr[fm][fn][0], pr[fm][fn][1]);
          u.y = cvt_pk_bf16(pr[fm][fn][2], pr[fm][fn][3]);
          *(uint2v*)&P2[w][(fm * 16 + l15) * 72 + fn * 16 + lg * 4] = u;
        }

      __builtin_amdgcn_s_setprio(1);
#pragma unroll
      for (int kc = 0; kc < 2; ++kc) {
        bf16x8 pf0 = *(const bf16x8*)&P2[w][(l15) * 72 + kc * 32 + lg * 8];
        bf16x8 pf1 = *(const bf16x8*)&P2[w][(16 + l15) * 72 + kc * 32 + lg * 8];
#pragma unroll
        for (int fd = 0; fd < 4; ++fd) {
          const int r = fd * 16 + l15;
          bf16x8 vf = *(const bf16x8*)&Vs[cur][r * 64 + ((((kc << 2) | lg) ^ (l15 & 7)) << 3)];
          o_acc[0][fd] = __builtin_amdgcn_mfma_f32_16x16x32_bf16(vf, pf0, o_acc[0][fd], 0, 0, 0);
          o_acc[1][fd] = __builtin_amdgcn_mfma_f32_16x16x32_bf16(vf, pf1, o_acc[1][fd], 0, 0, 0);
        }
      }
      __builtin_amdgcn_s_setprio(0);
    }

    asm volatile("" ::: "memory");
    __builtin_amdgcn_s_barrier();
    cur ^= 1;
  }

  const int pslot = ((bh * 8 + qblk) << 2) + chunk;
  __hip_bfloat16* op = Opart + (size_t)pslot * 16384;
#pragma unroll
  for (int fm = 0; fm < 2; ++fm) {
    float l = lpart[fm];
    l += __shfl_xor(l, 16);
    l += __shfl_xor(l, 32);
    const int qloc = w * 32 + fm * 16 + l15;
    if (lg == 0) Lpart[(size_t)pslot * 256 + qloc] = l;
#pragma unroll
    for (int fd = 0; fd < 4; ++fd) {
      uint2v u;
      u.x = cvt_pk_bf16(o_acc[fm][fd][0], o_acc[fm][fd][1]);
      u.y = cvt_pk_bf16(o_acc[fm][fd][2], o_acc[fm][fd][3]);
      *(uint2v*)(op + (size_t)qloc * 64 + fd * 16 + lg * 4) = u;
    }
  }
}

// -------------------- launch --------------------
extern "C" void kernel_launch(void* const* d_in, const int* in_sizes, int n_in,
                              void* d_out, int out_size, void* d_ws, size_t ws_size,
                              hipStream_t stream) {
  const float* x    = (const float*)d_in[0];
  const float* wq   = (const float*)d_in[1];
  const float* bq   = (const float*)d_in[2];
  const float* wk   = (const float*)d_in[3];
  const float* bk   = (const float*)d_in[4];
  const float* wv   = (const float*)d_in[5];
  const float* bv   = (const float*)d_in[6];
  const float* ln1g = (const float*)d_in[7];
  const float* ln1b = (const float*)d_in[8];
  const float* ln2g = (const float*)d_in[9];
  const float* ln2b = (const float*)d_in[10];
  const float* w1   = (const float*)d_in[11];
  const float* b1   = (const float*)d_in[12];
  const float* w2   = (const float*)d_in[13];
  const float* b2   = (const float*)d_in[14];
  float* out = (float*)d_out;

  char* ws = (char*)d_ws;
  const size_t MB = 1024 * 1024;
  __hip_bfloat16* h_bf  = (__hip_bfloat16*)(ws + 0);
  float* z_f32          = (float*)(ws + 0);
  __hip_bfloat16* qb    = (__hip_bfloat16*)(ws + 8 * MB);
  __hip_bfloat16* kb    = (__hip_bfloat16*)(ws + 16 * MB);
  __hip_bfloat16* z_bf  = (__hip_bfloat16*)(ws + 16 * MB);
  __hip_bfloat16* vtb   = (__hip_bfloat16*)(ws + 24 * MB);
  __hip_bfloat16* ff1   = (__hip_bfloat16*)(ws + 24 * MB);
  float* h_f32          = (float*)(ws + 32 * MB);
  __hip_bfloat16* p3    = (__hip_bfloat16*)(ws + 32 * MB);
  __hip_bfloat16* Opart = (__hip_bfloat16*)(ws + 48 * MB);
  __hip_bfloat16* p0    = (__hip_bfloat16*)(ws + 56 * MB);
  __hip_bfloat16* p1    = (__hip_bfloat16*)(ws + 64 * MB);
  __hip_bfloat16* p2    = (__hip_bfloat16*)(ws + 72 * MB);
  float* Lpart          = (float*)(ws + 80 * MB);
  __hip_bfloat16* wqkvT = (__hip_bfloat16*)(ws + 88 * MB);
  __hip_bfloat16* w1T   = (__hip_bfloat16*)(ws + 96 * MB);
  __hip_bfloat16* w2T   = (__hip_bfloat16*)(ws + 104 * MB);

  // fused prep: QKV/W1/W2 transposes + LN1 in one launch
  prep_all<<<6912, 256, 0, stream>>>(wq, wk, wv, w1, w2, x, ln1g, ln1b,
                                     wqkvT, w1T, w2T, h_f32, h_bf);

  // QKV projection: M=4096, N=3072, K=1024  (grid 12*32=384, %8==0)
  gemm_bt<0><<<dim3(12, 32), 512, 0, stream>>>(h_bf, wqkvT, 3072, 1024, 1024,
      nullptr, bq, bk, bv, qb, kb, vtb, nullptr, nullptr, nullptr, nullptr, nullptr);

  // flash v9: grid (chunk 4, qblk 8, bh 32)
  flash_attn<<<dim3(4, 8, 32), 512, 0, stream>>>(qb, kb, vtb, Opart, Lpart);

  // LN2 + KV-split merge fused: z = LN(h + sum(O)/sum(l))
  ln2_merge_fused<<<4096, 256, 0, stream>>>(h_f32, Opart, Lpart, ln2g, ln2b, z_f32, z_bf);

  // FFN1: relu(z @ w1 + b1), M=4096, N=4096, K=1024  (grid 16*32=512, %8==0)
  gemm_bt<1><<<dim3(16, 32), 512, 0, stream>>>(z_bf, w1T, 4096, 1024, 1024,
      b1, nullptr, nullptr, nullptr, nullptr, nullptr, nullptr, ff1, nullptr, nullptr, nullptr, nullptr);

  // FFN2 split-K=4 (1024 each), bf16 partials: M=4096, N=1024, K=4096 (grid 4*32*4=512)
  gemm_bt<2><<<dim3(4, 32, 4), 512, 0, stream>>>(ff1, w2T, 1024, 4096, 1024,
      nullptr, nullptr, nullptr, nullptr, nullptr, nullptr, nullptr, nullptr, p0, p1, p2, p3);

  // out = z + b2 + p0 + p1 + p2 + p3
  ffn2_merge<<<4096, 256, 0, stream>>>(p0, p1, p2, p3, z_f32, b2, out);
}

// Round 24
// 217.645 us; speedup vs baseline: 1.5150x; 1.0033x over previous
//
#include <hip/hip_runtime.h>
#include <hip/hip_bf16.h>
#include <cstdint>
#include <cstddef>

typedef __attribute__((ext_vector_type(8))) short bf16x8;
typedef __attribute__((ext_vector_type(4))) float f32x4;
typedef __attribute__((ext_vector_type(4))) short short4v;
typedef __attribute__((ext_vector_type(2))) unsigned int uint2v;

__device__ inline void gload_lds16(const void* g, void* l) {
  __builtin_amdgcn_global_load_lds((const __attribute__((address_space(1))) void*)g,
                                   (__attribute__((address_space(3))) void*)l, 16, 0, 0);
}

__device__ inline float exp2_fast(float x) {
  float r;
  asm volatile("v_exp_f32 %0, %1" : "=v"(r) : "v"(x));
  return r;
}

__device__ inline unsigned int cvt_pk_bf16(float lo, float hi) {
  unsigned int r;
  asm volatile("v_cvt_pk_bf16_f32 %0, %1, %2" : "=v"(r) : "v"(lo), "v"(hi));
  return r;
}

__device__ inline float bf2f(short s) {
  return __uint_as_float(((unsigned int)(unsigned short)s) << 16);
}

// ---------- fused prep: QKV/W1/W2 weight transposes + LN1, one launch ----------
__global__ void prep_all(const float* __restrict__ wq, const float* __restrict__ wk,
                         const float* __restrict__ wv, const float* __restrict__ w1,
                         const float* __restrict__ w2,
                         const float* __restrict__ x, const float* __restrict__ ln1g,
                         const float* __restrict__ ln1b,
                         __hip_bfloat16* __restrict__ wqkvT, __hip_bfloat16* __restrict__ w1T,
                         __hip_bfloat16* __restrict__ w2T,
                         float* __restrict__ h_f32, __hip_bfloat16* __restrict__ h_bf)
{
  __shared__ float tile[64][65];
  __shared__ float sb[4], ssb[4];
  const int b = blockIdx.x;
  const int t = threadIdx.x;

  if (b < 768) {
    const int y = b & 15, z = b >> 4;
    const int seg = z >> 4, h = z & 15;
    const float* src = (seg == 0) ? wq : (seg == 1) ? wk : wv;
    src += (size_t)h * 65536;
    const int r0 = y * 64;
#pragma unroll
    for (int i = 0; i < 16; ++i) {
      int idx = i * 256 + t;
      int r = idx >> 6, c = idx & 63;
      tile[r][c] = src[(size_t)(r0 + r) * 64 + c];
    }
    __syncthreads();
    const int drow0 = seg * 1024 + h * 64;
#pragma unroll
    for (int i = 0; i < 16; ++i) {
      int idx = i * 256 + t;
      int cc = idx >> 6, rr = idx & 63;
      wqkvT[(size_t)(drow0 + cc) * 1024 + r0 + rr] = __float2bfloat16(tile[rr][cc]);
    }
  } else if (b < 1792) {
    const int bb = b - 768;
    const int xb = bb & 63, yb = bb >> 6;
    const int c0 = xb * 64, r0 = yb * 64;
#pragma unroll
    for (int i = 0; i < 16; ++i) {
      int idx = i * 256 + t;
      int r = idx >> 6, c = idx & 63;
      tile[r][c] = w1[(size_t)(r0 + r) * 4096 + c0 + c];
    }
    __syncthreads();
#pragma unroll
    for (int i = 0; i < 16; ++i) {
      int idx = i * 256 + t;
      int cc = idx >> 6, rr = idx & 63;
      w1T[(size_t)(c0 + cc) * 1024 + r0 + rr] = __float2bfloat16(tile[rr][cc]);
    }
  } else if (b < 2816) {
    const int bb = b - 1792;
    const int xb = bb & 15, yb = bb >> 4;
    const int c0 = xb * 64, r0 = yb * 64;
#pragma unroll
    for (int i = 0; i < 16; ++i) {
      int idx = i * 256 + t;
      int r = idx >> 6, c = idx & 63;
      tile[r][c] = w2[(size_t)(r0 + r) * 1024 + c0 + c];
    }
    __syncthreads();
#pragma unroll
    for (int i = 0; i < 16; ++i) {
      int idx = i * 256 + t;
      int cc = idx >> 6, rr = idx & 63;
      w2T[(size_t)(c0 + cc) * 4096 + r0 + rr] = __float2bfloat16(tile[rr][cc]);
    }
  } else {
    const int row = b - 2816;
    float4 v = ((const float4*)(x + (size_t)row * 1024))[t];
    float s = v.x + v.y + v.z + v.w;
    float ss = v.x * v.x + v.y * v.y + v.z * v.z + v.w * v.w;
#pragma unroll
    for (int off = 1; off < 64; off <<= 1) {
      s += __shfl_xor(s, off);
      ss += __shfl_xor(ss, off);
    }
    const int w = t >> 6, lane = t & 63;
    if (lane == 0) { sb[w] = s; ssb[w] = ss; }
    __syncthreads();
    s = sb[0] + sb[1] + sb[2] + sb[3];
    ss = ssb[0] + ssb[1] + ssb[2] + ssb[3];
    const float mu = s * (1.f / 1024.f);
    const float var = ss * (1.f / 1024.f) - mu * mu;
    const float rstd = rsqrtf(var + 1e-5f);
    float4 gv = ((const float4*)ln1g)[t];
    float4 bv = ((const float4*)ln1b)[t];
    float4 o;
    o.x = (v.x - mu) * rstd * gv.x + bv.x;
    o.y = (v.y - mu) * rstd * gv.y + bv.y;
    o.z = (v.z - mu) * rstd * gv.z + bv.z;
    o.w = (v.w - mu) * rstd * gv.w + bv.w;
    ((float4*)(h_f32 + (size_t)row * 1024))[t] = o;
    __hip_bfloat16 hb[4] = { __float2bfloat16(o.x), __float2bfloat16(o.y),
                             __float2bfloat16(o.z), __float2bfloat16(o.w) };
    *(short4v*)(h_bf + (size_t)row * 1024 + t * 4) = *(const short4v*)hb;
  }
}

// ---------- LN2 fused with KV-split merge: y = h + sum(O)/sum(l); z = LN(y) ----------
__global__ void ln2_merge_fused(const float* __restrict__ hres,
                                const __hip_bfloat16* __restrict__ Opart,
                                const float* __restrict__ Lpart,
                                const float* __restrict__ g, const float* __restrict__ bta,
                                float* __restrict__ of32, __hip_bfloat16* __restrict__ obf)
{
  const int row = blockIdx.x;            // b*2048 + t
  const int b = row >> 11, tt = row & 2047;
  const int qblk = tt >> 8, qloc = tt & 255;
  const int nch = (qblk >> 1) + 1;
  const int t = threadIdx.x;
  const int hd = t >> 4;
  const int d0 = (t & 15) * 4;
  const int base = (((b * 16 + hd) * 8 + qblk) << 2);

  float4 v = ((const float4*)(hres + (size_t)row * 1024))[t];
  float l = 0.f;
  float o0 = 0.f, o1 = 0.f, o2 = 0.f, o3 = 0.f;
  for (int ch = 0; ch < nch; ++ch) {
    l += Lpart[(size_t)(base + ch) * 256 + qloc];
    short4v o4 = *(const short4v*)(Opart + (size_t)(base + ch) * 16384 + qloc * 64 + d0);
    o0 += bf2f(o4[0]); o1 += bf2f(o4[1]); o2 += bf2f(o4[2]); o3 += bf2f(o4[3]);
  }
  const float inv = 1.f / l;
  v.x += o0 * inv; v.y += o1 * inv; v.z += o2 * inv; v.w += o3 * inv;

  float s = v.x + v.y + v.z + v.w;
  float ss = v.x * v.x + v.y * v.y + v.z * v.z + v.w * v.w;
#pragma unroll
  for (int off = 1; off < 64; off <<= 1) {
    s += __shfl_xor(s, off);
    ss += __shfl_xor(ss, off);
  }
  __shared__ float sb[4], ssb[4];
  const int w = t >> 6, lane = t & 63;
  if (lane == 0) { sb[w] = s; ssb[w] = ss; }
  __syncthreads();
  s = sb[0] + sb[1] + sb[2] + sb[3];
  ss = ssb[0] + ssb[1] + ssb[2] + ssb[3];
  const float mu = s * (1.f / 1024.f);
  const float var = ss * (1.f / 1024.f) - mu * mu;
  const float rstd = rsqrtf(var + 1e-5f);
  float4 gv = ((const float4*)g)[t];
  float4 bv = ((const float4*)bta)[t];
  float4 o;
  o.x = (v.x - mu) * rstd * gv.x + bv.x;
  o.y = (v.y - mu) * rstd * gv.y + bv.y;
  o.z = (v.z - mu) * rstd * gv.z + bv.z;
  o.w = (v.w - mu) * rstd * gv.w + bv.w;
  ((float4*)(of32 + (size_t)row * 1024))[t] = o;
  __hip_bfloat16 hb[4] = { __float2bfloat16(o.x), __float2bfloat16(o.y),
                           __float2bfloat16(o.z), __float2bfloat16(o.w) };
  *(short4v*)(obf + (size_t)row * 1024 + t * 4) = *(const short4v*)hb;
}

// -------------------- GEMM: 8 waves, BM=128 BN=256 BK=32, 2-deep + T1 swizzle ---------
// EPI 0: QKV scatter (+bias); q written PRE-SCALED by 0.125*log2(e) (flash uses exp2
// directly — exactly one scaling application on the Q path).
template<int EPI>
__global__ __launch_bounds__(512, 2) void gemm_bt(
    const __hip_bfloat16* __restrict__ A, const __hip_bfloat16* __restrict__ Bt,
    int N, int Kf, int kLen,
    const float* __restrict__ bias,
    const float* __restrict__ bq, const float* __restrict__ bk, const float* __restrict__ bv,
    __hip_bfloat16* __restrict__ oq, __hip_bfloat16* __restrict__ ok, __hip_bfloat16* __restrict__ ovt,
    __hip_bfloat16* __restrict__ obf,
    __hip_bfloat16* __restrict__ opart0, __hip_bfloat16* __restrict__ opart1,
    __hip_bfloat16* __restrict__ opart2, __hip_bfloat16* __restrict__ opart3)
{
  __shared__ short As[2][128 * 32];
  __shared__ short Bs[2][256 * 32];
  const int t = threadIdx.x;
  const int lane = t & 63;
  const int w = t >> 6;
  const int wm = w >> 2, wn = w & 3;
  const int l15 = lane & 15, lg = lane >> 4;

  const int nwg = (int)(gridDim.x * gridDim.y);
  int wgid = (int)blockIdx.y * (int)gridDim.x + (int)blockIdx.x;
  wgid = (wgid & 7) * (nwg >> 3) + (wgid >> 3);
  const int bx = wgid % (int)gridDim.x;
  const int by = wgid / (int)gridDim.x;
  const int m0 = by * 128;
  const int n0 = bx * 256;
  const int kBase = (EPI == 2) ? (int)blockIdx.z * kLen : 0;
  const int kEnd0 = kBase + kLen;
  const int kEnd = (kEnd0 > Kf) ? Kf : kEnd0;

  f32x4 acc[4][4];
#pragma unroll
  for (int i = 0; i < 4; ++i)
#pragma unroll
    for (int j = 0; j < 4; ++j)
#pragma unroll
      for (int e = 0; e < 4; ++e) acc[i][j][e] = 0.f;

  auto STAGE = [&](int buf, int kk0) {
    {
      const int r = t >> 2, cc = t & 3;
      const int kk = (cc ^ ((r >> 1) & 3)) * 8;
      gload_lds16(A + (size_t)(m0 + r) * Kf + kk0 + kk, (char*)As + buf * 8192 + t * 16);
    }
#pragma unroll
    for (int i = 0; i < 2; ++i) {
      const int c = t + 512 * i;
      const int r = c >> 2, cc = c & 3;
      const int kk = (cc ^ ((r >> 1) & 3)) * 8;
      gload_lds16(Bt + (size_t)(n0 + r) * Kf + kk0 + kk, (char*)Bs + buf * 16384 + c * 16);
    }
  };

  STAGE(0, kBase);
  int buf = 0;
  for (int k0 = kBase; k0 < kEnd; k0 += 32) {
    const int knext = (k0 + 32 < kEnd) ? k0 + 32 : k0;
    STAGE(buf ^ 1, knext);
    asm volatile("s_waitcnt vmcnt(3)" ::: "memory");
    __builtin_amdgcn_s_barrier();
    asm volatile("" ::: "memory");

    bf16x8 af[4], bfr[4];
#pragma unroll
    for (int fm = 0; fm < 4; ++fm) {
      const int r = wm * 64 + fm * 16 + l15;
      const int kc = lg ^ ((r >> 1) & 3);
      af[fm] = *(const bf16x8*)&As[buf][r * 32 + kc * 8];
    }
#pragma unroll
    for (int fn = 0; fn < 4; ++fn) {
      const int r = wn * 64 + fn * 16 + l15;
      const int kc = lg ^ ((r >> 1) & 3);
      bfr[fn] = *(const bf16x8*)&Bs[buf][r * 32 + kc * 8];
    }
#pragma unroll
    for (int fm = 0; fm < 4; ++fm)
#pragma unroll
      for (int fn = 0; fn < 4; ++fn)
        acc[fm][fn] = __builtin_amdgcn_mfma_f32_16x16x32_bf16(af[fm], bfr[fn], acc[fm][fn], 0, 0, 0);

    asm volatile("" ::: "memory");
    __builtin_amdgcn_s_barrier();
    buf ^= 1;
  }

  const float CSCALE = 0.18033688011112042f;   // 0.125 * log2(e), folded into Q
#pragma unroll
  for (int fm = 0; fm < 4; ++fm) {
    const int mbase = m0 + wm * 64 + fm * 16 + lg * 4;
#pragma unroll
    for (int fn = 0; fn < 4; ++fn) {
      const int n = n0 + wn * 64 + fn * 16 + l15;
      if (EPI == 0) {
        const int seg = n >> 10;
        const int cn = n & 1023;
        const int h = cn >> 6, d = cn & 63;
        const float* bp = (seg == 0) ? bq : (seg == 1) ? bk : bv;
        const float bias_v = bp[cn];
#pragma unroll
        for (int rg = 0; rg < 4; ++rg) {
          const int m = mbase + rg;
          const int b = m >> 11, tt = m & 2047;
          const size_t bh = (size_t)(b * 16 + h);
          const float val = acc[fm][fn][rg] + bias_v;
          if (seg == 0)      oq[(bh * 2048 + tt) * 64 + d] = __float2bfloat16(val * CSCALE);
          else if (seg == 1) ok[(bh * 2048 + tt) * 64 + d] = __float2bfloat16(val);
          else               ovt[(bh * 64 + d) * 2048 + tt] = __float2bfloat16(val);
        }
      } else if (EPI == 1) {
        const float bias_v = bias[n];
#pragma unroll
        for (int rg = 0; rg < 4; ++rg) {
          const int m = mbase + rg;
          float val = acc[fm][fn][rg] + bias_v;
          val = fmaxf(val, 0.f);
          obf[(size_t)m * N + n] = __float2bfloat16(val);
        }
      } else {
        __hip_bfloat16* op = (blockIdx.z == 0) ? opart0 : (blockIdx.z == 1) ? opart1
                           : (blockIdx.z == 2) ? opart2 : opart3;
#pragma unroll
        for (int rg = 0; rg < 4; ++rg) {
          const int m = mbase + rg;
          op[(size_t)m * 1024 + n] = __float2bfloat16(acc[fm][fn][rg]);
        }
      }
    }
  }
}

// -------------------- FFN2 merge: out = z + b2 + p0 + p1 + p2 + p3 (bf16 partials) ----
__global__ void ffn2_merge(const __hip_bfloat16* __restrict__ p0, const __hip_bfloat16* __restrict__ p1,
                           const __hip_bfloat16* __restrict__ p2, const __hip_bfloat16* __restrict__ p3,
                           const float* __restrict__ z, const float* __restrict__ b2,
                           float* __restrict__ out)
{
  const size_t i = ((size_t)blockIdx.x * 256 + threadIdx.x) * 4;
  const float4 c = *(const float4*)(z + i);
  const float4 bb = *(const float4*)(b2 + (i & 1023));
  float o0 = c.x + bb.x, o1 = c.y + bb.y, o2 = c.z + bb.z, o3 = c.w + bb.w;
  short4v a0 = *(const short4v*)(p0 + i);
  short4v a1 = *(const short4v*)(p1 + i);
  short4v a2 = *(const short4v*)(p2 + i);
  short4v a3 = *(const short4v*)(p3 + i);
  o0 += bf2f(a0[0]) + bf2f(a1[0]) + bf2f(a2[0]) + bf2f(a3[0]);
  o1 += bf2f(a0[1]) + bf2f(a1[1]) + bf2f(a2[1]) + bf2f(a3[1]);
  o2 += bf2f(a0[2]) + bf2f(a1[2]) + bf2f(a2[2]) + bf2f(a3[2]);
  o3 += bf2f(a0[3]) + bf2f(a1[3]) + bf2f(a2[3]) + bf2f(a3[3]);
  float4 o; o.x = o0; o.y = o1; o.z = o2; o.w = o3;
  *(float4*)(out + i) = o;
}

// ---------- flash attention v9b: Q pre-scaled, exp2 direct; QBLK=256, 8 waves --------
__global__ __launch_bounds__(512, 2) void flash_attn(
    const __hip_bfloat16* __restrict__ Q, const __hip_bfloat16* __restrict__ Kb,
    const __hip_bfloat16* __restrict__ Vt,
    __hip_bfloat16* __restrict__ Opart, float* __restrict__ Lpart)
{
  __shared__ short Ks[2][64 * 64];
  __shared__ short Vs[2][64 * 64];
  __shared__ short P2[8][32 * 72];
  const int t = threadIdx.x;
  const int lane = t & 63, w = t >> 6;
  const int l15 = lane & 15, lg = lane >> 4;
  const int chunk = blockIdx.x, bh = blockIdx.z;
  const int qblk = 7 - (int)blockIdx.y;
  const int q0 = qblk * 256;
  const int s_base = chunk * 512;
  if (s_base > q0 + 255) return;
  const int s_hi = (s_base + 512 < q0 + 256) ? s_base + 512 : q0 + 256;
  const int ntiles = (s_hi - s_base) >> 6;
  const int qw = q0 + w * 32;

  const __hip_bfloat16* Qbh = Q + (size_t)bh * 2048 * 64;
  const __hip_bfloat16* Kbh = Kb + (size_t)bh * 2048 * 64;
  const __hip_bfloat16* Vbh = Vt + (size_t)bh * 64 * 2048;

  bf16x8 qf[2][2];
#pragma unroll
  for (int fm = 0; fm < 2; ++fm)
#pragma unroll
    for (int kc = 0; kc < 2; ++kc)
      qf[fm][kc] = *(const bf16x8*)(Qbh + (size_t)(qw + fm * 16 + l15) * 64 + kc * 32 + lg * 8);

  const int srow = t >> 3;
  const int schunk = ((t & 7) ^ (srow & 7)) * 8;

  auto STAGE = [&](int bufi, int s0) {
    const int dst = bufi * 8192 + t * 16;
    gload_lds16(Kbh + (size_t)(s0 + srow) * 64 + schunk, (char*)Ks + dst);
    gload_lds16(Vbh + (size_t)srow * 2048 + s0 + schunk, (char*)Vs + dst);
  };

  f32x4 o_acc[2][4];
  float lpart[2] = {0.f, 0.f};
#pragma unroll
  for (int fm = 0; fm < 2; ++fm)
#pragma unroll
    for (int fd = 0; fd < 4; ++fd)
#pragma unroll
      for (int e = 0; e < 4; ++e) o_acc[fm][fd][e] = 0.f;

  STAGE(0, s_base);
  int cur = 0;
  for (int ti = 0; ti < ntiles; ++ti) {
    const int s0 = s_base + ti * 64;
    const int nxt = (ti + 1 < ntiles) ? s0 + 64 : s0;
    STAGE(cur ^ 1, nxt);
    asm volatile("s_waitcnt vmcnt(2)" ::: "memory");
    __builtin_amdgcn_s_barrier();
    asm volatile("" ::: "memory");

    if (s0 <= qw + 31) {
      f32x4 s_acc[2][4];
#pragma unroll
      for (int fm = 0; fm < 2; ++fm)
#pragma unroll
        for (int fn = 0; fn < 4; ++fn)
#pragma unroll
          for (int e = 0; e < 4; ++e) s_acc[fm][fn][e] = 0.f;
      __builtin_amdgcn_s_setprio(1);
#pragma unroll
      for (int kc = 0; kc < 2; ++kc)
#pragma unroll
        for (int fn = 0; fn < 4; ++fn) {
          const int r = fn * 16 + l15;
          bf16x8 kf = *(const bf16x8*)&Ks[cur][r * 64 + ((((kc << 2) | lg) ^ (l15 & 7)) << 3)];
          s_acc[0][fn] = __builtin_amdgcn_mfma_f32_16x16x32_bf16(kf, qf[0][kc], s_acc[0][fn], 0, 0, 0);
          s_acc[1][fn] = __builtin_amdgcn_mfma_f32_16x16x32_bf16(kf, qf[1][kc], s_acc[1][fn], 0, 0, 0);
        }
      __builtin_amdgcn_s_setprio(0);

      const bool needmask = (s0 + 63 > qw);
      float pr[2][4][4];
#pragma unroll
      for (int fm = 0; fm < 2; ++fm) {
        const int qv = qw + fm * 16 + l15;
#pragma unroll
        for (int fn = 0; fn < 4; ++fn)
#pragma unroll
          for (int rg = 0; rg < 4; ++rg) {
            float p = exp2_fast(s_acc[fm][fn][rg]);   // Q pre-scaled: no *C here
            if (needmask) {
              const int sg = s0 + fn * 16 + lg * 4 + rg;
              p = (sg <= qv) ? p : 0.f;
            }
            pr[fm][fn][rg] = p;
            lpart[fm] += p;
          }
      }

#pragma unroll
      for (int fm = 0; fm < 2; ++fm)
#pragma unroll
        for (int fn = 0; fn < 4; ++fn) {
          uint2v u;
          u.x = cvt_pk_bf16(pr[fm][fn][0], pr[fm][fn][1]);
          u.y = cvt_pk_bf16(pr[fm][fn][2], pr[fm][fn][3]);
          *(uint2v*)&P2[w][(fm * 16 + l15) * 72 + fn * 16 + lg * 4] = u;
        }

      __builtin_amdgcn_s_setprio(1);
#pragma unroll
      for (int kc = 0; kc < 2; ++kc) {
        bf16x8 pf0 = *(const bf16x8*)&P2[w][(l15) * 72 + kc * 32 + lg * 8];
        bf16x8 pf1 = *(const bf16x8*)&P2[w][(16 + l15) * 72 + kc * 32 + lg * 8];
#pragma unroll
        for (int fd = 0; fd < 4; ++fd) {
          const int r = fd * 16 + l15;
          bf16x8 vf = *(const bf16x8*)&Vs[cur][r * 64 + ((((kc << 2) | lg) ^ (l15 & 7)) << 3)];
          o_acc[0][fd] = __builtin_amdgcn_mfma_f32_16x16x32_bf16(vf, pf0, o_acc[0][fd], 0, 0, 0);
          o_acc[1][fd] = __builtin_amdgcn_mfma_f32_16x16x32_bf16(vf, pf1, o_acc[1][fd], 0, 0, 0);
        }
      }
      __builtin_amdgcn_s_setprio(0);
    }

    asm volatile("" ::: "memory");
    __builtin_amdgcn_s_barrier();
    cur ^= 1;
  }

  const int pslot = ((bh * 8 + qblk) << 2) + chunk;
  __hip_bfloat16* op = Opart + (size_t)pslot * 16384;
#pragma unroll
  for (int fm = 0; fm < 2; ++fm) {
    float l = lpart[fm];
    l += __shfl_xor(l, 16);
    l += __shfl_xor(l, 32);
    const int qloc = w * 32 + fm * 16 + l15;
    if (lg == 0) Lpart[(size_t)pslot * 256 + qloc] = l;
#pragma unroll
    for (int fd = 0; fd < 4; ++fd) {
      uint2v u;
      u.x = cvt_pk_bf16(o_acc[fm][fd][0], o_acc[fm][fd][1]);
      u.y = cvt_pk_bf16(o_acc[fm][fd][2], o_acc[fm][fd][3]);
      *(uint2v*)(op + (size_t)qloc * 64 + fd * 16 + lg * 4) = u;
    }
  }
}

// -------------------- launch --------------------
extern "C" void kernel_launch(void* const* d_in, const int* in_sizes, int n_in,
                              void* d_out, int out_size, void* d_ws, size_t ws_size,
                              hipStream_t stream) {
  const float* x    = (const float*)d_in[0];
  const float* wq   = (const float*)d_in[1];
  const float* bq   = (const float*)d_in[2];
  const float* wk   = (const float*)d_in[3];
  const float* bk   = (const float*)d_in[4];
  const float* wv   = (const float*)d_in[5];
  const float* bv   = (const float*)d_in[6];
  const float* ln1g = (const float*)d_in[7];
  const float* ln1b = (const float*)d_in[8];
  const float* ln2g = (const float*)d_in[9];
  const float* ln2b = (const float*)d_in[10];
  const float* w1   = (const float*)d_in[11];
  const float* b1   = (const float*)d_in[12];
  const float* w2   = (const float*)d_in[13];
  const float* b2   = (const float*)d_in[14];
  float* out = (float*)d_out;

  char* ws = (char*)d_ws;
  const size_t MB = 1024 * 1024;
  __hip_bfloat16* h_bf  = (__hip_bfloat16*)(ws + 0);
  float* z_f32          = (float*)(ws + 0);
  __hip_bfloat16* qb    = (__hip_bfloat16*)(ws + 8 * MB);
  __hip_bfloat16* kb    = (__hip_bfloat16*)(ws + 16 * MB);
  __hip_bfloat16* z_bf  = (__hip_bfloat16*)(ws + 16 * MB);
  __hip_bfloat16* vtb   = (__hip_bfloat16*)(ws + 24 * MB);
  __hip_bfloat16* ff1   = (__hip_bfloat16*)(ws + 24 * MB);
  float* h_f32          = (float*)(ws + 32 * MB);
  __hip_bfloat16* p3    = (__hip_bfloat16*)(ws + 32 * MB);
  __hip_bfloat16* Opart = (__hip_bfloat16*)(ws + 48 * MB);
  __hip_bfloat16* p0    = (__hip_bfloat16*)(ws + 56 * MB);
  __hip_bfloat16* p1    = (__hip_bfloat16*)(ws + 64 * MB);
  __hip_bfloat16* p2    = (__hip_bfloat16*)(ws + 72 * MB);
  float* Lpart          = (float*)(ws + 80 * MB);
  __hip_bfloat16* wqkvT = (__hip_bfloat16*)(ws + 88 * MB);
  __hip_bfloat16* w1T   = (__hip_bfloat16*)(ws + 96 * MB);
  __hip_bfloat16* w2T   = (__hip_bfloat16*)(ws + 104 * MB);

  // fused prep: QKV/W1/W2 transposes + LN1 in one launch
  prep_all<<<6912, 256, 0, stream>>>(wq, wk, wv, w1, w2, x, ln1g, ln1b,
                                     wqkvT, w1T, w2T, h_f32, h_bf);

  // QKV projection: M=4096, N=3072, K=1024  (grid 12*32=384, %8==0)
  gemm_bt<0><<<dim3(12, 32), 512, 0, stream>>>(h_bf, wqkvT, 3072, 1024, 1024,
      nullptr, bq, bk, bv, qb, kb, vtb, nullptr, nullptr, nullptr, nullptr, nullptr);

  // flash v9b: grid (chunk 4, qblk 8, bh 32)
  flash_attn<<<dim3(4, 8, 32), 512, 0, stream>>>(qb, kb, vtb, Opart, Lpart);

  // LN2 + KV-split merge fused: z = LN(h + sum(O)/sum(l))
  ln2_merge_fused<<<4096, 256, 0, stream>>>(h_f32, Opart, Lpart, ln2g, ln2b, z_f32, z_bf);

  // FFN1: relu(z @ w1 + b1), M=4096, N=4096, K=1024  (grid 16*32=512, %8==0)
  gemm_bt<1><<<dim3(16, 32), 512, 0, stream>>>(z_bf, w1T, 4096, 1024, 1024,
      b1, nullptr, nullptr, nullptr, nullptr, nullptr, nullptr, ff1, nullptr, nullptr, nullptr, nullptr);

  // FFN2 split-K=4 (1024 each), bf16 partials: M=4096, N=1024, K=4096 (grid 4*32*4=512)
  gemm_bt<2><<<dim3(4, 32, 4), 512, 0, stream>>>(ff1, w2T, 1024, 4096, 1024,
      nullptr, nullptr, nullptr, nullptr, nullptr, nullptr, nullptr, nullptr, p0, p1, p2, p3);

  // out = z + b2 + p0 + p1 + p2 + p3
  ffn2_merge<<<4096, 256, 0, stream>>>(p0, p1, p2, p3, z_f32, b2, out);
}